// Round 2
// baseline (3971.675 us; speedup 1.0000x reference)
//
#include <hip/hip_runtime.h>
#include <hip/hip_bf16.h>

#define B_SZ 4
#define N_INST 2048
#define D_MODEL 512
#define S_TOT 2049          // N+1 (cls prepended)
#define NH 8
#define HD 64
#define ROWS (B_SZ*S_TOT)   // 8196

__device__ __forceinline__ float gelu_exact(float x){ return 0.5f*x*(1.f+erff(x*0.70710678118654752f)); }

// ---------------------------------------------------------------------------
// Gating MLP: weight[b,n] = sigmoid(MLP(x[b,n,:])), D->64(gelu)->64(gelu)->1
// one wave per instance; lane h owns hidden unit h.
// ---------------------------------------------------------------------------
__global__ __launch_bounds__(64) void aw_weight_kernel(
    const float* __restrict__ x,
    const float* __restrict__ W0, const float* __restrict__ b0,
    const float* __restrict__ W1, const float* __restrict__ b1,
    const float* __restrict__ W2, const float* __restrict__ b2,
    float* __restrict__ weight) {
  int inst = blockIdx.x;
  int h = threadIdx.x;
  __shared__ float xs[512];
  __shared__ float hs[64];
  const float* xp = x + (size_t)inst*D_MODEL;
  for (int i=h;i<512;i+=64) xs[i] = xp[i];
  __syncthreads();
  const float4* w0 = (const float4*)(W0 + (size_t)h*512);
  float acc = b0[h];
  #pragma unroll 8
  for (int k4=0;k4<128;k4++){
    float4 u = w0[k4]; int k = k4*4;
    acc += xs[k+0]*u.x + xs[k+1]*u.y + xs[k+2]*u.z + xs[k+3]*u.w;
  }
  hs[h] = gelu_exact(acc);
  __syncthreads();
  const float4* w1 = (const float4*)(W1 + (size_t)h*64);
  float acc2 = b1[h];
  #pragma unroll
  for (int k4=0;k4<16;k4++){
    float4 u = w1[k4]; int k = k4*4;
    acc2 += hs[k+0]*u.x + hs[k+1]*u.y + hs[k+2]*u.z + hs[k+3]*u.w;
  }
  float h2 = gelu_exact(acc2);
  float p = h2 * W2[h];
  #pragma unroll
  for (int o=32;o;o>>=1) p += __shfl_down(p, o);
  if (h==0){
    float s = p + b2[0];
    weight[inst] = 1.f/(1.f+expf(-s));
  }
}

// ---------------------------------------------------------------------------
// Build z = LN(concat(cls, x*w^p)) for one branch; also the key-mask bias.
// one block per (b,s) row.
// ---------------------------------------------------------------------------
__global__ __launch_bounds__(256) void build_z_kernel(
    const float* __restrict__ x, const float* __restrict__ weight,
    const float* __restrict__ cls, const float* __restrict__ g, const float* __restrict__ be,
    int branch, float* __restrict__ Z, float* __restrict__ maskb) {
  int row = blockIdx.x;
  int b = row / S_TOT, s = row % S_TOT;
  int t = threadIdx.x;
  __shared__ float v[512];
  __shared__ float red[16];
  float scale = 1.f;
  int valid = 1;
  const float* src = cls;
  if (s != 0){
    float w = weight[b*N_INST + (s-1)];
    bool neg = (w < 0.5f);
    valid = (branch==0) ? (neg?1:0) : (neg?0:1);
    scale = (branch==0) ? powf(w, 1.5f) : powf(w, 2.0f/3.0f);
    src = x + ((size_t)b*N_INST + (s-1))*D_MODEL;
  }
  if (t==0) maskb[row] = valid ? 0.f : -1e9f;
  float s1=0.f, s2=0.f;
  for (int i=t;i<512;i+=256){
    float val = src[i];
    if (s != 0) val *= scale;
    v[i]=val; s1+=val; s2+=val*val;
  }
  __syncthreads();
  #pragma unroll
  for (int o=32;o;o>>=1){ s1+=__shfl_down(s1,o); s2+=__shfl_down(s2,o); }
  if ((t&63)==0){ red[t>>6]=s1; red[8+(t>>6)]=s2; }
  __syncthreads();
  s1 = red[0]+red[1]+red[2]+red[3];
  s2 = red[8]+red[9]+red[10]+red[11];
  float mean = s1 * (1.f/512.f);
  float var  = s2 * (1.f/512.f) - mean*mean;
  float rn = rsqrtf(var + 1e-5f);
  float* zr = Z + (size_t)row*D_MODEL;
  for (int i=t;i<512;i+=256)
    zr[i] = (v[i]-mean)*rn*g[i] + be[i];
}

// out = LN(Z + X) rowwise
__global__ __launch_bounds__(256) void add_ln_kernel(
    const float* __restrict__ Zb, const float* __restrict__ Xb,
    const float* __restrict__ g, const float* __restrict__ be,
    float* __restrict__ outb) {
  int row = blockIdx.x;
  int t = threadIdx.x;
  __shared__ float v[512];
  __shared__ float red[16];
  const float* zr = Zb + (size_t)row*512;
  const float* xr = Xb + (size_t)row*512;
  float s1=0.f, s2=0.f;
  for (int i=t;i<512;i+=256){
    float val = zr[i] + xr[i];
    v[i]=val; s1+=val; s2+=val*val;
  }
  __syncthreads();
  #pragma unroll
  for (int o=32;o;o>>=1){ s1+=__shfl_down(s1,o); s2+=__shfl_down(s2,o); }
  if ((t&63)==0){ red[t>>6]=s1; red[8+(t>>6)]=s2; }
  __syncthreads();
  s1 = red[0]+red[1]+red[2]+red[3];
  s2 = red[8]+red[9]+red[10]+red[11];
  float mean = s1 * (1.f/512.f);
  float var  = s2 * (1.f/512.f) - mean*mean;
  float rn = rsqrtf(var + 1e-5f);
  float* orow = outb + (size_t)row*512;
  for (int i=t;i<512;i+=256)
    orow[i] = (v[i]-mean)*rn*g[i] + be[i];
}

// ---------------------------------------------------------------------------
// fp32 GEMM: C[M,N] = A[M,K] @ W[N,K]^T + bias[N].  64x64 tile, TK=16,
// 256 threads, 4x4 register blocking, float4 LDS reads.
// ---------------------------------------------------------------------------
__global__ __launch_bounds__(256) void gemm_bias_kernel(
    const float* __restrict__ A, const float* __restrict__ W,
    const float* __restrict__ bias, float* __restrict__ C,
    int M, int N, int K) {
  __shared__ __align__(16) float As[64][20];
  __shared__ __align__(16) float Ws[64][20];
  int t = threadIdx.x;
  int bm = blockIdx.y*64, bn = blockIdx.x*64;
  int tx = t & 15, ty = t >> 4;
  int lr = t >> 2, lc = t & 3;
  bool aok = (bm + lr) < M;
  const float* Arow = A + (size_t)(bm+lr)*K;
  const float* Wrow = W + (size_t)(bn+lr)*K;
  float c[4][4];
  #pragma unroll
  for (int i=0;i<4;i++)
    #pragma unroll
    for (int j=0;j<4;j++) c[i][j]=0.f;

  for (int k0=0;k0<K;k0+=16){
    __syncthreads();
    float4 av = make_float4(0.f,0.f,0.f,0.f);
    if (aok) av = *(const float4*)(Arow + k0 + lc*4);
    *(float4*)&As[lr][lc*4] = av;
    float4 wv = *(const float4*)(Wrow + k0 + lc*4);
    *(float4*)&Ws[lr][lc*4] = wv;
    __syncthreads();
    #pragma unroll
    for (int kq=0;kq<4;kq++){
      float4 a[4], w[4];
      #pragma unroll
      for (int i=0;i<4;i++) a[i] = *(const float4*)&As[ty+16*i][kq*4];
      #pragma unroll
      for (int j=0;j<4;j++) w[j] = *(const float4*)&Ws[tx+16*j][kq*4];
      #pragma unroll
      for (int i=0;i<4;i++)
        #pragma unroll
        for (int j=0;j<4;j++)
          c[i][j] += a[i].x*w[j].x + a[i].y*w[j].y + a[i].z*w[j].z + a[i].w*w[j].w;
    }
  }
  float bv[4];
  #pragma unroll
  for (int j=0;j<4;j++) bv[j] = bias[bn+tx+16*j];
  #pragma unroll
  for (int i=0;i<4;i++){
    int m = bm+ty+16*i;
    if (m < M){
      #pragma unroll
      for (int j=0;j<4;j++)
        C[(size_t)m*N + bn + tx + 16*j] = c[i][j] + bv[j];
    }
  }
}

// ---------------------------------------------------------------------------
// Flash attention over all queries (layer 0). Block = (qtile of 64, h, b).
// thread = (query q, key-group r of 16 keys). q-row and O in registers.
// ---------------------------------------------------------------------------
__global__ __launch_bounds__(256) void flash_attn_kernel(
    const float* __restrict__ qkv, const float* __restrict__ maskb,
    float* __restrict__ out) {
  int b = blockIdx.z, h = blockIdx.y;
  int S0 = blockIdx.x * 64;
  int t = threadIdx.x;
  int q = t & 63, r = t >> 6;
  __shared__ __align__(16) float Ks[64][68];
  __shared__ __align__(16) float Vs[64][68];
  __shared__ float bias_s[64];
  __shared__ float redm[4][64];
  __shared__ float redl[4][64];
  int qs = S0 + q;
  const float* qptr = qkv + ((size_t)(b*S_TOT) + (qs < S_TOT ? qs : 0))*1536 + h*64;
  float4 qreg[16];
  #pragma unroll
  for (int i=0;i<16;i++){
    float4 u = *(const float4*)(qptr + i*4);
    u.x*=0.125f; u.y*=0.125f; u.z*=0.125f; u.w*=0.125f;
    qreg[i]=u;
  }
  float m_run = -1e30f, l_part = 0.f;
  float4 O[16];
  #pragma unroll
  for (int i=0;i<16;i++) O[i] = make_float4(0.f,0.f,0.f,0.f);

  const int nt = (S_TOT + 63)/64;   // 33
  int lr = t >> 2, lc = t & 3;
  for (int kt=0; kt<nt; kt++){
    int K0 = kt*64;
    __syncthreads();
    {
      int key = K0 + lr;
      bool ok = key < S_TOT;
      const float* kp = qkv + ((size_t)(b*S_TOT) + (ok?key:0))*1536 + 512 + h*64;
      #pragma unroll
      for (int ii=0; ii<4; ii++){
        int cc = lc + ii*4;
        float4 kv = ok ? *(const float4*)(kp + cc*4)        : make_float4(0.f,0.f,0.f,0.f);
        float4 vv = ok ? *(const float4*)(kp + 512 + cc*4)  : make_float4(0.f,0.f,0.f,0.f);
        *(float4*)&Ks[lr][cc*4] = kv;
        *(float4*)&Vs[lr][cc*4] = vv;
      }
      if (t < 64) bias_s[t] = (K0+t < S_TOT) ? maskb[b*S_TOT + K0 + t] : -1e9f;
    }
    __syncthreads();
    float p[16];
    float tmax = -1e30f;
    #pragma unroll
    for (int jj=0;jj<16;jj++){
      int kk = r*16 + jj;
      float s = 0.f;
      #pragma unroll
      for (int d4=0; d4<16; d4++){
        float4 kv = *(const float4*)&Ks[kk][d4*4];
        s += qreg[d4].x*kv.x + qreg[d4].y*kv.y + qreg[d4].z*kv.z + qreg[d4].w*kv.w;
      }
      s += bias_s[kk];
      p[jj] = s;
      tmax = fmaxf(tmax, s);
    }
    redm[r][q] = tmax;
    __syncthreads();
    float m_new = fmaxf(m_run, fmaxf(fmaxf(redm[0][q], redm[1][q]),
                                     fmaxf(redm[2][q], redm[3][q])));
    float alpha = expf(m_run - m_new);
    float psum = 0.f;
    #pragma unroll
    for (int jj=0;jj<16;jj++){
      float pv = expf(p[jj] - m_new);
      p[jj] = pv; psum += pv;
    }
    l_part = l_part*alpha + psum;
    #pragma unroll
    for (int d4=0; d4<16; d4++){
      float4 o = O[d4];
      o.x*=alpha; o.y*=alpha; o.z*=alpha; o.w*=alpha;
      #pragma unroll
      for (int jj=0;jj<16;jj++){
        float4 v4 = *(const float4*)&Vs[r*16+jj][d4*4];
        float pv = p[jj];
        o.x += pv*v4.x; o.y += pv*v4.y; o.z += pv*v4.z; o.w += pv*v4.w;
      }
      O[d4]=o;
    }
    m_run = m_new;
  }
  redl[r][q] = l_part;
  __syncthreads();
  float l = redl[0][q]+redl[1][q]+redl[2][q]+redl[3][q];
  // combine O partials across r-groups in LDS (reuse Ks)
  #pragma unroll 1
  for (int rr=0; rr<4; rr++){
    if (r == rr){
      #pragma unroll
      for (int d4=0; d4<16; d4++){
        if (rr==0){ *(float4*)&Ks[q][d4*4] = O[d4]; }
        else {
          float4 cur = *(const float4*)&Ks[q][d4*4];
          cur.x+=O[d4].x; cur.y+=O[d4].y; cur.z+=O[d4].z; cur.w+=O[d4].w;
          *(float4*)&Ks[q][d4*4] = cur;
        }
      }
    }
    __syncthreads();
  }
  if (qs < S_TOT){
    float inv = 1.f/l;
    float* op = out + ((size_t)(b*S_TOT) + qs)*512 + h*64 + r*16;
    #pragma unroll
    for (int d4=0; d4<4; d4++){
      float4 o = *(const float4*)&Ks[q][r*16 + d4*4];
      o.x*=inv; o.y*=inv; o.z*=inv; o.w*=inv;
      *(float4*)(op + d4*4) = o;
    }
  }
}

// ---------------------------------------------------------------------------
// Layer-1 attention, query 0 only. Block per (h,b). Two-pass softmax in LDS.
// ---------------------------------------------------------------------------
__global__ __launch_bounds__(256) void attn_row0_kernel(
    const float* __restrict__ qkv, const float* __restrict__ maskb,
    float* __restrict__ out0) {
  int h = blockIdx.x, b = blockIdx.y;
  int t = threadIdx.x;
  __shared__ float qs[64];
  __shared__ float sc[S_TOT];
  __shared__ float red[8];
  __shared__ float redO[4][64];
  const float* base = qkv + (size_t)b*S_TOT*1536;
  if (t < 64) qs[t] = base[h*64 + t]*0.125f;
  __syncthreads();
  float lmax = -1e30f;
  for (int j=t; j<S_TOT; j+=256){
    const float* kp = base + (size_t)j*1536 + 512 + h*64;
    float s = maskb[b*S_TOT + j];
    #pragma unroll
    for (int d4=0; d4<16; d4++){
      float4 kv = *(const float4*)(kp + d4*4);
      s += qs[d4*4+0]*kv.x + qs[d4*4+1]*kv.y + qs[d4*4+2]*kv.z + qs[d4*4+3]*kv.w;
    }
    sc[j]=s;
    lmax = fmaxf(lmax, s);
  }
  #pragma unroll
  for (int o=32;o;o>>=1) lmax = fmaxf(lmax, __shfl_down(lmax, o));
  if ((t&63)==0) red[t>>6]=lmax;
  __syncthreads();
  float m = fmaxf(fmaxf(red[0],red[1]),fmaxf(red[2],red[3]));
  float lsum = 0.f;
  for (int j=t;j<S_TOT;j+=256){
    float p = expf(sc[j]-m);
    sc[j]=p; lsum+=p;
  }
  #pragma unroll
  for (int o=32;o;o>>=1) lsum += __shfl_down(lsum,o);
  __syncthreads();
  if ((t&63)==0) red[t>>6]=lsum;
  __syncthreads();
  float l = red[0]+red[1]+red[2]+red[3];
  int d = t & 63, rr = t >> 6;
  float acc = 0.f;
  for (int j=rr; j<S_TOT; j+=4)
    acc += sc[j]*base[(size_t)j*1536 + 1024 + h*64 + d];
  redO[rr][d]=acc;
  __syncthreads();
  if (t < 64){
    float o = (redO[0][t]+redO[1][t]+redO[2][t]+redO[3][t])/l;
    out0[b*512 + h*64 + t] = o;
  }
}

// layer-1 out-proj for row 0 + residual(z row0) + LN -> cls embedding slot
__global__ __launch_bounds__(256) void row0_proj_ln_kernel(
    const float* __restrict__ attn0, const float* __restrict__ Wo, const float* __restrict__ bo,
    const float* __restrict__ Z, const float* __restrict__ g, const float* __restrict__ be,
    float* __restrict__ clsbuf, int branch) {
  int b = blockIdx.x, t = threadIdx.x;
  __shared__ float xin[512];
  __shared__ float y[512];
  __shared__ float red[16];
  for (int i=t;i<512;i+=256) xin[i] = attn0[b*512+i];
  __syncthreads();
  for (int n=t;n<512;n+=256){
    const float4* wr = (const float4*)(Wo + (size_t)n*512);
    float acc = bo[n];
    for (int k4=0;k4<128;k4++){
      float4 u = wr[k4]; int k=k4*4;
      acc += xin[k+0]*u.x + xin[k+1]*u.y + xin[k+2]*u.z + xin[k+3]*u.w;
    }
    y[n] = acc + Z[(size_t)b*S_TOT*512 + n];
  }
  __syncthreads();
  float s1=0.f, s2=0.f;
  for (int i=t;i<512;i+=256){ float a=y[i]; s1+=a; s2+=a*a; }
  #pragma unroll
  for (int o=32;o;o>>=1){ s1+=__shfl_down(s1,o); s2+=__shfl_down(s2,o); }
  if ((t&63)==0){ red[t>>6]=s1; red[8+(t>>6)]=s2; }
  __syncthreads();
  s1 = red[0]+red[1]+red[2]+red[3];
  s2 = red[8]+red[9]+red[10]+red[11];
  float mean = s1*(1.f/512.f);
  float var  = s2*(1.f/512.f) - mean*mean;
  float rn = rsqrtf(var + 1e-5f);
  for (int i=t;i<512;i+=256)
    clsbuf[b*1024 + branch*512 + i] = (y[i]-mean)*rn*g[i] + be[i];
}

// final projection MLP: [B,1024] -> 512 gelu -> 512 gelu -> 512, fp32 out
__global__ __launch_bounds__(256) void final_mlp_kernel(
    const float* __restrict__ emb,
    const float* __restrict__ W0, const float* __restrict__ b0,
    const float* __restrict__ W1, const float* __restrict__ b1,
    const float* __restrict__ W2, const float* __restrict__ b2,
    float* __restrict__ outp) {
  int b = blockIdx.x, t = threadIdx.x;
  __shared__ float e[1024];
  __shared__ float h1[512];
  __shared__ float h2[512];
  for (int i=t;i<1024;i+=256) e[i]=emb[b*1024+i];
  __syncthreads();
  for (int n=t;n<512;n+=256){
    const float4* w = (const float4*)(W0 + (size_t)n*1024);
    float acc = b0[n];
    for (int k4=0;k4<256;k4++){
      float4 u = w[k4]; int k=k4*4;
      acc += e[k+0]*u.x + e[k+1]*u.y + e[k+2]*u.z + e[k+3]*u.w;
    }
    h1[n]=gelu_exact(acc);
  }
  __syncthreads();
  for (int n=t;n<512;n+=256){
    const float4* w = (const float4*)(W1 + (size_t)n*512);
    float acc = b1[n];
    for (int k4=0;k4<128;k4++){
      float4 u = w[k4]; int k=k4*4;
      acc += h1[k+0]*u.x + h1[k+1]*u.y + h1[k+2]*u.z + h1[k+3]*u.w;
    }
    h2[n]=gelu_exact(acc);
  }
  __syncthreads();
  for (int n=t;n<512;n+=256){
    const float4* w = (const float4*)(W2 + (size_t)n*512);
    float acc = b2[n];
    for (int k4=0;k4<128;k4++){
      float4 u = w[k4]; int k=k4*4;
      acc += h2[k+0]*u.x + h2[k+1]*u.y + h2[k+2]*u.z + h2[k+3]*u.w;
    }
    outp[b*512+n] = acc;
  }
}

// ---------------------------------------------------------------------------
extern "C" void kernel_launch(void* const* d_in, const int* in_sizes, int n_in,
                              void* d_out, int out_size, void* d_ws, size_t ws_size,
                              hipStream_t stream) {
  const float* x      = (const float*)d_in[0];
  const float* cls_tk = (const float*)d_in[1];
  const float* ln_g   = (const float*)d_in[2];
  const float* ln_b   = (const float*)d_in[3];
  const float* aw_W0  = (const float*)d_in[4];  const float* aw_b0 = (const float*)d_in[5];
  const float* aw_W1  = (const float*)d_in[6];  const float* aw_b1 = (const float*)d_in[7];
  const float* aw_W2  = (const float*)d_in[8];  const float* aw_b2 = (const float*)d_in[9];
  const float* pr_W0  = (const float*)d_in[10]; const float* pr_b0 = (const float*)d_in[11];
  const float* pr_W1  = (const float*)d_in[12]; const float* pr_b1 = (const float*)d_in[13];
  const float* pr_W2  = (const float*)d_in[14]; const float* pr_b2 = (const float*)d_in[15];
  const float* mWqkv[2] = {(const float*)d_in[16], (const float*)d_in[20]};
  const float* mbqkv[2] = {(const float*)d_in[17], (const float*)d_in[21]};
  const float* mWo[2]   = {(const float*)d_in[18], (const float*)d_in[22]};
  const float* mbo[2]   = {(const float*)d_in[19], (const float*)d_in[23]};

  float* ws = (float*)d_ws;
  size_t off = 0;
  float* weight = ws + off; off += 8192;                 // [B,N]
  float* maskb  = ws + off; off += 8448;                 // [B,S] bias
  float* Z      = ws + off; off += (size_t)ROWS*512;     // LN'd seq (residual base)
  float* T1     = ws + off; off += (size_t)ROWS*512;     // attn out / a1
  float* QKV    = ws + off; off += (size_t)ROWS*1536;
  float* T2     = QKV;                                   // alias: out-proj result lives in
                                                         // dead QKV space (QKV unused between
                                                         // flash_attn and layer-1 gemm)
  float* attn0  = ws + off; off += 2048;                 // [B,D]
  float* clsb   = ws + off; off += 4096;                 // [B,2D] emb
  (void)ws_size; (void)in_sizes; (void)n_in; (void)out_size;

  aw_weight_kernel<<<B_SZ*N_INST, 64, 0, stream>>>(
      x, aw_W0, aw_b0, aw_W1, aw_b1, aw_W2, aw_b2, weight);

  for (int br=0; br<2; br++){
    build_z_kernel<<<ROWS, 256, 0, stream>>>(x, weight, cls_tk, ln_g, ln_b, br, Z, maskb);
    // layer 0
    gemm_bias_kernel<<<dim3(1536/64, (ROWS+63)/64), 256, 0, stream>>>(
        Z, mWqkv[0], mbqkv[0], QKV, ROWS, 1536, 512);
    flash_attn_kernel<<<dim3((S_TOT+63)/64, NH, B_SZ), 256, 0, stream>>>(QKV, maskb, T1);
    gemm_bias_kernel<<<dim3(512/64, (ROWS+63)/64), 256, 0, stream>>>(
        T1, mWo[0], mbo[0], T2, ROWS, 512, 512);
    add_ln_kernel<<<ROWS, 256, 0, stream>>>(Z, T2, ln_g, ln_b, T1);
    // layer 1 (only row 0 of the output is consumed)
    gemm_bias_kernel<<<dim3(1536/64, (ROWS+63)/64), 256, 0, stream>>>(
        T1, mWqkv[1], mbqkv[1], QKV, ROWS, 1536, 512);
    attn_row0_kernel<<<dim3(NH, B_SZ), 256, 0, stream>>>(QKV, maskb, attn0);
    row0_proj_ln_kernel<<<B_SZ, 256, 0, stream>>>(
        attn0, mWo[1], mbo[1], Z, ln_g, ln_b, clsb, br);
  }
  final_mlp_kernel<<<B_SZ, 256, 0, stream>>>(
      clsb, pr_W0, pr_b0, pr_W1, pr_b1, pr_W2, pr_b2, (float*)d_out);
}

// Round 3
// 1963.362 us; speedup vs baseline: 2.0229x; 2.0229x over previous
//
#include <hip/hip_runtime.h>
#include <hip/hip_bf16.h>

#define B_SZ 4
#define N_INST 2048
#define D_MODEL 512
#define S_TOT 2049          // N+1 (cls prepended)
#define NH 8
#define HD 64
#define ROWS (B_SZ*S_TOT)   // 8196

__device__ __forceinline__ float gelu_exact(float x){ return 0.5f*x*(1.f+erff(x*0.70710678118654752f)); }

// ---------------------------------------------------------------------------
// Gating MLP: weight[b,n] = sigmoid(MLP(x[b,n,:])), D->64(gelu)->64(gelu)->1
// ---------------------------------------------------------------------------
__global__ __launch_bounds__(64) void aw_weight_kernel(
    const float* __restrict__ x,
    const float* __restrict__ W0, const float* __restrict__ b0,
    const float* __restrict__ W1, const float* __restrict__ b1,
    const float* __restrict__ W2, const float* __restrict__ b2,
    float* __restrict__ weight) {
  int inst = blockIdx.x;
  int h = threadIdx.x;
  __shared__ float xs[512];
  __shared__ float hs[64];
  const float* xp = x + (size_t)inst*D_MODEL;
  for (int i=h;i<512;i+=64) xs[i] = xp[i];
  __syncthreads();
  const float4* w0 = (const float4*)(W0 + (size_t)h*512);
  float acc = b0[h];
  #pragma unroll 8
  for (int k4=0;k4<128;k4++){
    float4 u = w0[k4]; int k = k4*4;
    acc += xs[k+0]*u.x + xs[k+1]*u.y + xs[k+2]*u.z + xs[k+3]*u.w;
  }
  hs[h] = gelu_exact(acc);
  __syncthreads();
  const float4* w1 = (const float4*)(W1 + (size_t)h*64);
  float acc2 = b1[h];
  #pragma unroll
  for (int k4=0;k4<16;k4++){
    float4 u = w1[k4]; int k = k4*4;
    acc2 += hs[k+0]*u.x + hs[k+1]*u.y + hs[k+2]*u.z + hs[k+3]*u.w;
  }
  float h2 = gelu_exact(acc2);
  float p = h2 * W2[h];
  #pragma unroll
  for (int o=32;o;o>>=1) p += __shfl_down(p, o);
  if (h==0){
    float s = p + b2[0];
    weight[inst] = 1.f/(1.f+expf(-s));
  }
}

// ---------------------------------------------------------------------------
// Compaction: per batch, build ascending list of valid seq positions.
// slot 0 = cls (pos 0); then all instances n with branch-validity (pos n+1).
// idx[b*S_TOT + slot] = seq position; cnt[b] = #valid (incl cls).
// ---------------------------------------------------------------------------
__global__ __launch_bounds__(256) void compact_kernel(
    const float* __restrict__ weight, int branch,
    int* __restrict__ idx, int* __restrict__ cnt) {
  int b = blockIdx.x;
  int t = threadIdx.x;
  int lane = t & 63, wv = t >> 6;
  __shared__ int wsum[4];
  __shared__ int base_s;
  if (t==0){ idx[b*S_TOT] = 0; base_s = 1; }
  __syncthreads();
  for (int c0=0; c0<N_INST; c0+=256){
    int n = c0 + t;
    float w = weight[b*N_INST + n];
    bool neg = (w < 0.5f);
    bool val = (branch==0) ? neg : !neg;
    unsigned long long m = __ballot(val);
    int prefix = __popcll(m & ((1ull<<lane)-1ull));
    if (lane==0) wsum[wv] = __popcll(m);
    __syncthreads();                                   // A
    int wbase = 0;
    #pragma unroll
    for (int i=0;i<4;i++) if (i<wv) wbase += wsum[i];
    int total = wsum[0]+wsum[1]+wsum[2]+wsum[3];
    int mybase = base_s;
    if (val) idx[b*S_TOT + mybase + wbase + prefix] = n + 1;
    __syncthreads();                                   // B
    if (t==0) base_s += total;
    __syncthreads();                                   // C
  }
  if (t==0) cnt[b] = base_s;
}

// ---------------------------------------------------------------------------
// Build compacted z: Z[b,slot,:] = LN(scale * seq[idx[b,slot]]).
// one block per (b,slot) row; early exit past cnt.
// ---------------------------------------------------------------------------
__global__ __launch_bounds__(256) void build_z_kernel(
    const float* __restrict__ x, const float* __restrict__ weight,
    const float* __restrict__ cls, const float* __restrict__ g, const float* __restrict__ be,
    int branch, const int* __restrict__ idx, const int* __restrict__ cnt,
    float* __restrict__ Z) {
  int row = blockIdx.x;
  int b = row / S_TOT, slot = row % S_TOT;
  if (slot >= cnt[b]) return;
  int t = threadIdx.x;
  __shared__ float v[512];
  __shared__ float red[16];
  int pos = idx[b*S_TOT + slot];
  float scale = 1.f;
  const float* src = cls;
  if (pos != 0){
    float w = weight[b*N_INST + (pos-1)];
    scale = (branch==0) ? powf(w, 1.5f) : powf(w, 2.0f/3.0f);
    src = x + ((size_t)b*N_INST + (pos-1))*D_MODEL;
  }
  float s1=0.f, s2=0.f;
  for (int i=t;i<512;i+=256){
    float val = src[i];
    if (pos != 0) val *= scale;
    v[i]=val; s1+=val; s2+=val*val;
  }
  __syncthreads();
  #pragma unroll
  for (int o=32;o;o>>=1){ s1+=__shfl_down(s1,o); s2+=__shfl_down(s2,o); }
  if ((t&63)==0){ red[t>>6]=s1; red[8+(t>>6)]=s2; }
  __syncthreads();
  s1 = red[0]+red[1]+red[2]+red[3];
  s2 = red[8]+red[9]+red[10]+red[11];
  float mean = s1 * (1.f/512.f);
  float var  = s2 * (1.f/512.f) - mean*mean;
  float rn = rsqrtf(var + 1e-5f);
  float* zr = Z + (size_t)row*D_MODEL;
  for (int i=t;i<512;i+=256)
    zr[i] = (v[i]-mean)*rn*g[i] + be[i];
}

// out = LN(Z + X) rowwise, compaction-gated
__global__ __launch_bounds__(256) void add_ln_kernel(
    const float* __restrict__ Zb, const float* __restrict__ Xb,
    const float* __restrict__ g, const float* __restrict__ be,
    const int* __restrict__ cnt, float* __restrict__ outb) {
  int row = blockIdx.x;
  if ((row % S_TOT) >= cnt[row / S_TOT]) return;
  int t = threadIdx.x;
  __shared__ float v[512];
  __shared__ float red[16];
  const float* zr = Zb + (size_t)row*512;
  const float* xr = Xb + (size_t)row*512;
  float s1=0.f, s2=0.f;
  for (int i=t;i<512;i+=256){
    float val = zr[i] + xr[i];
    v[i]=val; s1+=val; s2+=val*val;
  }
  __syncthreads();
  #pragma unroll
  for (int o=32;o;o>>=1){ s1+=__shfl_down(s1,o); s2+=__shfl_down(s2,o); }
  if ((t&63)==0){ red[t>>6]=s1; red[8+(t>>6)]=s2; }
  __syncthreads();
  s1 = red[0]+red[1]+red[2]+red[3];
  s2 = red[8]+red[9]+red[10]+red[11];
  float mean = s1 * (1.f/512.f);
  float var  = s2 * (1.f/512.f) - mean*mean;
  float rn = rsqrtf(var + 1e-5f);
  float* orow = outb + (size_t)row*512;
  for (int i=t;i<512;i+=256)
    orow[i] = (v[i]-mean)*rn*g[i] + be[i];
}

// ---------------------------------------------------------------------------
// fp32 GEMM: C[M,N] = A[M,K] @ W[N,K]^T + bias[N]. Rows gated by cnt[] (per
// batch compaction); whole-tile early exit when no row valid.
// ---------------------------------------------------------------------------
__global__ __launch_bounds__(256) void gemm_bias_kernel(
    const float* __restrict__ A, const float* __restrict__ W,
    const float* __restrict__ bias, float* __restrict__ C,
    int M, int N, int K, const int* __restrict__ cnt) {
  int t = threadIdx.x;
  int bm = blockIdx.y*64, bn = blockIdx.x*64;
  int tx = t & 15, ty = t >> 4;
  int lr = t >> 2, lc = t & 3;
  int arow = bm + lr;
  bool aok = arow < M;
  if (aok) aok = (arow % S_TOT) < cnt[arow / S_TOT];
  if (__syncthreads_or(aok ? 1 : 0) == 0) return;

  __shared__ __align__(16) float As[64][20];
  __shared__ __align__(16) float Ws[64][20];
  const float* Arow = A + (size_t)arow*K;
  const float* Wrow = W + (size_t)(bn+lr)*K;
  float c[4][4];
  #pragma unroll
  for (int i=0;i<4;i++)
    #pragma unroll
    for (int j=0;j<4;j++) c[i][j]=0.f;

  for (int k0=0;k0<K;k0+=16){
    __syncthreads();
    float4 av = make_float4(0.f,0.f,0.f,0.f);
    if (aok) av = *(const float4*)(Arow + k0 + lc*4);
    *(float4*)&As[lr][lc*4] = av;
    float4 wv = *(const float4*)(Wrow + k0 + lc*4);
    *(float4*)&Ws[lr][lc*4] = wv;
    __syncthreads();
    #pragma unroll
    for (int kq=0;kq<4;kq++){
      float4 a[4], w[4];
      #pragma unroll
      for (int i=0;i<4;i++) a[i] = *(const float4*)&As[ty+16*i][kq*4];
      #pragma unroll
      for (int j=0;j<4;j++) w[j] = *(const float4*)&Ws[tx+16*j][kq*4];
      #pragma unroll
      for (int i=0;i<4;i++)
        #pragma unroll
        for (int j=0;j<4;j++)
          c[i][j] += a[i].x*w[j].x + a[i].y*w[j].y + a[i].z*w[j].z + a[i].w*w[j].w;
    }
  }
  float bv[4];
  #pragma unroll
  for (int j=0;j<4;j++) bv[j] = bias[bn+tx+16*j];
  #pragma unroll
  for (int i=0;i<4;i++){
    int m = bm+ty+16*i;
    bool ok = (m < M) && ((m % S_TOT) < cnt[m / S_TOT]);
    if (ok){
      #pragma unroll
      for (int j=0;j<4;j++)
        C[(size_t)m*N + bn + tx + 16*j] = c[i][j] + bv[j];
    }
  }
}

// ---------------------------------------------------------------------------
// Flash attention over compacted queries/keys (layer 0). Block = (qtile, h, b).
// thread = (query q, key-group r of 16 keys). All compacted keys are valid;
// only the tail of the last tile needs masking.
// ---------------------------------------------------------------------------
__global__ __launch_bounds__(256) void flash_attn_kernel(
    const float* __restrict__ qkv, const int* __restrict__ cnt,
    float* __restrict__ out) {
  int b = blockIdx.z, h = blockIdx.y;
  int cb = cnt[b];
  int S0 = blockIdx.x * 64;
  if (S0 >= cb) return;
  int t = threadIdx.x;
  int q = t & 63, r = t >> 6;
  __shared__ __align__(16) float Ks[64][68];
  __shared__ __align__(16) float Vs[64][68];
  __shared__ float bias_s[64];
  __shared__ float redm[4][64];
  __shared__ float redl[4][64];
  int qs = S0 + q;
  const float* qptr = qkv + ((size_t)(b*S_TOT) + (qs < cb ? qs : 0))*1536 + h*64;
  float4 qreg[16];
  #pragma unroll
  for (int i=0;i<16;i++){
    float4 u = *(const float4*)(qptr + i*4);
    u.x*=0.125f; u.y*=0.125f; u.z*=0.125f; u.w*=0.125f;
    qreg[i]=u;
  }
  float m_run = -1e30f, l_part = 0.f;
  float4 O[16];
  #pragma unroll
  for (int i=0;i<16;i++) O[i] = make_float4(0.f,0.f,0.f,0.f);

  const int nt = (cb + 63)/64;
  int lr = t >> 2, lc = t & 3;
  for (int kt=0; kt<nt; kt++){
    int K0 = kt*64;
    __syncthreads();
    {
      int key = K0 + lr;
      bool ok = key < cb;
      const float* kp = qkv + ((size_t)(b*S_TOT) + (ok?key:0))*1536 + 512 + h*64;
      #pragma unroll
      for (int ii=0; ii<4; ii++){
        int cc = lc + ii*4;
        float4 kv = ok ? *(const float4*)(kp + cc*4)        : make_float4(0.f,0.f,0.f,0.f);
        float4 vv = ok ? *(const float4*)(kp + 512 + cc*4)  : make_float4(0.f,0.f,0.f,0.f);
        *(float4*)&Ks[lr][cc*4] = kv;
        *(float4*)&Vs[lr][cc*4] = vv;
      }
      if (t < 64) bias_s[t] = (K0+t < cb) ? 0.f : -1e9f;
    }
    __syncthreads();
    float p[16];
    float tmax = -1e30f;
    #pragma unroll
    for (int jj=0;jj<16;jj++){
      int kk = r*16 + jj;
      float s = 0.f;
      #pragma unroll
      for (int d4=0; d4<16; d4++){
        float4 kv = *(const float4*)&Ks[kk][d4*4];
        s += qreg[d4].x*kv.x + qreg[d4].y*kv.y + qreg[d4].z*kv.z + qreg[d4].w*kv.w;
      }
      s += bias_s[kk];
      p[jj] = s;
      tmax = fmaxf(tmax, s);
    }
    redm[r][q] = tmax;
    __syncthreads();
    float m_new = fmaxf(m_run, fmaxf(fmaxf(redm[0][q], redm[1][q]),
                                     fmaxf(redm[2][q], redm[3][q])));
    float alpha = expf(m_run - m_new);
    float psum = 0.f;
    #pragma unroll
    for (int jj=0;jj<16;jj++){
      float pv = expf(p[jj] - m_new);
      p[jj] = pv; psum += pv;
    }
    l_part = l_part*alpha + psum;
    #pragma unroll
    for (int d4=0; d4<16; d4++){
      float4 o = O[d4];
      o.x*=alpha; o.y*=alpha; o.z*=alpha; o.w*=alpha;
      #pragma unroll
      for (int jj=0;jj<16;jj++){
        float4 v4 = *(const float4*)&Vs[r*16+jj][d4*4];
        float pv = p[jj];
        o.x += pv*v4.x; o.y += pv*v4.y; o.z += pv*v4.z; o.w += pv*v4.w;
      }
      O[d4]=o;
    }
    m_run = m_new;
  }
  redl[r][q] = l_part;
  __syncthreads();
  float l = redl[0][q]+redl[1][q]+redl[2][q]+redl[3][q];
  // combine O partials across r-groups in LDS (reuse Ks)
  #pragma unroll 1
  for (int rr=0; rr<4; rr++){
    if (r == rr){
      #pragma unroll
      for (int d4=0; d4<16; d4++){
        if (rr==0){ *(float4*)&Ks[q][d4*4] = O[d4]; }
        else {
          float4 cur = *(const float4*)&Ks[q][d4*4];
          cur.x+=O[d4].x; cur.y+=O[d4].y; cur.z+=O[d4].z; cur.w+=O[d4].w;
          *(float4*)&Ks[q][d4*4] = cur;
        }
      }
    }
    __syncthreads();
  }
  if (qs < cb){
    float inv = 1.f/l;
    float* op = out + ((size_t)(b*S_TOT) + qs)*512 + h*64 + r*16;
    #pragma unroll
    for (int d4=0; d4<4; d4++){
      float4 o = *(const float4*)&Ks[q][r*16 + d4*4];
      o.x*=inv; o.y*=inv; o.z*=inv; o.w*=inv;
      *(float4*)(op + d4*4) = o;
    }
  }
}

// ---------------------------------------------------------------------------
// Layer-1 attention, query 0 only, over compacted keys. Block per (h,b).
// ---------------------------------------------------------------------------
__global__ __launch_bounds__(256) void attn_row0_kernel(
    const float* __restrict__ qkv, const int* __restrict__ cnt,
    float* __restrict__ out0) {
  int h = blockIdx.x, b = blockIdx.y;
  int cb = cnt[b];
  int t = threadIdx.x;
  __shared__ float qs[64];
  __shared__ float sc[S_TOT];
  __shared__ float red[8];
  __shared__ float redO[4][64];
  const float* base = qkv + (size_t)b*S_TOT*1536;
  if (t < 64) qs[t] = base[h*64 + t]*0.125f;
  __syncthreads();
  float lmax = -1e30f;
  for (int j=t; j<cb; j+=256){
    const float* kp = base + (size_t)j*1536 + 512 + h*64;
    float s = 0.f;
    #pragma unroll
    for (int d4=0; d4<16; d4++){
      float4 kv = *(const float4*)(kp + d4*4);
      s += qs[d4*4+0]*kv.x + qs[d4*4+1]*kv.y + qs[d4*4+2]*kv.z + qs[d4*4+3]*kv.w;
    }
    sc[j]=s;
    lmax = fmaxf(lmax, s);
  }
  #pragma unroll
  for (int o=32;o;o>>=1) lmax = fmaxf(lmax, __shfl_down(lmax, o));
  if ((t&63)==0) red[t>>6]=lmax;
  __syncthreads();
  float m = fmaxf(fmaxf(red[0],red[1]),fmaxf(red[2],red[3]));
  float lsum = 0.f;
  for (int j=t;j<cb;j+=256){
    float p = expf(sc[j]-m);
    sc[j]=p; lsum+=p;
  }
  #pragma unroll
  for (int o=32;o;o>>=1) lsum += __shfl_down(lsum,o);
  __syncthreads();
  if ((t&63)==0) red[t>>6]=lsum;
  __syncthreads();
  float l = red[0]+red[1]+red[2]+red[3];
  int d = t & 63, rr = t >> 6;
  float acc = 0.f;
  for (int j=rr; j<cb; j+=4)
    acc += sc[j]*base[(size_t)j*1536 + 1024 + h*64 + d];
  redO[rr][d]=acc;
  __syncthreads();
  if (t < 64){
    float o = (redO[0][t]+redO[1][t]+redO[2][t]+redO[3][t])/l;
    out0[b*512 + h*64 + t] = o;
  }
}

// layer-1 out-proj for row 0 + residual(z row0) + LN -> cls embedding slot
__global__ __launch_bounds__(256) void row0_proj_ln_kernel(
    const float* __restrict__ attn0, const float* __restrict__ Wo, const float* __restrict__ bo,
    const float* __restrict__ Z, const float* __restrict__ g, const float* __restrict__ be,
    float* __restrict__ clsbuf, int branch) {
  int b = blockIdx.x, t = threadIdx.x;
  __shared__ float xin[512];
  __shared__ float y[512];
  __shared__ float red[16];
  for (int i=t;i<512;i+=256) xin[i] = attn0[b*512+i];
  __syncthreads();
  for (int n=t;n<512;n+=256){
    const float4* wr = (const float4*)(Wo + (size_t)n*512);
    float acc = bo[n];
    for (int k4=0;k4<128;k4++){
      float4 u = wr[k4]; int k=k4*4;
      acc += xin[k+0]*u.x + xin[k+1]*u.y + xin[k+2]*u.z + xin[k+3]*u.w;
    }
    y[n] = acc + Z[(size_t)b*S_TOT*512 + n];
  }
  __syncthreads();
  float s1=0.f, s2=0.f;
  for (int i=t;i<512;i+=256){ float a=y[i]; s1+=a; s2+=a*a; }
  #pragma unroll
  for (int o=32;o;o>>=1){ s1+=__shfl_down(s1,o); s2+=__shfl_down(s2,o); }
  if ((t&63)==0){ red[t>>6]=s1; red[8+(t>>6)]=s2; }
  __syncthreads();
  s1 = red[0]+red[1]+red[2]+red[3];
  s2 = red[8]+red[9]+red[10]+red[11];
  float mean = s1*(1.f/512.f);
  float var  = s2*(1.f/512.f) - mean*mean;
  float rn = rsqrtf(var + 1e-5f);
  for (int i=t;i<512;i+=256)
    clsbuf[b*1024 + branch*512 + i] = (y[i]-mean)*rn*g[i] + be[i];
}

// final projection MLP: [B,1024] -> 512 gelu -> 512 gelu -> 512, fp32 out
__global__ __launch_bounds__(256) void final_mlp_kernel(
    const float* __restrict__ emb,
    const float* __restrict__ W0, const float* __restrict__ b0,
    const float* __restrict__ W1, const float* __restrict__ b1,
    const float* __restrict__ W2, const float* __restrict__ b2,
    float* __restrict__ outp) {
  int b = blockIdx.x, t = threadIdx.x;
  __shared__ float e[1024];
  __shared__ float h1[512];
  __shared__ float h2[512];
  for (int i=t;i<1024;i+=256) e[i]=emb[b*1024+i];
  __syncthreads();
  for (int n=t;n<512;n+=256){
    const float4* w = (const float4*)(W0 + (size_t)n*1024);
    float acc = b0[n];
    for (int k4=0;k4<256;k4++){
      float4 u = w[k4]; int k=k4*4;
      acc += e[k+0]*u.x + e[k+1]*u.y + e[k+2]*u.z + e[k+3]*u.w;
    }
    h1[n]=gelu_exact(acc);
  }
  __syncthreads();
  for (int n=t;n<512;n+=256){
    const float4* w = (const float4*)(W1 + (size_t)n*512);
    float acc = b1[n];
    for (int k4=0;k4<128;k4++){
      float4 u = w[k4]; int k=k4*4;
      acc += h1[k+0]*u.x + h1[k+1]*u.y + h1[k+2]*u.z + h1[k+3]*u.w;
    }
    h2[n]=gelu_exact(acc);
  }
  __syncthreads();
  for (int n=t;n<512;n+=256){
    const float4* w = (const float4*)(W2 + (size_t)n*512);
    float acc = b2[n];
    for (int k4=0;k4<128;k4++){
      float4 u = w[k4]; int k=k4*4;
      acc += h2[k+0]*u.x + h2[k+1]*u.y + h2[k+2]*u.z + h2[k+3]*u.w;
    }
    outp[b*512+n] = acc;
  }
}

// ---------------------------------------------------------------------------
extern "C" void kernel_launch(void* const* d_in, const int* in_sizes, int n_in,
                              void* d_out, int out_size, void* d_ws, size_t ws_size,
                              hipStream_t stream) {
  const float* x      = (const float*)d_in[0];
  const float* cls_tk = (const float*)d_in[1];
  const float* ln_g   = (const float*)d_in[2];
  const float* ln_b   = (const float*)d_in[3];
  const float* aw_W0  = (const float*)d_in[4];  const float* aw_b0 = (const float*)d_in[5];
  const float* aw_W1  = (const float*)d_in[6];  const float* aw_b1 = (const float*)d_in[7];
  const float* aw_W2  = (const float*)d_in[8];  const float* aw_b2 = (const float*)d_in[9];
  const float* pr_W0  = (const float*)d_in[10]; const float* pr_b0 = (const float*)d_in[11];
  const float* pr_W1  = (const float*)d_in[12]; const float* pr_b1 = (const float*)d_in[13];
  const float* pr_W2  = (const float*)d_in[14]; const float* pr_b2 = (const float*)d_in[15];
  const float* mWqkv[2] = {(const float*)d_in[16], (const float*)d_in[20]};
  const float* mbqkv[2] = {(const float*)d_in[17], (const float*)d_in[21]};
  const float* mWo[2]   = {(const float*)d_in[18], (const float*)d_in[22]};
  const float* mbo[2]   = {(const float*)d_in[19], (const float*)d_in[23]};

  float* ws = (float*)d_ws;
  size_t off = 0;
  float* weight = ws + off; off += 8192;                 // [B,N]
  int*   idx    = (int*)(ws + off); off += 8448;         // [B,S] compacted seq positions
  int*   cnt    = (int*)(ws + off); off += 16;           // [B]
  float* Z      = ws + off; off += (size_t)ROWS*512;     // LN'd compacted seq (residual base)
  float* T1     = ws + off; off += (size_t)ROWS*512;     // attn out / a1
  float* QKV    = ws + off; off += (size_t)ROWS*1536;
  float* T2     = QKV;                                   // alias: out-proj result lives in
                                                         // dead QKV space
  float* attn0  = ws + off; off += 2048;                 // [B,D]
  float* clsb   = ws + off; off += 4096;                 // [B,2D] emb
  (void)ws_size; (void)in_sizes; (void)n_in; (void)out_size;

  aw_weight_kernel<<<B_SZ*N_INST, 64, 0, stream>>>(
      x, aw_W0, aw_b0, aw_W1, aw_b1, aw_W2, aw_b2, weight);

  for (int br=0; br<2; br++){
    compact_kernel<<<B_SZ, 256, 0, stream>>>(weight, br, idx, cnt);
    build_z_kernel<<<ROWS, 256, 0, stream>>>(x, weight, cls_tk, ln_g, ln_b, br, idx, cnt, Z);
    // layer 0 (all compacted rows)
    gemm_bias_kernel<<<dim3(1536/64, (ROWS+63)/64), 256, 0, stream>>>(
        Z, mWqkv[0], mbqkv[0], QKV, ROWS, 1536, 512, cnt);
    flash_attn_kernel<<<dim3((S_TOT+63)/64, NH, B_SZ), 256, 0, stream>>>(QKV, cnt, T1);
    gemm_bias_kernel<<<dim3(512/64, (ROWS+63)/64), 256, 0, stream>>>(
        T1, mWo[0], mbo[0], T2, ROWS, 512, 512, cnt);
    add_ln_kernel<<<ROWS, 256, 0, stream>>>(Z, T2, ln_g, ln_b, cnt, T1);
    // layer 1 (only row 0 of the output is consumed; keys = compacted rows)
    gemm_bias_kernel<<<dim3(1536/64, (ROWS+63)/64), 256, 0, stream>>>(
        T1, mWqkv[1], mbqkv[1], QKV, ROWS, 1536, 512, cnt);
    attn_row0_kernel<<<dim3(NH, B_SZ), 256, 0, stream>>>(QKV, cnt, attn0);
    row0_proj_ln_kernel<<<B_SZ, 256, 0, stream>>>(
        attn0, mWo[1], mbo[1], Z, ln_g, ln_b, clsb, br);
  }
  final_mlp_kernel<<<B_SZ, 256, 0, stream>>>(
      clsb, pr_W0, pr_b0, pr_W1, pr_b1, pr_W2, pr_b2, (float*)d_out);
}

// Round 4
// 1394.881 us; speedup vs baseline: 2.8473x; 1.4075x over previous
//
#include <hip/hip_runtime.h>
#include <hip/hip_bf16.h>

#define B_SZ 4
#define N_INST 2048
#define D_MODEL 512
#define S_TOT 2049          // N+1 (cls prepended)
#define NH 8
#define HD 64
#define ROWS (B_SZ*S_TOT)   // 8196

typedef __attribute__((ext_vector_type(4))) float f32x4;
typedef __attribute__((ext_vector_type(8))) short bf16x8;

__device__ __forceinline__ float gelu_exact(float x){ return 0.5f*x*(1.f+erff(x*0.70710678118654752f)); }
__device__ __forceinline__ unsigned short f2bf(float x){
  unsigned int u = __float_as_uint(x);
  u += 0x7fffu + ((u>>16)&1u);
  return (unsigned short)(u>>16);
}
__device__ __forceinline__ unsigned int pk2(unsigned short lo, unsigned short hi){
  return (unsigned int)lo | ((unsigned int)hi << 16);
}

// ---------------------------------------------------------------------------
// Gating MLP: weight[b,n] = sigmoid(MLP(x[b,n,:])), D->64(gelu)->64(gelu)->1
// ---------------------------------------------------------------------------
__global__ __launch_bounds__(64) void aw_weight_kernel(
    const float* __restrict__ x,
    const float* __restrict__ W0, const float* __restrict__ b0,
    const float* __restrict__ W1, const float* __restrict__ b1,
    const float* __restrict__ W2, const float* __restrict__ b2,
    float* __restrict__ weight) {
  int inst = blockIdx.x;
  int h = threadIdx.x;
  __shared__ float xs[512];
  __shared__ float hs[64];
  const float* xp = x + (size_t)inst*D_MODEL;
  for (int i=h;i<512;i+=64) xs[i] = xp[i];
  __syncthreads();
  const float4* w0 = (const float4*)(W0 + (size_t)h*512);
  float acc = b0[h];
  #pragma unroll 8
  for (int k4=0;k4<128;k4++){
    float4 u = w0[k4]; int k = k4*4;
    acc += xs[k+0]*u.x + xs[k+1]*u.y + xs[k+2]*u.z + xs[k+3]*u.w;
  }
  hs[h] = gelu_exact(acc);
  __syncthreads();
  const float4* w1 = (const float4*)(W1 + (size_t)h*64);
  float acc2 = b1[h];
  #pragma unroll
  for (int k4=0;k4<16;k4++){
    float4 u = w1[k4]; int k = k4*4;
    acc2 += hs[k+0]*u.x + hs[k+1]*u.y + hs[k+2]*u.z + hs[k+3]*u.w;
  }
  float h2 = gelu_exact(acc2);
  float p = h2 * W2[h];
  #pragma unroll
  for (int o=32;o;o>>=1) p += __shfl_down(p, o);
  if (h==0){
    float s = p + b2[0];
    weight[inst] = 1.f/(1.f+expf(-s));
  }
}

// ---------------------------------------------------------------------------
// Compaction: per batch, ascending list of valid seq positions (slot0 = cls).
// ---------------------------------------------------------------------------
__global__ __launch_bounds__(256) void compact_kernel(
    const float* __restrict__ weight, int branch,
    int* __restrict__ idx, int* __restrict__ cnt) {
  int b = blockIdx.x;
  int t = threadIdx.x;
  int lane = t & 63, wv = t >> 6;
  __shared__ int wsum[4];
  __shared__ int base_s;
  if (t==0){ idx[b*S_TOT] = 0; base_s = 1; }
  __syncthreads();
  for (int c0=0; c0<N_INST; c0+=256){
    int n = c0 + t;
    float w = weight[b*N_INST + n];
    bool neg = (w < 0.5f);
    bool val = (branch==0) ? neg : !neg;
    unsigned long long m = __ballot(val);
    int prefix = __popcll(m & ((1ull<<lane)-1ull));
    if (lane==0) wsum[wv] = __popcll(m);
    __syncthreads();
    int wbase = 0;
    #pragma unroll
    for (int i=0;i<4;i++) if (i<wv) wbase += wsum[i];
    int total = wsum[0]+wsum[1]+wsum[2]+wsum[3];
    int mybase = base_s;
    if (val) idx[b*S_TOT + mybase + wbase + prefix] = n + 1;
    __syncthreads();
    if (t==0) base_s += total;
    __syncthreads();
  }
  if (t==0) cnt[b] = base_s;
}

// ---------------------------------------------------------------------------
// Build compacted z: Z[b,slot,:] = LN(scale * seq[idx[b,slot]]).
// ---------------------------------------------------------------------------
__global__ __launch_bounds__(256) void build_z_kernel(
    const float* __restrict__ x, const float* __restrict__ weight,
    const float* __restrict__ cls, const float* __restrict__ g, const float* __restrict__ be,
    int branch, const int* __restrict__ idx, const int* __restrict__ cnt,
    float* __restrict__ Z) {
  int row = blockIdx.x;
  int b = row / S_TOT, slot = row % S_TOT;
  if (slot >= cnt[b]) return;
  int t = threadIdx.x;
  __shared__ float v[512];
  __shared__ float red[16];
  int pos = idx[b*S_TOT + slot];
  float scale = 1.f;
  const float* src = cls;
  if (pos != 0){
    float w = weight[b*N_INST + (pos-1)];
    scale = (branch==0) ? powf(w, 1.5f) : powf(w, 2.0f/3.0f);
    src = x + ((size_t)b*N_INST + (pos-1))*D_MODEL;
  }
  float s1=0.f, s2=0.f;
  for (int i=t;i<512;i+=256){
    float val = src[i];
    if (pos != 0) val *= scale;
    v[i]=val; s1+=val; s2+=val*val;
  }
  __syncthreads();
  #pragma unroll
  for (int o=32;o;o>>=1){ s1+=__shfl_down(s1,o); s2+=__shfl_down(s2,o); }
  if ((t&63)==0){ red[t>>6]=s1; red[8+(t>>6)]=s2; }
  __syncthreads();
  s1 = red[0]+red[1]+red[2]+red[3];
  s2 = red[8]+red[9]+red[10]+red[11];
  float mean = s1 * (1.f/512.f);
  float var  = s2 * (1.f/512.f) - mean*mean;
  float rn = rsqrtf(var + 1e-5f);
  float* zr = Z + (size_t)row*D_MODEL;
  for (int i=t;i<512;i+=256)
    zr[i] = (v[i]-mean)*rn*g[i] + be[i];
}

// out = LN(Z + X) rowwise, compaction-gated
__global__ __launch_bounds__(256) void add_ln_kernel(
    const float* __restrict__ Zb, const float* __restrict__ Xb,
    const float* __restrict__ g, const float* __restrict__ be,
    const int* __restrict__ cnt, float* __restrict__ outb) {
  int row = blockIdx.x;
  if ((row % S_TOT) >= cnt[row / S_TOT]) return;
  int t = threadIdx.x;
  __shared__ float v[512];
  __shared__ float red[16];
  const float* zr = Zb + (size_t)row*512;
  const float* xr = Xb + (size_t)row*512;
  float s1=0.f, s2=0.f;
  for (int i=t;i<512;i+=256){
    float val = zr[i] + xr[i];
    v[i]=val; s1+=val; s2+=val*val;
  }
  __syncthreads();
  #pragma unroll
  for (int o=32;o;o>>=1){ s1+=__shfl_down(s1,o); s2+=__shfl_down(s2,o); }
  if ((t&63)==0){ red[t>>6]=s1; red[8+(t>>6)]=s2; }
  __syncthreads();
  s1 = red[0]+red[1]+red[2]+red[3];
  s2 = red[8]+red[9]+red[10]+red[11];
  float mean = s1 * (1.f/512.f);
  float var  = s2 * (1.f/512.f) - mean*mean;
  float rn = rsqrtf(var + 1e-5f);
  float* orow = outb + (size_t)row*512;
  for (int i=t;i<512;i+=256)
    orow[i] = (v[i]-mean)*rn*g[i] + be[i];
}

// ---------------------------------------------------------------------------
// fp32 GEMM: C[M,N] = A[M,K] @ W[N,K]^T + bias[N]; rows gated by cnt[].
// ---------------------------------------------------------------------------
__global__ __launch_bounds__(256) void gemm_bias_kernel(
    const float* __restrict__ A, const float* __restrict__ W,
    const float* __restrict__ bias, float* __restrict__ C,
    int M, int N, int K, const int* __restrict__ cnt) {
  int t = threadIdx.x;
  int bm = blockIdx.y*64, bn = blockIdx.x*64;
  int tx = t & 15, ty = t >> 4;
  int lr = t >> 2, lc = t & 3;
  int arow = bm + lr;
  bool aok = arow < M;
  if (aok) aok = (arow % S_TOT) < cnt[arow / S_TOT];
  if (__syncthreads_or(aok ? 1 : 0) == 0) return;

  __shared__ __align__(16) float As[64][20];
  __shared__ __align__(16) float Ws[64][20];
  const float* Arow = A + (size_t)arow*K;
  const float* Wrow = W + (size_t)(bn+lr)*K;
  float c[4][4];
  #pragma unroll
  for (int i=0;i<4;i++)
    #pragma unroll
    for (int j=0;j<4;j++) c[i][j]=0.f;

  for (int k0=0;k0<K;k0+=16){
    __syncthreads();
    float4 av = make_float4(0.f,0.f,0.f,0.f);
    if (aok) av = *(const float4*)(Arow + k0 + lc*4);
    *(float4*)&As[lr][lc*4] = av;
    float4 wv = *(const float4*)(Wrow + k0 + lc*4);
    *(float4*)&Ws[lr][lc*4] = wv;
    __syncthreads();
    #pragma unroll
    for (int kq=0;kq<4;kq++){
      float4 a[4], w[4];
      #pragma unroll
      for (int i=0;i<4;i++) a[i] = *(const float4*)&As[ty+16*i][kq*4];
      #pragma unroll
      for (int j=0;j<4;j++) w[j] = *(const float4*)&Ws[tx+16*j][kq*4];
      #pragma unroll
      for (int i=0;i<4;i++)
        #pragma unroll
        for (int j=0;j<4;j++)
          c[i][j] += a[i].x*w[j].x + a[i].y*w[j].y + a[i].z*w[j].z + a[i].w*w[j].w;
    }
  }
  float bv[4];
  #pragma unroll
  for (int j=0;j<4;j++) bv[j] = bias[bn+tx+16*j];
  #pragma unroll
  for (int i=0;i<4;i++){
    int m = bm+ty+16*i;
    bool ok = (m < M) && ((m % S_TOT) < cnt[m / S_TOT]);
    if (ok){
      #pragma unroll
      for (int j=0;j<4;j++)
        C[(size_t)m*N + bn + tx + 16*j] = c[i][j] + bv[j];
    }
  }
}

// ---------------------------------------------------------------------------
// MFMA flash attention (layer 0), compacted keys. Block = (q-tile 64, h, b);
// 4 waves, each owns 16 queries. Per k-tile (64 keys):
//   S^T = K·Q^T via mfma_16x16x32_bf16  (A=K from LDS, B=Q registers)
//   online softmax per column (q) via shfl_xor(16/32)
//   P -> per-wave LDS buffer (bf16, B-operand order)
//   O^T += V^T·P via mfma               (A=V^T staged transposed in LDS)
// All LDS arrays XOR-granule-swizzled (g ^= row&7) to kill bank conflicts.
// ---------------------------------------------------------------------------
__global__ __launch_bounds__(256) void flash_attn_kernel(
    const float* __restrict__ qkv, const int* __restrict__ cnt,
    float* __restrict__ out) {
  int b = blockIdx.z, h = blockIdx.y;
  int cb = cnt[b];
  int S0 = blockIdx.x * 64;
  if (S0 >= cb) return;
  int t = threadIdx.x;
  int lane = t & 63, w = t >> 6;
  int l15 = lane & 15, l4 = lane >> 4;

  __shared__ unsigned short Kbf[64*64];      // [key][d], granule-swizzled
  __shared__ unsigned short Vt[64*64];       // [d][key], granule-swizzled
  __shared__ unsigned short Pbuf[4][16*64];  // per-wave [q][key], granule-swizzled

  const float* basep = qkv + (size_t)(b*S_TOT)*1536;

  // Q fragments (B operand): lane holds Q[q=S0+w*16+l15][d=c*32+l4*8+j]*0.125
  int qg = S0 + w*16 + l15;
  int qr = (qg < cb) ? qg : 0;
  const float* qp = basep + (size_t)qr*1536 + h*64;
  bf16x8 Qf[2];
  #pragma unroll
  for (int c=0;c<2;c++){
    int d0 = c*32 + l4*8;
    float4 a = *(const float4*)(qp + d0);
    float4 bq = *(const float4*)(qp + d0 + 4);
    bf16x8 q8;
    q8[0]=(short)f2bf(a.x*0.125f);  q8[1]=(short)f2bf(a.y*0.125f);
    q8[2]=(short)f2bf(a.z*0.125f);  q8[3]=(short)f2bf(a.w*0.125f);
    q8[4]=(short)f2bf(bq.x*0.125f); q8[5]=(short)f2bf(bq.y*0.125f);
    q8[6]=(short)f2bf(bq.z*0.125f); q8[7]=(short)f2bf(bq.w*0.125f);
    Qf[c]=q8;
  }

  float m_run = -1e30f, l_run = 0.f;
  f32x4 accO[4];
  #pragma unroll
  for (int mt=0;mt<4;mt++) accO[mt] = (f32x4){0.f,0.f,0.f,0.f};

  unsigned int* Ku = (unsigned int*)Kbf;
  unsigned int* Vu = (unsigned int*)Vt;
  const int nt = (cb + 63)/64;
  for (int kt=0; kt<nt; kt++){
    int K0 = kt*64;
    __syncthreads();
    // ---- stage K rows -> Kbf[key][d] bf16 (thread: key=t>>2, dims (t&3)*16..+15)
    {
      int key = t>>2;
      int keyr = (K0+key < cb) ? (K0+key) : 0;
      const float* kp = basep + (size_t)keyr*1536 + 512 + h*64 + (t&3)*16;
      float4 x0 = *(const float4*)(kp);
      float4 x1 = *(const float4*)(kp+4);
      float4 x2 = *(const float4*)(kp+8);
      float4 x3 = *(const float4*)(kp+12);
      int g0 = (t&3)*2;
      int gs0 = g0 ^ (key&7), gs1 = (g0+1) ^ (key&7);
      uint4 pa, pb;
      pa.x = pk2(f2bf(x0.x), f2bf(x0.y)); pa.y = pk2(f2bf(x0.z), f2bf(x0.w));
      pa.z = pk2(f2bf(x1.x), f2bf(x1.y)); pa.w = pk2(f2bf(x1.z), f2bf(x1.w));
      pb.x = pk2(f2bf(x2.x), f2bf(x2.y)); pb.y = pk2(f2bf(x2.z), f2bf(x2.w));
      pb.z = pk2(f2bf(x3.x), f2bf(x3.y)); pb.w = pk2(f2bf(x3.z), f2bf(x3.w));
      *(uint4*)(Ku + key*32 + gs0*4) = pa;
      *(uint4*)(Ku + key*32 + gs1*4) = pb;
    }
    // ---- stage V transposed -> Vt[d][key] bf16 (thread: keys 2kp,2kp+1; dims d8*8..+7)
    {
      int kp2 = t & 31;
      int d8 = t >> 5;
      int k0g = K0 + 2*kp2;
      int kr0 = (k0g   < cb) ? k0g   : 0;
      int kr1 = (k0g+1 < cb) ? k0g+1 : 0;
      const float* vp0 = basep + (size_t)kr0*1536 + 1024 + h*64 + d8*8;
      const float* vp1 = basep + (size_t)kr1*1536 + 1024 + h*64 + d8*8;
      float4 a0 = *(const float4*)(vp0);
      float4 a1 = *(const float4*)(vp0+4);
      float4 b0 = *(const float4*)(vp1);
      float4 b1 = *(const float4*)(vp1+4);
      float r0[8] = {a0.x,a0.y,a0.z,a0.w,a1.x,a1.y,a1.z,a1.w};
      float r1[8] = {b0.x,b0.y,b0.z,b0.w,b1.x,b1.y,b1.z,b1.w};
      int k8 = kp2 >> 2;
      #pragma unroll
      for (int dd=0; dd<8; dd++){
        int d = d8*8 + dd;
        Vu[d*32 + (k8 ^ (d&7))*4 + (kp2&3)] = pk2(f2bf(r0[dd]), f2bf(r1[dd]));
      }
    }
    __syncthreads();

    // ---- S^T = K·Q^T : acc[mt] is 16key x 16q tile (keys mt*16..+15)
    f32x4 acc[4];
    #pragma unroll
    for (int mt=0;mt<4;mt++) acc[mt] = (f32x4){0.f,0.f,0.f,0.f};
    #pragma unroll
    for (int mt=0;mt<4;mt++){
      int row = mt*16 + l15;
      #pragma unroll
      for (int c=0;c<2;c++){
        int gs = (c*4 + l4) ^ (row & 7);
        bf16x8 kf = *(const bf16x8*)&Kbf[row*64 + gs*8];
        acc[mt] = __builtin_amdgcn_mfma_f32_16x16x32_bf16(kf, Qf[c], acc[mt], 0,0,0);
      }
    }
    // ---- online softmax per column q=l15 (lane holds keys mt*16+l4*4+r)
    float p[4][4];
    float tmax = -1e30f;
    #pragma unroll
    for (int mt=0;mt<4;mt++)
      #pragma unroll
      for (int r=0;r<4;r++){
        int key = K0 + mt*16 + l4*4 + r;
        float s = (key < cb) ? acc[mt][r] : -1e30f;
        p[mt][r] = s;
        tmax = fmaxf(tmax, s);
      }
    tmax = fmaxf(tmax, __shfl_xor(tmax, 16));
    tmax = fmaxf(tmax, __shfl_xor(tmax, 32));
    float m_new = fmaxf(m_run, tmax);
    float alpha = __expf(m_run - m_new);
    float psum = 0.f;
    #pragma unroll
    for (int mt=0;mt<4;mt++)
      #pragma unroll
      for (int r=0;r<4;r++){
        float pv = __expf(p[mt][r] - m_new);
        p[mt][r] = pv; psum += pv;
      }
    psum += __shfl_xor(psum, 16);
    psum += __shfl_xor(psum, 32);
    l_run = l_run*alpha + psum;
    m_run = m_new;

    // ---- write P -> Pbuf[q][key] bf16 (granule-swizzled by q&7)
    #pragma unroll
    for (int mt=0;mt<4;mt++){
      int keyl = mt*16 + l4*4;
      int gs = (keyl >> 3) ^ (l15 & 7);
      uint2 w2;
      w2.x = pk2(f2bf(p[mt][0]), f2bf(p[mt][1]));
      w2.y = pk2(f2bf(p[mt][2]), f2bf(p[mt][3]));
      *(uint2*)&Pbuf[w][ l15*64 + gs*8 + (keyl & 7) ] = w2;
    }
    // ---- rescale O, then O^T += V^T·P
    #pragma unroll
    for (int mt=0;mt<4;mt++){
      accO[mt][0]*=alpha; accO[mt][1]*=alpha; accO[mt][2]*=alpha; accO[mt][3]*=alpha;
    }
    #pragma unroll
    for (int c2=0;c2<2;c2++){
      int gp = (c2*4 + l4) ^ (l15 & 7);
      bf16x8 pf = *(const bf16x8*)&Pbuf[w][ l15*64 + gp*8 ];
      #pragma unroll
      for (int mt=0;mt<4;mt++){
        int d = mt*16 + l15;
        int gv = (c2*4 + l4) ^ (d & 7);
        bf16x8 vf = *(const bf16x8*)&Vt[ d*64 + gv*8 ];
        accO[mt] = __builtin_amdgcn_mfma_f32_16x16x32_bf16(vf, pf, accO[mt], 0,0,0);
      }
    }
  }
  // ---- epilogue: O[q][d] = accO^T / l_run ; lane q=l15, d=mt*16+l4*4+r
  if (qg < cb){
    float inv = 1.f/l_run;
    float* op = out + ((size_t)(b*S_TOT) + qg)*512 + h*64;
    #pragma unroll
    for (int mt=0;mt<4;mt++){
      float4 o;
      o.x = accO[mt][0]*inv; o.y = accO[mt][1]*inv;
      o.z = accO[mt][2]*inv; o.w = accO[mt][3]*inv;
      *(float4*)(op + mt*16 + l4*4) = o;
    }
  }
}

// ---------------------------------------------------------------------------
// Layer-1 attention, query 0 only, over compacted keys. Block per (h,b).
// ---------------------------------------------------------------------------
__global__ __launch_bounds__(256) void attn_row0_kernel(
    const float* __restrict__ qkv, const int* __restrict__ cnt,
    float* __restrict__ out0) {
  int h = blockIdx.x, b = blockIdx.y;
  int cb = cnt[b];
  int t = threadIdx.x;
  __shared__ float qs[64];
  __shared__ float sc[S_TOT];
  __shared__ float red[8];
  __shared__ float redO[4][64];
  const float* base = qkv + (size_t)b*S_TOT*1536;
  if (t < 64) qs[t] = base[h*64 + t]*0.125f;
  __syncthreads();
  float lmax = -1e30f;
  for (int j=t; j<cb; j+=256){
    const float* kp = base + (size_t)j*1536 + 512 + h*64;
    float s = 0.f;
    #pragma unroll
    for (int d4=0; d4<16; d4++){
      float4 kv = *(const float4*)(kp + d4*4);
      s += qs[d4*4+0]*kv.x + qs[d4*4+1]*kv.y + qs[d4*4+2]*kv.z + qs[d4*4+3]*kv.w;
    }
    sc[j]=s;
    lmax = fmaxf(lmax, s);
  }
  #pragma unroll
  for (int o=32;o;o>>=1) lmax = fmaxf(lmax, __shfl_down(lmax, o));
  if ((t&63)==0) red[t>>6]=lmax;
  __syncthreads();
  float m = fmaxf(fmaxf(red[0],red[1]),fmaxf(red[2],red[3]));
  float lsum = 0.f;
  for (int j=t;j<cb;j+=256){
    float p = expf(sc[j]-m);
    sc[j]=p; lsum+=p;
  }
  #pragma unroll
  for (int o=32;o;o>>=1) lsum += __shfl_down(lsum,o);
  __syncthreads();
  if ((t&63)==0) red[t>>6]=lsum;
  __syncthreads();
  float l = red[0]+red[1]+red[2]+red[3];
  int d = t & 63, rr = t >> 6;
  float acc = 0.f;
  for (int j=rr; j<cb; j+=4)
    acc += sc[j]*base[(size_t)j*1536 + 1024 + h*64 + d];
  redO[rr][d]=acc;
  __syncthreads();
  if (t < 64){
    float o = (redO[0][t]+redO[1][t]+redO[2][t]+redO[3][t])/l;
    out0[b*512 + h*64 + t] = o;
  }
}

// layer-1 out-proj for row 0 + residual(z row0) + LN -> cls embedding slot
__global__ __launch_bounds__(256) void row0_proj_ln_kernel(
    const float* __restrict__ attn0, const float* __restrict__ Wo, const float* __restrict__ bo,
    const float* __restrict__ Z, const float* __restrict__ g, const float* __restrict__ be,
    float* __restrict__ clsbuf, int branch) {
  int b = blockIdx.x, t = threadIdx.x;
  __shared__ float xin[512];
  __shared__ float y[512];
  __shared__ float red[16];
  for (int i=t;i<512;i+=256) xin[i] = attn0[b*512+i];
  __syncthreads();
  for (int n=t;n<512;n+=256){
    const float4* wr = (const float4*)(Wo + (size_t)n*512);
    float acc = bo[n];
    for (int k4=0;k4<128;k4++){
      float4 u = wr[k4]; int k=k4*4;
      acc += xin[k+0]*u.x + xin[k+1]*u.y + xin[k+2]*u.z + xin[k+3]*u.w;
    }
    y[n] = acc + Z[(size_t)b*S_TOT*512 + n];
  }
  __syncthreads();
  float s1=0.f, s2=0.f;
  for (int i=t;i<512;i+=256){ float a=y[i]; s1+=a; s2+=a*a; }
  #pragma unroll
  for (int o=32;o;o>>=1){ s1+=__shfl_down(s1,o); s2+=__shfl_down(s2,o); }
  if ((t&63)==0){ red[t>>6]=s1; red[8+(t>>6)]=s2; }
  __syncthreads();
  s1 = red[0]+red[1]+red[2]+red[3];
  s2 = red[8]+red[9]+red[10]+red[11];
  float mean = s1*(1.f/512.f);
  float var  = s2*(1.f/512.f) - mean*mean;
  float rn = rsqrtf(var + 1e-5f);
  for (int i=t;i<512;i+=256)
    clsbuf[b*1024 + branch*512 + i] = (y[i]-mean)*rn*g[i] + be[i];
}

// final projection MLP: [B,1024] -> 512 gelu -> 512 gelu -> 512, fp32 out
__global__ __launch_bounds__(256) void final_mlp_kernel(
    const float* __restrict__ emb,
    const float* __restrict__ W0, const float* __restrict__ b0,
    const float* __restrict__ W1, const float* __restrict__ b1,
    const float* __restrict__ W2, const float* __restrict__ b2,
    float* __restrict__ outp) {
  int b = blockIdx.x, t = threadIdx.x;
  __shared__ float e[1024];
  __shared__ float h1[512];
  __shared__ float h2[512];
  for (int i=t;i<1024;i+=256) e[i]=emb[b*1024+i];
  __syncthreads();
  for (int n=t;n<512;n+=256){
    const float4* w = (const float4*)(W0 + (size_t)n*1024);
    float acc = b0[n];
    for (int k4=0;k4<256;k4++){
      float4 u = w[k4]; int k=k4*4;
      acc += e[k+0]*u.x + e[k+1]*u.y + e[k+2]*u.z + e[k+3]*u.w;
    }
    h1[n]=gelu_exact(acc);
  }
  __syncthreads();
  for (int n=t;n<512;n+=256){
    const float4* w = (const float4*)(W1 + (size_t)n*512);
    float acc = b1[n];
    for (int k4=0;k4<128;k4++){
      float4 u = w[k4]; int k=k4*4;
      acc += h1[k+0]*u.x + h1[k+1]*u.y + h1[k+2]*u.z + h1[k+3]*u.w;
    }
    h2[n]=gelu_exact(acc);
  }
  __syncthreads();
  for (int n=t;n<512;n+=256){
    const float4* w = (const float4*)(W2 + (size_t)n*512);
    float acc = b2[n];
    for (int k4=0;k4<128;k4++){
      float4 u = w[k4]; int k=k4*4;
      acc += h2[k+0]*u.x + h2[k+1]*u.y + h2[k+2]*u.z + h2[k+3]*u.w;
    }
    outp[b*512+n] = acc;
  }
}

// ---------------------------------------------------------------------------
extern "C" void kernel_launch(void* const* d_in, const int* in_sizes, int n_in,
                              void* d_out, int out_size, void* d_ws, size_t ws_size,
                              hipStream_t stream) {
  const float* x      = (const float*)d_in[0];
  const float* cls_tk = (const float*)d_in[1];
  const float* ln_g   = (const float*)d_in[2];
  const float* ln_b   = (const float*)d_in[3];
  const float* aw_W0  = (const float*)d_in[4];  const float* aw_b0 = (const float*)d_in[5];
  const float* aw_W1  = (const float*)d_in[6];  const float* aw_b1 = (const float*)d_in[7];
  const float* aw_W2  = (const float*)d_in[8];  const float* aw_b2 = (const float*)d_in[9];
  const float* pr_W0  = (const float*)d_in[10]; const float* pr_b0 = (const float*)d_in[11];
  const float* pr_W1  = (const float*)d_in[12]; const float* pr_b1 = (const float*)d_in[13];
  const float* pr_W2  = (const float*)d_in[14]; const float* pr_b2 = (const float*)d_in[15];
  const float* mWqkv[2] = {(const float*)d_in[16], (const float*)d_in[20]};
  const float* mbqkv[2] = {(const float*)d_in[17], (const float*)d_in[21]};
  const float* mWo[2]   = {(const float*)d_in[18], (const float*)d_in[22]};
  const float* mbo[2]   = {(const float*)d_in[19], (const float*)d_in[23]};

  float* ws = (float*)d_ws;
  size_t off = 0;
  float* weight = ws + off; off += 8192;                 // [B,N]
  int*   idx    = (int*)(ws + off); off += 8448;         // [B,S] compacted seq positions
  int*   cnt    = (int*)(ws + off); off += 16;           // [B]
  float* Z      = ws + off; off += (size_t)ROWS*512;     // LN'd compacted seq (residual base)
  float* T1     = ws + off; off += (size_t)ROWS*512;     // attn out / a1
  float* QKV    = ws + off; off += (size_t)ROWS*1536;
  float* T2     = QKV;                                   // alias: out-proj result in dead QKV space
  float* attn0  = ws + off; off += 2048;                 // [B,D]
  float* clsb   = ws + off; off += 4096;                 // [B,2D] emb
  (void)ws_size; (void)in_sizes; (void)n_in; (void)out_size;

  aw_weight_kernel<<<B_SZ*N_INST, 64, 0, stream>>>(
      x, aw_W0, aw_b0, aw_W1, aw_b1, aw_W2, aw_b2, weight);

  for (int br=0; br<2; br++){
    compact_kernel<<<B_SZ, 256, 0, stream>>>(weight, br, idx, cnt);
    build_z_kernel<<<ROWS, 256, 0, stream>>>(x, weight, cls_tk, ln_g, ln_b, br, idx, cnt, Z);
    // layer 0 (all compacted rows)
    gemm_bias_kernel<<<dim3(1536/64, (ROWS+63)/64), 256, 0, stream>>>(
        Z, mWqkv[0], mbqkv[0], QKV, ROWS, 1536, 512, cnt);
    flash_attn_kernel<<<dim3((S_TOT+63)/64, NH, B_SZ), 256, 0, stream>>>(QKV, cnt, T1);
    gemm_bias_kernel<<<dim3(512/64, (ROWS+63)/64), 256, 0, stream>>>(
        T1, mWo[0], mbo[0], T2, ROWS, 512, 512, cnt);
    add_ln_kernel<<<ROWS, 256, 0, stream>>>(Z, T2, ln_g, ln_b, cnt, T1);
    // layer 1 (only row 0 consumed; keys = compacted rows)
    gemm_bias_kernel<<<dim3(1536/64, (ROWS+63)/64), 256, 0, stream>>>(
        T1, mWqkv[1], mbqkv[1], QKV, ROWS, 1536, 512, cnt);
    attn_row0_kernel<<<dim3(NH, B_SZ), 256, 0, stream>>>(QKV, cnt, attn0);
    row0_proj_ln_kernel<<<B_SZ, 256, 0, stream>>>(
        attn0, mWo[1], mbo[1], Z, ln_g, ln_b, clsb, br);
  }
  final_mlp_kernel<<<B_SZ, 256, 0, stream>>>(
      clsb, pr_W0, pr_b0, pr_W1, pr_b1, pr_W2, pr_b2, (float*)d_out);
}

// Round 6
// 993.558 us; speedup vs baseline: 3.9974x; 1.4039x over previous
//
#include <hip/hip_runtime.h>
#include <hip/hip_bf16.h>

#define B_SZ 4
#define N_INST 2048
#define D_MODEL 512
#define S_TOT 2049          // N+1 (cls prepended)
#define NH 8
#define HD 64
#define ROWS (B_SZ*S_TOT)   // 8196

typedef __attribute__((ext_vector_type(4))) float f32x4;
typedef __attribute__((ext_vector_type(8))) short bf16x8;

__device__ __forceinline__ float gelu_exact(float x){ return 0.5f*x*(1.f+erff(x*0.70710678118654752f)); }
__device__ __forceinline__ unsigned short f2bf(float x){
  unsigned int u = __float_as_uint(x);
  u += 0x7fffu + ((u>>16)&1u);
  return (unsigned short)(u>>16);
}
__device__ __forceinline__ float bfval(unsigned short u){ return __uint_as_float(((unsigned int)u)<<16); }
__device__ __forceinline__ unsigned int pk2(unsigned short lo, unsigned short hi){
  return (unsigned int)lo | ((unsigned int)hi << 16);
}

#define GLOAD16(gp, lp) __builtin_amdgcn_global_load_lds( \
    (const __attribute__((address_space(1))) void*)(gp), \
    (__attribute__((address_space(3))) void*)(lp), 16, 0, 0)

// ---------------------------------------------------------------------------
// Gating MLP: weight[b,n] = sigmoid(MLP(x[b,n,:])), D->64(gelu)->64(gelu)->1
// ---------------------------------------------------------------------------
__global__ __launch_bounds__(64) void aw_weight_kernel(
    const float* __restrict__ x,
    const float* __restrict__ W0, const float* __restrict__ b0,
    const float* __restrict__ W1, const float* __restrict__ b1,
    const float* __restrict__ W2, const float* __restrict__ b2,
    float* __restrict__ weight) {
  int inst = blockIdx.x;
  int h = threadIdx.x;
  __shared__ float xs[512];
  __shared__ float hs[64];
  const float* xp = x + (size_t)inst*D_MODEL;
  for (int i=h;i<512;i+=64) xs[i] = xp[i];
  __syncthreads();
  const float4* w0 = (const float4*)(W0 + (size_t)h*512);
  float acc = b0[h];
  #pragma unroll 8
  for (int k4=0;k4<128;k4++){
    float4 u = w0[k4]; int k = k4*4;
    acc += xs[k+0]*u.x + xs[k+1]*u.y + xs[k+2]*u.z + xs[k+3]*u.w;
  }
  hs[h] = gelu_exact(acc);
  __syncthreads();
  const float4* w1 = (const float4*)(W1 + (size_t)h*64);
  float acc2 = b1[h];
  #pragma unroll
  for (int k4=0;k4<16;k4++){
    float4 u = w1[k4]; int k = k4*4;
    acc2 += hs[k+0]*u.x + hs[k+1]*u.y + hs[k+2]*u.z + hs[k+3]*u.w;
  }
  float h2 = gelu_exact(acc2);
  float p = h2 * W2[h];
  #pragma unroll
  for (int o=32;o;o>>=1) p += __shfl_down(p, o);
  if (h==0){
    float s = p + b2[0];
    weight[inst] = 1.f/(1.f+expf(-s));
  }
}

// ---------------------------------------------------------------------------
// Split fp32 -> (hi, lo) bf16 pair.  lo = bf16(x - float(hi)).
// ---------------------------------------------------------------------------
__global__ __launch_bounds__(256) void split_kernel(
    const float* __restrict__ w, unsigned short* __restrict__ hi,
    unsigned short* __restrict__ lo, int n) {
  int i = blockIdx.x*256 + threadIdx.x;
  if (i < n){
    float v = w[i];
    unsigned short h = f2bf(v);
    hi[i] = h;
    lo[i] = f2bf(v - bfval(h));
  }
}

// ---------------------------------------------------------------------------
// Compaction: per batch, ascending list of valid seq positions (slot0 = cls).
// ---------------------------------------------------------------------------
__global__ __launch_bounds__(256) void compact_kernel(
    const float* __restrict__ weight, int branch,
    int* __restrict__ idx, int* __restrict__ cnt) {
  int b = blockIdx.x;
  int t = threadIdx.x;
  int lane = t & 63, wv = t >> 6;
  __shared__ int wsum[4];
  __shared__ int base_s;
  if (t==0){ idx[b*S_TOT] = 0; base_s = 1; }
  __syncthreads();
  for (int c0=0; c0<N_INST; c0+=256){
    int n = c0 + t;
    float w = weight[b*N_INST + n];
    bool neg = (w < 0.5f);
    bool val = (branch==0) ? neg : !neg;
    unsigned long long m = __ballot(val);
    int prefix = __popcll(m & ((1ull<<lane)-1ull));
    if (lane==0) wsum[wv] = __popcll(m);
    __syncthreads();
    int wbase = 0;
    #pragma unroll
    for (int i=0;i<4;i++) if (i<wv) wbase += wsum[i];
    int total = wsum[0]+wsum[1]+wsum[2]+wsum[3];
    int mybase = base_s;
    if (val) idx[b*S_TOT + mybase + wbase + prefix] = n + 1;
    __syncthreads();
    if (t==0) base_s += total;
    __syncthreads();
  }
  if (t==0) cnt[b] = base_s;
}

// ---------------------------------------------------------------------------
// Build compacted z = LN(scale*seq[idx]) -> hi/lo bf16 pair.
// ---------------------------------------------------------------------------
__global__ __launch_bounds__(256) void build_z_kernel(
    const float* __restrict__ x, const float* __restrict__ weight,
    const float* __restrict__ cls, const float* __restrict__ g, const float* __restrict__ be,
    int branch, const int* __restrict__ idx, const int* __restrict__ cnt,
    unsigned short* __restrict__ Zh, unsigned short* __restrict__ Zl) {
  int row = blockIdx.x;
  int b = row / S_TOT, slot = row % S_TOT;
  if (slot >= cnt[b]) return;
  int t = threadIdx.x;
  __shared__ float v[512];
  __shared__ float red[16];
  int pos = idx[b*S_TOT + slot];
  float scale = 1.f;
  const float* src = cls;
  if (pos != 0){
    float w = weight[b*N_INST + (pos-1)];
    scale = (branch==0) ? powf(w, 1.5f) : powf(w, 2.0f/3.0f);
    src = x + ((size_t)b*N_INST + (pos-1))*D_MODEL;
  }
  float s1=0.f, s2=0.f;
  for (int i=t;i<512;i+=256){
    float val = src[i];
    if (pos != 0) val *= scale;
    v[i]=val; s1+=val; s2+=val*val;
  }
  __syncthreads();
  #pragma unroll
  for (int o=32;o;o>>=1){ s1+=__shfl_down(s1,o); s2+=__shfl_down(s2,o); }
  if ((t&63)==0){ red[t>>6]=s1; red[8+(t>>6)]=s2; }
  __syncthreads();
  s1 = red[0]+red[1]+red[2]+red[3];
  s2 = red[8]+red[9]+red[10]+red[11];
  float mean = s1 * (1.f/512.f);
  float var  = s2 * (1.f/512.f) - mean*mean;
  float rn = rsqrtf(var + 1e-5f);
  size_t ro = (size_t)row*512;
  for (int i=t;i<512;i+=256){
    float o = (v[i]-mean)*rn*g[i] + be[i];
    unsigned short hbits = f2bf(o);
    Zh[ro+i] = hbits;
    Zl[ro+i] = f2bf(o - bfval(hbits));
  }
}

// out = LN((Zh+Zl) + T2) rowwise -> hi/lo bf16 pair (the a1 operand)
__global__ __launch_bounds__(256) void add_ln_kernel(
    const unsigned short* __restrict__ Zh, const unsigned short* __restrict__ Zl,
    const float* __restrict__ T2,
    const float* __restrict__ g, const float* __restrict__ be,
    const int* __restrict__ cnt,
    unsigned short* __restrict__ Ah, unsigned short* __restrict__ Al) {
  int row = blockIdx.x;
  if ((row % S_TOT) >= cnt[row / S_TOT]) return;
  int t = threadIdx.x;
  __shared__ float v[512];
  __shared__ float red[16];
  size_t ro = (size_t)row*512;
  float s1=0.f, s2=0.f;
  for (int i=t;i<512;i+=256){
    float val = bfval(Zh[ro+i]) + bfval(Zl[ro+i]) + T2[ro+i];
    v[i]=val; s1+=val; s2+=val*val;
  }
  __syncthreads();
  #pragma unroll
  for (int o=32;o;o>>=1){ s1+=__shfl_down(s1,o); s2+=__shfl_down(s2,o); }
  if ((t&63)==0){ red[t>>6]=s1; red[8+(t>>6)]=s2; }
  __syncthreads();
  s1 = red[0]+red[1]+red[2]+red[3];
  s2 = red[8]+red[9]+red[10]+red[11];
  float mean = s1 * (1.f/512.f);
  float var  = s2 * (1.f/512.f) - mean*mean;
  float rn = rsqrtf(var + 1e-5f);
  for (int i=t;i<512;i+=256){
    float o = (v[i]-mean)*rn*g[i] + be[i];
    unsigned short hbits = f2bf(o);
    Ah[ro+i] = hbits;
    Al[ro+i] = f2bf(o - bfval(hbits));
  }
}

// ---------------------------------------------------------------------------
// MFMA GEMM (bf16 hi/lo 3-pass): C[M,N] = (Ah+Al)[M,512] @ (Wh+Wl)[N,512]^T + bias.
// 64x64 tile, BK=64, 4 waves; wave w stages one operand, owns n-strip w*16.
// Staging via global_load_lds width 16 with XOR-granule source swizzle.
// Rows gated per-batch by cnt[].
// ---------------------------------------------------------------------------
__global__ __launch_bounds__(256) void mfma_gemm_kernel(
    const unsigned short* __restrict__ Ahg, const unsigned short* __restrict__ Alg,
    const unsigned short* __restrict__ Whg, const unsigned short* __restrict__ Wlg,
    const float* __restrict__ bias, float* __restrict__ C,
    int M, int N, const int* __restrict__ cnt) {
  int t = threadIdx.x;
  int bm = blockIdx.y*64, bn = blockIdx.x*64;
  {
    int r = bm + (t>>2);
    bool ok = (r < M) && ((r % S_TOT) < cnt[r / S_TOT]);
    if (__syncthreads_or(ok ? 1 : 0) == 0) return;
  }
  __shared__ unsigned short Ahs[64*64], Als[64*64], Whs[64*64], Wls[64*64];
  int lane = t & 63, w = t >> 6;
  int l15 = lane & 15, l4 = lane >> 4;

  // staging: wave w stages operand w (8 issues of 1 KB each).
  // NOTE: no pointer arrays here — gfx950 rejects constant-initialized arrays
  // of LDS-derived generic pointers (addrspacecast static initializer).
  const unsigned short* src;
  unsigned short* dst;
  if      (w == 0){ src = Ahg; dst = Ahs; }
  else if (w == 1){ src = Alg; dst = Als; }
  else if (w == 2){ src = Whg; dst = Whs; }
  else            { src = Wlg; dst = Wls; }
  int tb  = (w < 2) ? bm : bn;
  int lim = (w < 2) ? M  : N;
  int lrow = lane >> 3;   // 0..7
  int lg   = lane & 7;
  const unsigned short* gp[8];
  #pragma unroll
  for (int i=0;i<8;i++){
    int row_l = i*8 + lrow;
    int rg = tb + row_l; if (rg >= lim) rg = lim-1;
    gp[i] = src + (size_t)rg*512 + (size_t)((lg ^ (row_l&7))*8);
  }

  f32x4 acc[4];
  #pragma unroll
  for (int mt=0;mt<4;mt++) acc[mt] = (f32x4){0.f,0.f,0.f,0.f};

  for (int ch=0; ch<8; ch++){
    __syncthreads();
    #pragma unroll
    for (int i=0;i<8;i++)
      GLOAD16(gp[i] + ch*64, dst + i*512);
    __syncthreads();
    #pragma unroll
    for (int ks=0; ks<2; ks++){
      int wrow = w*16 + l15;
      int wgs = (ks*4 + l4) ^ (wrow & 7);
      bf16x8 wh = *(const bf16x8*)&Whs[wrow*64 + wgs*8];
      bf16x8 wl = *(const bf16x8*)&Wls[wrow*64 + wgs*8];
      #pragma unroll
      for (int mt=0;mt<4;mt++){
        int arow = mt*16 + l15;
        int ags = (ks*4 + l4) ^ (arow & 7);
        bf16x8 ah = *(const bf16x8*)&Ahs[arow*64 + ags*8];
        bf16x8 al = *(const bf16x8*)&Als[arow*64 + ags*8];
        acc[mt] = __builtin_amdgcn_mfma_f32_16x16x32_bf16(ah, wh, acc[mt], 0,0,0);
        acc[mt] = __builtin_amdgcn_mfma_f32_16x16x32_bf16(ah, wl, acc[mt], 0,0,0);
        acc[mt] = __builtin_amdgcn_mfma_f32_16x16x32_bf16(al, wh, acc[mt], 0,0,0);
      }
    }
  }
  // epilogue: lane (l15, l4), reg r -> C[bm + mt*16 + l4*4 + r][bn + w*16 + l15]
  int ncol = bn + w*16 + l15;
  float bv = bias[ncol];
  #pragma unroll
  for (int mt=0;mt<4;mt++){
    #pragma unroll
    for (int r=0;r<4;r++){
      int mrow = bm + mt*16 + l4*4 + r;
      bool ok = (mrow < M) && ((mrow % S_TOT) < cnt[mrow / S_TOT]);
      if (ok) C[(size_t)mrow*N + ncol] = acc[mt][r] + bv;
    }
  }
}

// ---------------------------------------------------------------------------
// MFMA flash attention (layer 0), compacted keys; epilogue emits hi/lo bf16.
// ---------------------------------------------------------------------------
__global__ __launch_bounds__(256) void flash_attn_kernel(
    const float* __restrict__ qkv, const int* __restrict__ cnt,
    unsigned short* __restrict__ Oh, unsigned short* __restrict__ Ol) {
  int b = blockIdx.z, h = blockIdx.y;
  int cb = cnt[b];
  int S0 = blockIdx.x * 64;
  if (S0 >= cb) return;
  int t = threadIdx.x;
  int lane = t & 63, w = t >> 6;
  int l15 = lane & 15, l4 = lane >> 4;

  __shared__ unsigned short Kbf[64*64];
  __shared__ unsigned short Vt[64*64];
  __shared__ unsigned short Pbuf[4][16*64];

  const float* basep = qkv + (size_t)(b*S_TOT)*1536;

  int qg = S0 + w*16 + l15;
  int qr = (qg < cb) ? qg : 0;
  const float* qp = basep + (size_t)qr*1536 + h*64;
  bf16x8 Qf[2];
  #pragma unroll
  for (int c=0;c<2;c++){
    int d0 = c*32 + l4*8;
    float4 a = *(const float4*)(qp + d0);
    float4 bq = *(const float4*)(qp + d0 + 4);
    bf16x8 q8;
    q8[0]=(short)f2bf(a.x*0.125f);  q8[1]=(short)f2bf(a.y*0.125f);
    q8[2]=(short)f2bf(a.z*0.125f);  q8[3]=(short)f2bf(a.w*0.125f);
    q8[4]=(short)f2bf(bq.x*0.125f); q8[5]=(short)f2bf(bq.y*0.125f);
    q8[6]=(short)f2bf(bq.z*0.125f); q8[7]=(short)f2bf(bq.w*0.125f);
    Qf[c]=q8;
  }

  float m_run = -1e30f, l_run = 0.f;
  f32x4 accO[4];
  #pragma unroll
  for (int mt=0;mt<4;mt++) accO[mt] = (f32x4){0.f,0.f,0.f,0.f};

  unsigned int* Ku = (unsigned int*)Kbf;
  unsigned int* Vu = (unsigned int*)Vt;
  const int nt = (cb + 63)/64;
  for (int kt=0; kt<nt; kt++){
    int K0 = kt*64;
    __syncthreads();
    {
      int key = t>>2;
      int keyr = (K0+key < cb) ? (K0+key) : 0;
      const float* kp = basep + (size_t)keyr*1536 + 512 + h*64 + (t&3)*16;
      float4 x0 = *(const float4*)(kp);
      float4 x1 = *(const float4*)(kp+4);
      float4 x2 = *(const float4*)(kp+8);
      float4 x3 = *(const float4*)(kp+12);
      int g0 = (t&3)*2;
      int gs0 = g0 ^ (key&7), gs1 = (g0+1) ^ (key&7);
      uint4 pa, pb;
      pa.x = pk2(f2bf(x0.x), f2bf(x0.y)); pa.y = pk2(f2bf(x0.z), f2bf(x0.w));
      pa.z = pk2(f2bf(x1.x), f2bf(x1.y)); pa.w = pk2(f2bf(x1.z), f2bf(x1.w));
      pb.x = pk2(f2bf(x2.x), f2bf(x2.y)); pb.y = pk2(f2bf(x2.z), f2bf(x2.w));
      pb.z = pk2(f2bf(x3.x), f2bf(x3.y)); pb.w = pk2(f2bf(x3.z), f2bf(x3.w));
      *(uint4*)(Ku + key*32 + gs0*4) = pa;
      *(uint4*)(Ku + key*32 + gs1*4) = pb;
    }
    {
      int kp2 = t & 31;
      int d8 = t >> 5;
      int k0g = K0 + 2*kp2;
      int kr0 = (k0g   < cb) ? k0g   : 0;
      int kr1 = (k0g+1 < cb) ? k0g+1 : 0;
      const float* vp0 = basep + (size_t)kr0*1536 + 1024 + h*64 + d8*8;
      const float* vp1 = basep + (size_t)kr1*1536 + 1024 + h*64 + d8*8;
      float4 a0 = *(const float4*)(vp0);
      float4 a1 = *(const float4*)(vp0+4);
      float4 b0 = *(const float4*)(vp1);
      float4 b1 = *(const float4*)(vp1+4);
      float r0[8] = {a0.x,a0.y,a0.z,a0.w,a1.x,a1.y,a1.z,a1.w};
      float r1[8] = {b0.x,b0.y,b0.z,b0.w,b1.x,b1.y,b1.z,b1.w};
      int k8 = kp2 >> 2;
      #pragma unroll
      for (int dd=0; dd<8; dd++){
        int d = d8*8 + dd;
        Vu[d*32 + (k8 ^ (d&7))*4 + (kp2&3)] = pk2(f2bf(r0[dd]), f2bf(r1[dd]));
      }
    }
    __syncthreads();

    f32x4 acc[4];
    #pragma unroll
    for (int mt=0;mt<4;mt++) acc[mt] = (f32x4){0.f,0.f,0.f,0.f};
    #pragma unroll
    for (int mt=0;mt<4;mt++){
      int row = mt*16 + l15;
      #pragma unroll
      for (int c=0;c<2;c++){
        int gs = (c*4 + l4) ^ (row & 7);
        bf16x8 kf = *(const bf16x8*)&Kbf[row*64 + gs*8];
        acc[mt] = __builtin_amdgcn_mfma_f32_16x16x32_bf16(kf, Qf[c], acc[mt], 0,0,0);
      }
    }
    float p[4][4];
    float tmax = -1e30f;
    #pragma unroll
    for (int mt=0;mt<4;mt++)
      #pragma unroll
      for (int r=0;r<4;r++){
        int key = K0 + mt*16 + l4*4 + r;
        float s = (key < cb) ? acc[mt][r] : -1e30f;
        p[mt][r] = s;
        tmax = fmaxf(tmax, s);
      }
    tmax = fmaxf(tmax, __shfl_xor(tmax, 16));
    tmax = fmaxf(tmax, __shfl_xor(tmax, 32));
    float m_new = fmaxf(m_run, tmax);
    float alpha = __expf(m_run - m_new);
    float psum = 0.f;
    #pragma unroll
    for (int mt=0;mt<4;mt++)
      #pragma unroll
      for (int r=0;r<4;r++){
        float pv = __expf(p[mt][r] - m_new);
        p[mt][r] = pv; psum += pv;
      }
    psum += __shfl_xor(psum, 16);
    psum += __shfl_xor(psum, 32);
    l_run = l_run*alpha + psum;
    m_run = m_new;

    #pragma unroll
    for (int mt=0;mt<4;mt++){
      int keyl = mt*16 + l4*4;
      int gs = (keyl >> 3) ^ (l15 & 7);
      uint2 w2;
      w2.x = pk2(f2bf(p[mt][0]), f2bf(p[mt][1]));
      w2.y = pk2(f2bf(p[mt][2]), f2bf(p[mt][3]));
      *(uint2*)&Pbuf[w][ l15*64 + gs*8 + (keyl & 7) ] = w2;
    }
    #pragma unroll
    for (int mt=0;mt<4;mt++){
      accO[mt][0]*=alpha; accO[mt][1]*=alpha; accO[mt][2]*=alpha; accO[mt][3]*=alpha;
    }
    #pragma unroll
    for (int c2=0;c2<2;c2++){
      int gpv = (c2*4 + l4) ^ (l15 & 7);
      bf16x8 pf = *(const bf16x8*)&Pbuf[w][ l15*64 + gpv*8 ];
      #pragma unroll
      for (int mt=0;mt<4;mt++){
        int d = mt*16 + l15;
        int gv = (c2*4 + l4) ^ (d & 7);
        bf16x8 vf = *(const bf16x8*)&Vt[ d*64 + gv*8 ];
        accO[mt] = __builtin_amdgcn_mfma_f32_16x16x32_bf16(vf, pf, accO[mt], 0,0,0);
      }
    }
  }
  if (qg < cb){
    float inv = 1.f/l_run;
    size_t ro = ((size_t)(b*S_TOT) + qg)*512 + h*64;
    #pragma unroll
    for (int mt=0;mt<4;mt++){
      float v0 = accO[mt][0]*inv, v1 = accO[mt][1]*inv;
      float v2 = accO[mt][2]*inv, v3 = accO[mt][3]*inv;
      unsigned short h0=f2bf(v0), h1=f2bf(v1), h2=f2bf(v2), h3=f2bf(v3);
      uint2 hw; hw.x = pk2(h0,h1); hw.y = pk2(h2,h3);
      uint2 lw;
      lw.x = pk2(f2bf(v0-bfval(h0)), f2bf(v1-bfval(h1)));
      lw.y = pk2(f2bf(v2-bfval(h2)), f2bf(v3-bfval(h3)));
      *(uint2*)&Oh[ro + mt*16 + l4*4] = hw;
      *(uint2*)&Ol[ro + mt*16 + l4*4] = lw;
    }
  }
}

// ---------------------------------------------------------------------------
// Layer-1 attention, query 0 only, over compacted keys. Block per (h,b).
// ---------------------------------------------------------------------------
__global__ __launch_bounds__(256) void attn_row0_kernel(
    const float* __restrict__ qkv, const int* __restrict__ cnt,
    float* __restrict__ out0) {
  int h = blockIdx.x, b = blockIdx.y;
  int cb = cnt[b];
  int t = threadIdx.x;
  __shared__ float qs[64];
  __shared__ float sc[S_TOT];
  __shared__ float red[8];
  __shared__ float redO[4][64];
  const float* base = qkv + (size_t)b*S_TOT*1536;
  if (t < 64) qs[t] = base[h*64 + t]*0.125f;
  __syncthreads();
  float lmax = -1e30f;
  for (int j=t; j<cb; j+=256){
    const float* kp = base + (size_t)j*1536 + 512 + h*64;
    float s = 0.f;
    #pragma unroll
    for (int d4=0; d4<16; d4++){
      float4 kv = *(const float4*)(kp + d4*4);
      s += qs[d4*4+0]*kv.x + qs[d4*4+1]*kv.y + qs[d4*4+2]*kv.z + qs[d4*4+3]*kv.w;
    }
    sc[j]=s;
    lmax = fmaxf(lmax, s);
  }
  #pragma unroll
  for (int o=32;o;o>>=1) lmax = fmaxf(lmax, __shfl_down(lmax, o));
  if ((t&63)==0) red[t>>6]=lmax;
  __syncthreads();
  float m = fmaxf(fmaxf(red[0],red[1]),fmaxf(red[2],red[3]));
  float lsum = 0.f;
  for (int j=t;j<cb;j+=256){
    float p = expf(sc[j]-m);
    sc[j]=p; lsum+=p;
  }
  #pragma unroll
  for (int o=32;o;o>>=1) lsum += __shfl_down(lsum,o);
  __syncthreads();
  if ((t&63)==0) red[t>>6]=lsum;
  __syncthreads();
  float l = red[0]+red[1]+red[2]+red[3];
  int d = t & 63, rr = t >> 6;
  float acc = 0.f;
  for (int j=rr; j<cb; j+=4)
    acc += sc[j]*base[(size_t)j*1536 + 1024 + h*64 + d];
  redO[rr][d]=acc;
  __syncthreads();
  if (t < 64){
    float o = (redO[0][t]+redO[1][t]+redO[2][t]+redO[3][t])/l;
    out0[b*512 + h*64 + t] = o;
  }
}

// layer-1 out-proj for row 0 + residual(z row0) + LN -> cls embedding slot
__global__ __launch_bounds__(256) void row0_proj_ln_kernel(
    const float* __restrict__ attn0, const float* __restrict__ Wo, const float* __restrict__ bo,
    const unsigned short* __restrict__ Zh, const unsigned short* __restrict__ Zl,
    const float* __restrict__ g, const float* __restrict__ be,
    float* __restrict__ clsbuf, int branch) {
  int b = blockIdx.x, t = threadIdx.x;
  __shared__ float xin[512];
  __shared__ float y[512];
  __shared__ float red[16];
  for (int i=t;i<512;i+=256) xin[i] = attn0[b*512+i];
  __syncthreads();
  size_t z0 = (size_t)b*S_TOT*512;
  for (int n=t;n<512;n+=256){
    const float4* wr = (const float4*)(Wo + (size_t)n*512);
    float acc = bo[n];
    for (int k4=0;k4<128;k4++){
      float4 u = wr[k4]; int k=k4*4;
      acc += xin[k+0]*u.x + xin[k+1]*u.y + xin[k+2]*u.z + xin[k+3]*u.w;
    }
    y[n] = acc + bfval(Zh[z0+n]) + bfval(Zl[z0+n]);
  }
  __syncthreads();
  float s1=0.f, s2=0.f;
  for (int i=t;i<512;i+=256){ float a=y[i]; s1+=a; s2+=a*a; }
  #pragma unroll
  for (int o=32;o;o>>=1){ s1+=__shfl_down(s1,o); s2+=__shfl_down(s2,o); }
  if ((t&63)==0){ red[t>>6]=s1; red[8+(t>>6)]=s2; }
  __syncthreads();
  s1 = red[0]+red[1]+red[2]+red[3];
  s2 = red[8]+red[9]+red[10]+red[11];
  float mean = s1*(1.f/512.f);
  float var  = s2*(1.f/512.f) - mean*mean;
  float rn = rsqrtf(var + 1e-5f);
  for (int i=t;i<512;i+=256)
    clsbuf[b*1024 + branch*512 + i] = (y[i]-mean)*rn*g[i] + be[i];
}

// final projection MLP: [B,1024] -> 512 gelu -> 512 gelu -> 512, fp32 out
__global__ __launch_bounds__(256) void final_mlp_kernel(
    const float* __restrict__ emb,
    const float* __restrict__ W0, const float* __restrict__ b0,
    const float* __restrict__ W1, const float* __restrict__ b1,
    const float* __restrict__ W2, const float* __restrict__ b2,
    float* __restrict__ outp) {
  int b = blockIdx.x, t = threadIdx.x;
  __shared__ float e[1024];
  __shared__ float h1[512];
  __shared__ float h2[512];
  for (int i=t;i<1024;i+=256) e[i]=emb[b*1024+i];
  __syncthreads();
  for (int n=t;n<512;n+=256){
    const float4* w = (const float4*)(W0 + (size_t)n*1024);
    float acc = b0[n];
    for (int k4=0;k4<256;k4++){
      float4 u = w[k4]; int k=k4*4;
      acc += e[k+0]*u.x + e[k+1]*u.y + e[k+2]*u.z + e[k+3]*u.w;
    }
    h1[n]=gelu_exact(acc);
  }
  __syncthreads();
  for (int n=t;n<512;n+=256){
    const float4* w = (const float4*)(W1 + (size_t)n*512);
    float acc = b1[n];
    for (int k4=0;k4<128;k4++){
      float4 u = w[k4]; int k=k4*4;
      acc += h1[k+0]*u.x + h1[k+1]*u.y + h1[k+2]*u.z + h1[k+3]*u.w;
    }
    h2[n]=gelu_exact(acc);
  }
  __syncthreads();
  for (int n=t;n<512;n+=256){
    const float4* w = (const float4*)(W2 + (size_t)n*512);
    float acc = b2[n];
    for (int k4=0;k4<128;k4++){
      float4 u = w[k4]; int k=k4*4;
      acc += h2[k+0]*u.x + h2[k+1]*u.y + h2[k+2]*u.z + h2[k+3]*u.w;
    }
    outp[b*512+n] = acc;
  }
}

// ---------------------------------------------------------------------------
extern "C" void kernel_launch(void* const* d_in, const int* in_sizes, int n_in,
                              void* d_out, int out_size, void* d_ws, size_t ws_size,
                              hipStream_t stream) {
  const float* x      = (const float*)d_in[0];
  const float* cls_tk = (const float*)d_in[1];
  const float* ln_g   = (const float*)d_in[2];
  const float* ln_b   = (const float*)d_in[3];
  const float* aw_W0  = (const float*)d_in[4];  const float* aw_b0 = (const float*)d_in[5];
  const float* aw_W1  = (const float*)d_in[6];  const float* aw_b1 = (const float*)d_in[7];
  const float* aw_W2  = (const float*)d_in[8];  const float* aw_b2 = (const float*)d_in[9];
  const float* pr_W0  = (const float*)d_in[10]; const float* pr_b0 = (const float*)d_in[11];
  const float* pr_W1  = (const float*)d_in[12]; const float* pr_b1 = (const float*)d_in[13];
  const float* pr_W2  = (const float*)d_in[14]; const float* pr_b2 = (const float*)d_in[15];
  const float* mWqkv[2] = {(const float*)d_in[16], (const float*)d_in[20]};
  const float* mbqkv[2] = {(const float*)d_in[17], (const float*)d_in[21]};
  const float* mWo[2]   = {(const float*)d_in[18], (const float*)d_in[22]};
  const float* mbo[2]   = {(const float*)d_in[19], (const float*)d_in[23]};

  float* ws = (float*)d_ws;
  size_t off = 0;
  float* weight = ws + off; off += 8192;                      // [B,N]
  int*   idx    = (int*)(ws + off); off += 8448;              // [B,S]
  int*   cnt    = (int*)(ws + off); off += 16;                // [B]
  const size_t HBUF = (size_t)ROWS*512/2;                     // bf16 array in float units
  unsigned short* Zh = (unsigned short*)(ws + off); off += HBUF;
  unsigned short* Zl = (unsigned short*)(ws + off); off += HBUF;
  float* QKV    = ws + off; off += (size_t)ROWS*1536;
  float* T2     = QKV;                                        // alias: dead QKV space
  unsigned short* Oh = (unsigned short*)(ws + off); off += HBUF;  // also a1 hi
  unsigned short* Ol = (unsigned short*)(ws + off); off += HBUF;  // also a1 lo
  unsigned short* Wq0h = (unsigned short*)(ws + off); off += 393216;
  unsigned short* Wq0l = (unsigned short*)(ws + off); off += 393216;
  unsigned short* Wq1h = (unsigned short*)(ws + off); off += 393216;
  unsigned short* Wq1l = (unsigned short*)(ws + off); off += 393216;
  unsigned short* Wo0h = (unsigned short*)(ws + off); off += 131072;
  unsigned short* Wo0l = (unsigned short*)(ws + off); off += 131072;
  float* attn0  = ws + off; off += 2048;                      // [B,D]
  float* clsb   = ws + off; off += 4096;                      // [B,2D]
  (void)ws_size; (void)in_sizes; (void)n_in; (void)out_size;

  aw_weight_kernel<<<B_SZ*N_INST, 64, 0, stream>>>(
      x, aw_W0, aw_b0, aw_W1, aw_b1, aw_W2, aw_b2, weight);

  split_kernel<<<(786432+255)/256, 256, 0, stream>>>(mWqkv[0], Wq0h, Wq0l, 786432);
  split_kernel<<<(786432+255)/256, 256, 0, stream>>>(mWqkv[1], Wq1h, Wq1l, 786432);
  split_kernel<<<(262144+255)/256, 256, 0, stream>>>(mWo[0],  Wo0h, Wo0l, 262144);

  for (int br=0; br<2; br++){
    compact_kernel<<<B_SZ, 256, 0, stream>>>(weight, br, idx, cnt);
    build_z_kernel<<<ROWS, 256, 0, stream>>>(x, weight, cls_tk, ln_g, ln_b, br, idx, cnt, Zh, Zl);
    // layer 0
    mfma_gemm_kernel<<<dim3(1536/64, (ROWS+63)/64), 256, 0, stream>>>(
        Zh, Zl, Wq0h, Wq0l, mbqkv[0], QKV, ROWS, 1536, cnt);
    flash_attn_kernel<<<dim3((S_TOT+63)/64, NH, B_SZ), 256, 0, stream>>>(QKV, cnt, Oh, Ol);
    mfma_gemm_kernel<<<dim3(512/64, (ROWS+63)/64), 256, 0, stream>>>(
        Oh, Ol, Wo0h, Wo0l, mbo[0], T2, ROWS, 512, cnt);
    add_ln_kernel<<<ROWS, 256, 0, stream>>>(Zh, Zl, T2, ln_g, ln_b, cnt, Oh, Ol); // a1 -> Oh/Ol
    // layer 1 (only row 0 consumed)
    mfma_gemm_kernel<<<dim3(1536/64, (ROWS+63)/64), 256, 0, stream>>>(
        Oh, Ol, Wq1h, Wq1l, mbqkv[1], QKV, ROWS, 1536, cnt);
    attn_row0_kernel<<<dim3(NH, B_SZ), 256, 0, stream>>>(QKV, cnt, attn0);
    row0_proj_ln_kernel<<<B_SZ, 256, 0, stream>>>(
        attn0, mWo[1], mbo[1], Zh, Zl, ln_g, ln_b, clsb, br);
  }
  final_mlp_kernel<<<B_SZ, 256, 0, stream>>>(
      clsb, pr_W0, pr_b0, pr_W1, pr_b1, pr_W2, pr_b2, (float*)d_out);
}

// Round 7
// 911.994 us; speedup vs baseline: 4.3549x; 1.0894x over previous
//
#include <hip/hip_runtime.h>
#include <hip/hip_bf16.h>

#define B_SZ 4
#define N_INST 2048
#define D_MODEL 512
#define S_TOT 2049          // N+1 (cls prepended)
#define NH 8
#define HD 64
#define ROWS (B_SZ*S_TOT)   // 8196

typedef __attribute__((ext_vector_type(4))) float f32x4;
typedef __attribute__((ext_vector_type(8))) short bf16x8;

__device__ __forceinline__ float gelu_exact(float x){ return 0.5f*x*(1.f+erff(x*0.70710678118654752f)); }
__device__ __forceinline__ unsigned short f2bf(float x){
  unsigned int u = __float_as_uint(x);
  u += 0x7fffu + ((u>>16)&1u);
  return (unsigned short)(u>>16);
}
__device__ __forceinline__ float bfval(unsigned short u){ return __uint_as_float(((unsigned int)u)<<16); }
__device__ __forceinline__ unsigned int pk2(unsigned short lo, unsigned short hi){
  return (unsigned int)lo | ((unsigned int)hi << 16);
}

#define GLOAD16(gp, lp) __builtin_amdgcn_global_load_lds( \
    (const __attribute__((address_space(1))) void*)(gp), \
    (__attribute__((address_space(3))) void*)(lp), 16, 0, 0)

// ---------------------------------------------------------------------------
// One-time transpose: W0T[k][h] = W0[h][k]   (64x512 -> 512x64, fp32)
// ---------------------------------------------------------------------------
__global__ __launch_bounds__(256) void transpose_w0_kernel(
    const float* __restrict__ W0, float* __restrict__ W0T) {
  int i = blockIdx.x*256 + threadIdx.x;     // over 64*512 elements, read-coalesced
  if (i < 64*512){
    int h = i >> 9, k = i & 511;
    W0T[k*64 + h] = W0[i];
  }
}

// ---------------------------------------------------------------------------
// Gating MLP: weight[b,n] = sigmoid(MLP(x[b,n,:])), D->64(gelu)->64(gelu)->1
// One wave per instance; lane h owns hidden unit h. Layer-1 weights read from
// W0T so consecutive lanes hit consecutive addresses (coalesced); x[k] is an
// LDS same-address broadcast (conflict-free). fp32 throughout: the w<0.5 mask
// is a threshold — bf16 logits risk borderline branch flips.
// ---------------------------------------------------------------------------
__global__ __launch_bounds__(64) void aw_weight_kernel(
    const float* __restrict__ x,
    const float* __restrict__ W0T, const float* __restrict__ b0,
    const float* __restrict__ W1, const float* __restrict__ b1,
    const float* __restrict__ W2, const float* __restrict__ b2,
    float* __restrict__ weight) {
  int inst = blockIdx.x;
  int h = threadIdx.x;
  __shared__ float xs[512];
  __shared__ float hs[64];
  const float* xp = x + (size_t)inst*D_MODEL;
  for (int i=h;i<512;i+=64) xs[i] = xp[i];
  __syncthreads();
  float acc = b0[h];
  const float* w0c = W0T + h;
  #pragma unroll 16
  for (int k=0;k<512;k++)
    acc = fmaf(xs[k], w0c[k*64], acc);
  hs[h] = gelu_exact(acc);
  __syncthreads();
  const float4* w1 = (const float4*)(W1 + (size_t)h*64);
  float acc2 = b1[h];
  #pragma unroll
  for (int k4=0;k4<16;k4++){
    float4 u = w1[k4]; int k = k4*4;
    acc2 += hs[k+0]*u.x + hs[k+1]*u.y + hs[k+2]*u.z + hs[k+3]*u.w;
  }
  float h2 = gelu_exact(acc2);
  float p = h2 * W2[h];
  #pragma unroll
  for (int o=32;o;o>>=1) p += __shfl_down(p, o);
  if (h==0){
    float s = p + b2[0];
    weight[inst] = 1.f/(1.f+expf(-s));
  }
}

// ---------------------------------------------------------------------------
// Split fp32 -> (hi, lo) bf16 pair.  lo = bf16(x - float(hi)).
// ---------------------------------------------------------------------------
__global__ __launch_bounds__(256) void split_kernel(
    const float* __restrict__ w, unsigned short* __restrict__ hi,
    unsigned short* __restrict__ lo, int n) {
  int i = blockIdx.x*256 + threadIdx.x;
  if (i < n){
    float v = w[i];
    unsigned short h = f2bf(v);
    hi[i] = h;
    lo[i] = f2bf(v - bfval(h));
  }
}

// ---------------------------------------------------------------------------
// Compaction: per batch, ascending list of valid seq positions (slot0 = cls).
// ---------------------------------------------------------------------------
__global__ __launch_bounds__(256) void compact_kernel(
    const float* __restrict__ weight, int branch,
    int* __restrict__ idx, int* __restrict__ cnt) {
  int b = blockIdx.x;
  int t = threadIdx.x;
  int lane = t & 63, wv = t >> 6;
  __shared__ int wsum[4];
  __shared__ int base_s;
  if (t==0){ idx[b*S_TOT] = 0; base_s = 1; }
  __syncthreads();
  for (int c0=0; c0<N_INST; c0+=256){
    int n = c0 + t;
    float w = weight[b*N_INST + n];
    bool neg = (w < 0.5f);
    bool val = (branch==0) ? neg : !neg;
    unsigned long long m = __ballot(val);
    int prefix = __popcll(m & ((1ull<<lane)-1ull));
    if (lane==0) wsum[wv] = __popcll(m);
    __syncthreads();
    int wbase = 0;
    #pragma unroll
    for (int i=0;i<4;i++) if (i<wv) wbase += wsum[i];
    int total = wsum[0]+wsum[1]+wsum[2]+wsum[3];
    int mybase = base_s;
    if (val) idx[b*S_TOT + mybase + wbase + prefix] = n + 1;
    __syncthreads();
    if (t==0) base_s += total;
    __syncthreads();
  }
  if (t==0) cnt[b] = base_s;
}

// ---------------------------------------------------------------------------
// Build compacted z = LN(scale*seq[idx]) -> hi/lo bf16 pair.
// ---------------------------------------------------------------------------
__global__ __launch_bounds__(256) void build_z_kernel(
    const float* __restrict__ x, const float* __restrict__ weight,
    const float* __restrict__ cls, const float* __restrict__ g, const float* __restrict__ be,
    int branch, const int* __restrict__ idx, const int* __restrict__ cnt,
    unsigned short* __restrict__ Zh, unsigned short* __restrict__ Zl) {
  int row = blockIdx.x;
  int b = row / S_TOT, slot = row % S_TOT;
  if (slot >= cnt[b]) return;
  int t = threadIdx.x;
  __shared__ float v[512];
  __shared__ float red[16];
  int pos = idx[b*S_TOT + slot];
  float scale = 1.f;
  const float* src = cls;
  if (pos != 0){
    float w = weight[b*N_INST + (pos-1)];
    scale = (branch==0) ? powf(w, 1.5f) : powf(w, 2.0f/3.0f);
    src = x + ((size_t)b*N_INST + (pos-1))*D_MODEL;
  }
  float s1=0.f, s2=0.f;
  for (int i=t;i<512;i+=256){
    float val = src[i];
    if (pos != 0) val *= scale;
    v[i]=val; s1+=val; s2+=val*val;
  }
  __syncthreads();
  #pragma unroll
  for (int o=32;o;o>>=1){ s1+=__shfl_down(s1,o); s2+=__shfl_down(s2,o); }
  if ((t&63)==0){ red[t>>6]=s1; red[8+(t>>6)]=s2; }
  __syncthreads();
  s1 = red[0]+red[1]+red[2]+red[3];
  s2 = red[8]+red[9]+red[10]+red[11];
  float mean = s1 * (1.f/512.f);
  float var  = s2 * (1.f/512.f) - mean*mean;
  float rn = rsqrtf(var + 1e-5f);
  size_t ro = (size_t)row*512;
  for (int i=t;i<512;i+=256){
    float o = (v[i]-mean)*rn*g[i] + be[i];
    unsigned short hbits = f2bf(o);
    Zh[ro+i] = hbits;
    Zl[ro+i] = f2bf(o - bfval(hbits));
  }
}

// out = LN((Zh+Zl) + T2) rowwise -> hi/lo bf16 pair (the a1 operand)
__global__ __launch_bounds__(256) void add_ln_kernel(
    const unsigned short* __restrict__ Zh, const unsigned short* __restrict__ Zl,
    const float* __restrict__ T2,
    const float* __restrict__ g, const float* __restrict__ be,
    const int* __restrict__ cnt,
    unsigned short* __restrict__ Ah, unsigned short* __restrict__ Al) {
  int row = blockIdx.x;
  if ((row % S_TOT) >= cnt[row / S_TOT]) return;
  int t = threadIdx.x;
  __shared__ float v[512];
  __shared__ float red[16];
  size_t ro = (size_t)row*512;
  float s1=0.f, s2=0.f;
  for (int i=t;i<512;i+=256){
    float val = bfval(Zh[ro+i]) + bfval(Zl[ro+i]) + T2[ro+i];
    v[i]=val; s1+=val; s2+=val*val;
  }
  __syncthreads();
  #pragma unroll
  for (int o=32;o;o>>=1){ s1+=__shfl_down(s1,o); s2+=__shfl_down(s2,o); }
  if ((t&63)==0){ red[t>>6]=s1; red[8+(t>>6)]=s2; }
  __syncthreads();
  s1 = red[0]+red[1]+red[2]+red[3];
  s2 = red[8]+red[9]+red[10]+red[11];
  float mean = s1 * (1.f/512.f);
  float var  = s2 * (1.f/512.f) - mean*mean;
  float rn = rsqrtf(var + 1e-5f);
  for (int i=t;i<512;i+=256){
    float o = (v[i]-mean)*rn*g[i] + be[i];
    unsigned short hbits = f2bf(o);
    Ah[ro+i] = hbits;
    Al[ro+i] = f2bf(o - bfval(hbits));
  }
}

// ---------------------------------------------------------------------------
// MFMA GEMM (bf16 hi/lo 3-pass): C[M,N] = (Ah+Al)[M,512] @ (Wh+Wl)[N,512]^T + bias.
// 64x64 tile, BK=64, 4 waves; wave w stages one operand, owns n-strip w*16.
// Rows gated per-batch by cnt[].
// ---------------------------------------------------------------------------
__global__ __launch_bounds__(256) void mfma_gemm_kernel(
    const unsigned short* __restrict__ Ahg, const unsigned short* __restrict__ Alg,
    const unsigned short* __restrict__ Whg, const unsigned short* __restrict__ Wlg,
    const float* __restrict__ bias, float* __restrict__ C,
    int M, int N, const int* __restrict__ cnt) {
  int t = threadIdx.x;
  int bm = blockIdx.y*64, bn = blockIdx.x*64;
  {
    int r = bm + (t>>2);
    bool ok = (r < M) && ((r % S_TOT) < cnt[r / S_TOT]);
    if (__syncthreads_or(ok ? 1 : 0) == 0) return;
  }
  __shared__ unsigned short Ahs[64*64], Als[64*64], Whs[64*64], Wls[64*64];
  int lane = t & 63, w = t >> 6;
  int l15 = lane & 15, l4 = lane >> 4;

  // staging: wave w stages operand w (8 issues of 1 KB each).
  // NOTE: no pointer arrays — gfx950 rejects static-initialized arrays of
  // LDS-derived generic pointers (addrspacecast in static initializer).
  const unsigned short* src;
  unsigned short* dst;
  if      (w == 0){ src = Ahg; dst = Ahs; }
  else if (w == 1){ src = Alg; dst = Als; }
  else if (w == 2){ src = Whg; dst = Whs; }
  else            { src = Wlg; dst = Wls; }
  int tb  = (w < 2) ? bm : bn;
  int lim = (w < 2) ? M  : N;
  int lrow = lane >> 3;   // 0..7
  int lg   = lane & 7;
  const unsigned short* gp[8];
  #pragma unroll
  for (int i=0;i<8;i++){
    int row_l = i*8 + lrow;
    int rg = tb + row_l; if (rg >= lim) rg = lim-1;
    gp[i] = src + (size_t)rg*512 + (size_t)((lg ^ (row_l&7))*8);
  }

  f32x4 acc[4];
  #pragma unroll
  for (int mt=0;mt<4;mt++) acc[mt] = (f32x4){0.f,0.f,0.f,0.f};

  for (int ch=0; ch<8; ch++){
    __syncthreads();
    #pragma unroll
    for (int i=0;i<8;i++)
      GLOAD16(gp[i] + ch*64, dst + i*512);
    __syncthreads();
    #pragma unroll
    for (int ks=0; ks<2; ks++){
      int wrow = w*16 + l15;
      int wgs = (ks*4 + l4) ^ (wrow & 7);
      bf16x8 wh = *(const bf16x8*)&Whs[wrow*64 + wgs*8];
      bf16x8 wl = *(const bf16x8*)&Wls[wrow*64 + wgs*8];
      #pragma unroll
      for (int mt=0;mt<4;mt++){
        int arow = mt*16 + l15;
        int ags = (ks*4 + l4) ^ (arow & 7);
        bf16x8 ah = *(const bf16x8*)&Ahs[arow*64 + ags*8];
        bf16x8 al = *(const bf16x8*)&Als[arow*64 + ags*8];
        acc[mt] = __builtin_amdgcn_mfma_f32_16x16x32_bf16(ah, wh, acc[mt], 0,0,0);
        acc[mt] = __builtin_amdgcn_mfma_f32_16x16x32_bf16(ah, wl, acc[mt], 0,0,0);
        acc[mt] = __builtin_amdgcn_mfma_f32_16x16x32_bf16(al, wh, acc[mt], 0,0,0);
      }
    }
  }
  int ncol = bn + w*16 + l15;
  float bv = bias[ncol];
  #pragma unroll
  for (int mt=0;mt<4;mt++){
    #pragma unroll
    for (int r=0;r<4;r++){
      int mrow = bm + mt*16 + l4*4 + r;
      bool ok = (mrow < M) && ((mrow % S_TOT) < cnt[mrow / S_TOT]);
      if (ok) C[(size_t)mrow*N + ncol] = acc[mt][r] + bv;
    }
  }
}

// ---------------------------------------------------------------------------
// MFMA flash attention (layer 0), compacted keys; epilogue emits hi/lo bf16.
// ---------------------------------------------------------------------------
__global__ __launch_bounds__(256) void flash_attn_kernel(
    const float* __restrict__ qkv, const int* __restrict__ cnt,
    unsigned short* __restrict__ Oh, unsigned short* __restrict__ Ol) {
  int b = blockIdx.z, h = blockIdx.y;
  int cb = cnt[b];
  int S0 = blockIdx.x * 64;
  if (S0 >= cb) return;
  int t = threadIdx.x;
  int lane = t & 63, w = t >> 6;
  int l15 = lane & 15, l4 = lane >> 4;

  __shared__ unsigned short Kbf[64*64];
  __shared__ unsigned short Vt[64*64];
  __shared__ unsigned short Pbuf[4][16*64];

  const float* basep = qkv + (size_t)(b*S_TOT)*1536;

  int qg = S0 + w*16 + l15;
  int qr = (qg < cb) ? qg : 0;
  const float* qp = basep + (size_t)qr*1536 + h*64;
  bf16x8 Qf[2];
  #pragma unroll
  for (int c=0;c<2;c++){
    int d0 = c*32 + l4*8;
    float4 a = *(const float4*)(qp + d0);
    float4 bq = *(const float4*)(qp + d0 + 4);
    bf16x8 q8;
    q8[0]=(short)f2bf(a.x*0.125f);  q8[1]=(short)f2bf(a.y*0.125f);
    q8[2]=(short)f2bf(a.z*0.125f);  q8[3]=(short)f2bf(a.w*0.125f);
    q8[4]=(short)f2bf(bq.x*0.125f); q8[5]=(short)f2bf(bq.y*0.125f);
    q8[6]=(short)f2bf(bq.z*0.125f); q8[7]=(short)f2bf(bq.w*0.125f);
    Qf[c]=q8;
  }

  float m_run = -1e30f, l_run = 0.f;
  f32x4 accO[4];
  #pragma unroll
  for (int mt=0;mt<4;mt++) accO[mt] = (f32x4){0.f,0.f,0.f,0.f};

  unsigned int* Ku = (unsigned int*)Kbf;
  unsigned int* Vu = (unsigned int*)Vt;
  const int nt = (cb + 63)/64;
  for (int kt=0; kt<nt; kt++){
    int K0 = kt*64;
    __syncthreads();
    {
      int key = t>>2;
      int keyr = (K0+key < cb) ? (K0+key) : 0;
      const float* kp = basep + (size_t)keyr*1536 + 512 + h*64 + (t&3)*16;
      float4 x0 = *(const float4*)(kp);
      float4 x1 = *(const float4*)(kp+4);
      float4 x2 = *(const float4*)(kp+8);
      float4 x3 = *(const float4*)(kp+12);
      int g0 = (t&3)*2;
      int gs0 = g0 ^ (key&7), gs1 = (g0+1) ^ (key&7);
      uint4 pa, pb;
      pa.x = pk2(f2bf(x0.x), f2bf(x0.y)); pa.y = pk2(f2bf(x0.z), f2bf(x0.w));
      pa.z = pk2(f2bf(x1.x), f2bf(x1.y)); pa.w = pk2(f2bf(x1.z), f2bf(x1.w));
      pb.x = pk2(f2bf(x2.x), f2bf(x2.y)); pb.y = pk2(f2bf(x2.z), f2bf(x2.w));
      pb.z = pk2(f2bf(x3.x), f2bf(x3.y)); pb.w = pk2(f2bf(x3.z), f2bf(x3.w));
      *(uint4*)(Ku + key*32 + gs0*4) = pa;
      *(uint4*)(Ku + key*32 + gs1*4) = pb;
    }
    {
      int kp2 = t & 31;
      int d8 = t >> 5;
      int k0g = K0 + 2*kp2;
      int kr0 = (k0g   < cb) ? k0g   : 0;
      int kr1 = (k0g+1 < cb) ? k0g+1 : 0;
      const float* vp0 = basep + (size_t)kr0*1536 + 1024 + h*64 + d8*8;
      const float* vp1 = basep + (size_t)kr1*1536 + 1024 + h*64 + d8*8;
      float4 a0 = *(const float4*)(vp0);
      float4 a1 = *(const float4*)(vp0+4);
      float4 b0 = *(const float4*)(vp1);
      float4 b1 = *(const float4*)(vp1+4);
      float r0[8] = {a0.x,a0.y,a0.z,a0.w,a1.x,a1.y,a1.z,a1.w};
      float r1[8] = {b0.x,b0.y,b0.z,b0.w,b1.x,b1.y,b1.z,b1.w};
      int k8 = kp2 >> 2;
      #pragma unroll
      for (int dd=0; dd<8; dd++){
        int d = d8*8 + dd;
        Vu[d*32 + (k8 ^ (d&7))*4 + (kp2&3)] = pk2(f2bf(r0[dd]), f2bf(r1[dd]));
      }
    }
    __syncthreads();

    f32x4 acc[4];
    #pragma unroll
    for (int mt=0;mt<4;mt++) acc[mt] = (f32x4){0.f,0.f,0.f,0.f};
    #pragma unroll
    for (int mt=0;mt<4;mt++){
      int row = mt*16 + l15;
      #pragma unroll
      for (int c=0;c<2;c++){
        int gs = (c*4 + l4) ^ (row & 7);
        bf16x8 kf = *(const bf16x8*)&Kbf[row*64 + gs*8];
        acc[mt] = __builtin_amdgcn_mfma_f32_16x16x32_bf16(kf, Qf[c], acc[mt], 0,0,0);
      }
    }
    float p[4][4];
    float tmax = -1e30f;
    #pragma unroll
    for (int mt=0;mt<4;mt++)
      #pragma unroll
      for (int r=0;r<4;r++){
        int key = K0 + mt*16 + l4*4 + r;
        float s = (key < cb) ? acc[mt][r] : -1e30f;
        p[mt][r] = s;
        tmax = fmaxf(tmax, s);
      }
    tmax = fmaxf(tmax, __shfl_xor(tmax, 16));
    tmax = fmaxf(tmax, __shfl_xor(tmax, 32));
    float m_new = fmaxf(m_run, tmax);
    float alpha = __expf(m_run - m_new);
    float psum = 0.f;
    #pragma unroll
    for (int mt=0;mt<4;mt++)
      #pragma unroll
      for (int r=0;r<4;r++){
        float pv = __expf(p[mt][r] - m_new);
        p[mt][r] = pv; psum += pv;
      }
    psum += __shfl_xor(psum, 16);
    psum += __shfl_xor(psum, 32);
    l_run = l_run*alpha + psum;
    m_run = m_new;

    #pragma unroll
    for (int mt=0;mt<4;mt++){
      int keyl = mt*16 + l4*4;
      int gs = (keyl >> 3) ^ (l15 & 7);
      uint2 w2;
      w2.x = pk2(f2bf(p[mt][0]), f2bf(p[mt][1]));
      w2.y = pk2(f2bf(p[mt][2]), f2bf(p[mt][3]));
      *(uint2*)&Pbuf[w][ l15*64 + gs*8 + (keyl & 7) ] = w2;
    }
    #pragma unroll
    for (int mt=0;mt<4;mt++){
      accO[mt][0]*=alpha; accO[mt][1]*=alpha; accO[mt][2]*=alpha; accO[mt][3]*=alpha;
    }
    #pragma unroll
    for (int c2=0;c2<2;c2++){
      int gpv = (c2*4 + l4) ^ (l15 & 7);
      bf16x8 pf = *(const bf16x8*)&Pbuf[w][ l15*64 + gpv*8 ];
      #pragma unroll
      for (int mt=0;mt<4;mt++){
        int d = mt*16 + l15;
        int gv = (c2*4 + l4) ^ (d & 7);
        bf16x8 vf = *(const bf16x8*)&Vt[ d*64 + gv*8 ];
        accO[mt] = __builtin_amdgcn_mfma_f32_16x16x32_bf16(vf, pf, accO[mt], 0,0,0);
      }
    }
  }
  if (qg < cb){
    float inv = 1.f/l_run;
    size_t ro = ((size_t)(b*S_TOT) + qg)*512 + h*64;
    #pragma unroll
    for (int mt=0;mt<4;mt++){
      float v0 = accO[mt][0]*inv, v1 = accO[mt][1]*inv;
      float v2 = accO[mt][2]*inv, v3 = accO[mt][3]*inv;
      unsigned short h0=f2bf(v0), h1=f2bf(v1), h2=f2bf(v2), h3=f2bf(v3);
      uint2 hw; hw.x = pk2(h0,h1); hw.y = pk2(h2,h3);
      uint2 lw;
      lw.x = pk2(f2bf(v0-bfval(h0)), f2bf(v1-bfval(h1)));
      lw.y = pk2(f2bf(v2-bfval(h2)), f2bf(v3-bfval(h3)));
      *(uint2*)&Oh[ro + mt*16 + l4*4] = hw;
      *(uint2*)&Ol[ro + mt*16 + l4*4] = lw;
    }
  }
}

// ---------------------------------------------------------------------------
// Layer-1 attention, query 0 only, over compacted keys. Block per (h,b).
// ---------------------------------------------------------------------------
__global__ __launch_bounds__(256) void attn_row0_kernel(
    const float* __restrict__ qkv, const int* __restrict__ cnt,
    float* __restrict__ out0) {
  int h = blockIdx.x, b = blockIdx.y;
  int cb = cnt[b];
  int t = threadIdx.x;
  __shared__ float qs[64];
  __shared__ float sc[S_TOT];
  __shared__ float red[8];
  __shared__ float redO[4][64];
  const float* base = qkv + (size_t)b*S_TOT*1536;
  if (t < 64) qs[t] = base[h*64 + t]*0.125f;
  __syncthreads();
  float lmax = -1e30f;
  for (int j=t; j<cb; j+=256){
    const float* kp = base + (size_t)j*1536 + 512 + h*64;
    float s = 0.f;
    #pragma unroll
    for (int d4=0; d4<16; d4++){
      float4 kv = *(const float4*)(kp + d4*4);
      s += qs[d4*4+0]*kv.x + qs[d4*4+1]*kv.y + qs[d4*4+2]*kv.z + qs[d4*4+3]*kv.w;
    }
    sc[j]=s;
    lmax = fmaxf(lmax, s);
  }
  #pragma unroll
  for (int o=32;o;o>>=1) lmax = fmaxf(lmax, __shfl_down(lmax, o));
  if ((t&63)==0) red[t>>6]=lmax;
  __syncthreads();
  float m = fmaxf(fmaxf(red[0],red[1]),fmaxf(red[2],red[3]));
  float lsum = 0.f;
  for (int j=t;j<cb;j+=256){
    float p = expf(sc[j]-m);
    sc[j]=p; lsum+=p;
  }
  #pragma unroll
  for (int o=32;o;o>>=1) lsum += __shfl_down(lsum,o);
  __syncthreads();
  if ((t&63)==0) red[t>>6]=lsum;
  __syncthreads();
  float l = red[0]+red[1]+red[2]+red[3];
  int d = t & 63, rr = t >> 6;
  float acc = 0.f;
  for (int j=rr; j<cb; j+=4)
    acc += sc[j]*base[(size_t)j*1536 + 1024 + h*64 + d];
  redO[rr][d]=acc;
  __syncthreads();
  if (t < 64){
    float o = (redO[0][t]+redO[1][t]+redO[2][t]+redO[3][t])/l;
    out0[b*512 + h*64 + t] = o;
  }
}

// layer-1 out-proj for row 0 + residual(z row0) + LN -> cls embedding slot
__global__ __launch_bounds__(256) void row0_proj_ln_kernel(
    const float* __restrict__ attn0, const float* __restrict__ Wo, const float* __restrict__ bo,
    const unsigned short* __restrict__ Zh, const unsigned short* __restrict__ Zl,
    const float* __restrict__ g, const float* __restrict__ be,
    float* __restrict__ clsbuf, int branch) {
  int b = blockIdx.x, t = threadIdx.x;
  __shared__ float xin[512];
  __shared__ float y[512];
  __shared__ float red[16];
  for (int i=t;i<512;i+=256) xin[i] = attn0[b*512+i];
  __syncthreads();
  size_t z0 = (size_t)b*S_TOT*512;
  for (int n=t;n<512;n+=256){
    const float4* wr = (const float4*)(Wo + (size_t)n*512);
    float acc = bo[n];
    for (int k4=0;k4<128;k4++){
      float4 u = wr[k4]; int k=k4*4;
      acc += xin[k+0]*u.x + xin[k+1]*u.y + xin[k+2]*u.z + xin[k+3]*u.w;
    }
    y[n] = acc + bfval(Zh[z0+n]) + bfval(Zl[z0+n]);
  }
  __syncthreads();
  float s1=0.f, s2=0.f;
  for (int i=t;i<512;i+=256){ float a=y[i]; s1+=a; s2+=a*a; }
  #pragma unroll
  for (int o=32;o;o>>=1){ s1+=__shfl_down(s1,o); s2+=__shfl_down(s2,o); }
  if ((t&63)==0){ red[t>>6]=s1; red[8+(t>>6)]=s2; }
  __syncthreads();
  s1 = red[0]+red[1]+red[2]+red[3];
  s2 = red[8]+red[9]+red[10]+red[11];
  float mean = s1*(1.f/512.f);
  float var  = s2*(1.f/512.f) - mean*mean;
  float rn = rsqrtf(var + 1e-5f);
  for (int i=t;i<512;i+=256)
    clsbuf[b*1024 + branch*512 + i] = (y[i]-mean)*rn*g[i] + be[i];
}

// final projection MLP: [B,1024] -> 512 gelu -> 512 gelu -> 512, fp32 out
__global__ __launch_bounds__(256) void final_mlp_kernel(
    const float* __restrict__ emb,
    const float* __restrict__ W0, const float* __restrict__ b0,
    const float* __restrict__ W1, const float* __restrict__ b1,
    const float* __restrict__ W2, const float* __restrict__ b2,
    float* __restrict__ outp) {
  int b = blockIdx.x, t = threadIdx.x;
  __shared__ float e[1024];
  __shared__ float h1[512];
  __shared__ float h2[512];
  for (int i=t;i<1024;i+=256) e[i]=emb[b*1024+i];
  __syncthreads();
  for (int n=t;n<512;n+=256){
    const float4* w = (const float4*)(W0 + (size_t)n*1024);
    float acc = b0[n];
    for (int k4=0;k4<256;k4++){
      float4 u = w[k4]; int k=k4*4;
      acc += e[k+0]*u.x + e[k+1]*u.y + e[k+2]*u.z + e[k+3]*u.w;
    }
    h1[n]=gelu_exact(acc);
  }
  __syncthreads();
  for (int n=t;n<512;n+=256){
    const float4* w = (const float4*)(W1 + (size_t)n*512);
    float acc = b1[n];
    for (int k4=0;k4<128;k4++){
      float4 u = w[k4]; int k=k4*4;
      acc += h1[k+0]*u.x + h1[k+1]*u.y + h1[k+2]*u.z + h1[k+3]*u.w;
    }
    h2[n]=gelu_exact(acc);
  }
  __syncthreads();
  for (int n=t;n<512;n+=256){
    const float4* w = (const float4*)(W2 + (size_t)n*512);
    float acc = b2[n];
    for (int k4=0;k4<128;k4++){
      float4 u = w[k4]; int k=k4*4;
      acc += h2[k+0]*u.x + h2[k+1]*u.y + h2[k+2]*u.z + h2[k+3]*u.w;
    }
    outp[b*512+n] = acc;
  }
}

// ---------------------------------------------------------------------------
extern "C" void kernel_launch(void* const* d_in, const int* in_sizes, int n_in,
                              void* d_out, int out_size, void* d_ws, size_t ws_size,
                              hipStream_t stream) {
  const float* x      = (const float*)d_in[0];
  const float* cls_tk = (const float*)d_in[1];
  const float* ln_g   = (const float*)d_in[2];
  const float* ln_b   = (const float*)d_in[3];
  const float* aw_W0  = (const float*)d_in[4];  const float* aw_b0 = (const float*)d_in[5];
  const float* aw_W1  = (const float*)d_in[6];  const float* aw_b1 = (const float*)d_in[7];
  const float* aw_W2  = (const float*)d_in[8];  const float* aw_b2 = (const float*)d_in[9];
  const float* pr_W0  = (const float*)d_in[10]; const float* pr_b0 = (const float*)d_in[11];
  const float* pr_W1  = (const float*)d_in[12]; const float* pr_b1 = (const float*)d_in[13];
  const float* pr_W2  = (const float*)d_in[14]; const float* pr_b2 = (const float*)d_in[15];
  const float* mWqkv[2] = {(const float*)d_in[16], (const float*)d_in[20]};
  const float* mbqkv[2] = {(const float*)d_in[17], (const float*)d_in[21]};
  const float* mWo[2]   = {(const float*)d_in[18], (const float*)d_in[22]};
  const float* mbo[2]   = {(const float*)d_in[19], (const float*)d_in[23]};

  float* ws = (float*)d_ws;
  size_t off = 0;
  float* weight = ws + off; off += 8192;                      // [B,N]
  int*   idx    = (int*)(ws + off); off += 8448;              // [B,S]
  int*   cnt    = (int*)(ws + off); off += 16;                // [B]
  float* W0T    = ws + off; off += 32768;                     // [512][64] transposed gating W0
  const size_t HBUF = (size_t)ROWS*512/2;                     // bf16 array in float units
  unsigned short* Zh = (unsigned short*)(ws + off); off += HBUF;
  unsigned short* Zl = (unsigned short*)(ws + off); off += HBUF;
  float* QKV    = ws + off; off += (size_t)ROWS*1536;
  float* T2     = QKV;                                        // alias: dead QKV space
  unsigned short* Oh = (unsigned short*)(ws + off); off += HBUF;  // also a1 hi
  unsigned short* Ol = (unsigned short*)(ws + off); off += HBUF;  // also a1 lo
  unsigned short* Wq0h = (unsigned short*)(ws + off); off += 393216;
  unsigned short* Wq0l = (unsigned short*)(ws + off); off += 393216;
  unsigned short* Wq1h = (unsigned short*)(ws + off); off += 393216;
  unsigned short* Wq1l = (unsigned short*)(ws + off); off += 393216;
  unsigned short* Wo0h = (unsigned short*)(ws + off); off += 131072;
  unsigned short* Wo0l = (unsigned short*)(ws + off); off += 131072;
  float* attn0  = ws + off; off += 2048;                      // [B,D]
  float* clsb   = ws + off; off += 4096;                      // [B,2D]
  (void)ws_size; (void)in_sizes; (void)n_in; (void)out_size;

  transpose_w0_kernel<<<(32768+255)/256, 256, 0, stream>>>(aw_W0, W0T);
  aw_weight_kernel<<<B_SZ*N_INST, 64, 0, stream>>>(
      x, W0T, aw_b0, aw_W1, aw_b1, aw_W2, aw_b2, weight);

  split_kernel<<<(786432+255)/256, 256, 0, stream>>>(mWqkv[0], Wq0h, Wq0l, 786432);
  split_kernel<<<(786432+255)/256, 256, 0, stream>>>(mWqkv[1], Wq1h, Wq1l, 786432);
  split_kernel<<<(262144+255)/256, 256, 0, stream>>>(mWo[0],  Wo0h, Wo0l, 262144);

  for (int br=0; br<2; br++){
    compact_kernel<<<B_SZ, 256, 0, stream>>>(weight, br, idx, cnt);
    build_z_kernel<<<ROWS, 256, 0, stream>>>(x, weight, cls_tk, ln_g, ln_b, br, idx, cnt, Zh, Zl);
    // layer 0
    mfma_gemm_kernel<<<dim3(1536/64, (ROWS+63)/64), 256, 0, stream>>>(
        Zh, Zl, Wq0h, Wq0l, mbqkv[0], QKV, ROWS, 1536, cnt);
    flash_attn_kernel<<<dim3((S_TOT+63)/64, NH, B_SZ), 256, 0, stream>>>(QKV, cnt, Oh, Ol);
    mfma_gemm_kernel<<<dim3(512/64, (ROWS+63)/64), 256, 0, stream>>>(
        Oh, Ol, Wo0h, Wo0l, mbo[0], T2, ROWS, 512, cnt);
    add_ln_kernel<<<ROWS, 256, 0, stream>>>(Zh, Zl, T2, ln_g, ln_b, cnt, Oh, Ol); // a1 -> Oh/Ol
    // layer 1 (only row 0 consumed)
    mfma_gemm_kernel<<<dim3(1536/64, (ROWS+63)/64), 256, 0, stream>>>(
        Oh, Ol, Wq1h, Wq1l, mbqkv[1], QKV, ROWS, 1536, cnt);
    attn_row0_kernel<<<dim3(NH, B_SZ), 256, 0, stream>>>(QKV, cnt, attn0);
    row0_proj_ln_kernel<<<B_SZ, 256, 0, stream>>>(
        attn0, mWo[1], mbo[1], Zh, Zl, ln_g, ln_b, clsb, br);
  }
  final_mlp_kernel<<<B_SZ, 256, 0, stream>>>(
      clsb, pr_W0, pr_b0, pr_W1, pr_b1, pr_W2, pr_b2, (float*)d_out);
}

// Round 8
// 747.419 us; speedup vs baseline: 5.3139x; 1.2202x over previous
//
#include <hip/hip_runtime.h>
#include <hip/hip_bf16.h>

#define B_SZ 4
#define N_INST 2048
#define D_MODEL 512
#define S_TOT 2049          // N+1 (cls prepended)
#define NH 8
#define HD 64
#define ROWS (B_SZ*S_TOT)   // 8196

typedef __attribute__((ext_vector_type(4))) float f32x4;
typedef __attribute__((ext_vector_type(8))) short bf16x8;

__device__ __forceinline__ float gelu_exact(float x){ return 0.5f*x*(1.f+erff(x*0.70710678118654752f)); }
__device__ __forceinline__ unsigned short f2bf(float x){
  unsigned int u = __float_as_uint(x);
  u += 0x7fffu + ((u>>16)&1u);
  return (unsigned short)(u>>16);
}
__device__ __forceinline__ float bfval(unsigned short u){ return __uint_as_float(((unsigned int)u)<<16); }
__device__ __forceinline__ unsigned int pk2(unsigned short lo, unsigned short hi){
  return (unsigned int)lo | ((unsigned int)hi << 16);
}

#define GLOAD16(gp, lp) __builtin_amdgcn_global_load_lds( \
    (const __attribute__((address_space(1))) void*)(gp), \
    (__attribute__((address_space(3))) void*)(lp), 16, 0, 0)

// ---------------------------------------------------------------------------
// One-time transpose: W0T[k][h] = W0[h][k]   (64x512 -> 512x64, fp32)
// ---------------------------------------------------------------------------
__global__ __launch_bounds__(256) void transpose_w0_kernel(
    const float* __restrict__ W0, float* __restrict__ W0T) {
  int i = blockIdx.x*256 + threadIdx.x;
  if (i < 64*512){
    int h = i >> 9, k = i & 511;
    W0T[k*64 + h] = W0[i];
  }
}

// ---------------------------------------------------------------------------
// Gating MLP: weight[b,n] = sigmoid(MLP(x[b,n,:])). fp32 throughout — the
// w<0.5 mask is a threshold; bf16 logits risk borderline branch flips.
// ---------------------------------------------------------------------------
__global__ __launch_bounds__(64) void aw_weight_kernel(
    const float* __restrict__ x,
    const float* __restrict__ W0T, const float* __restrict__ b0,
    const float* __restrict__ W1, const float* __restrict__ b1,
    const float* __restrict__ W2, const float* __restrict__ b2,
    float* __restrict__ weight) {
  int inst = blockIdx.x;
  int h = threadIdx.x;
  __shared__ float xs[512];
  __shared__ float hs[64];
  const float* xp = x + (size_t)inst*D_MODEL;
  for (int i=h;i<512;i+=64) xs[i] = xp[i];
  __syncthreads();
  float acc = b0[h];
  const float* w0c = W0T + h;
  #pragma unroll 16
  for (int k=0;k<512;k++)
    acc = fmaf(xs[k], w0c[k*64], acc);
  hs[h] = gelu_exact(acc);
  __syncthreads();
  const float4* w1 = (const float4*)(W1 + (size_t)h*64);
  float acc2 = b1[h];
  #pragma unroll
  for (int k4=0;k4<16;k4++){
    float4 u = w1[k4]; int k = k4*4;
    acc2 += hs[k+0]*u.x + hs[k+1]*u.y + hs[k+2]*u.z + hs[k+3]*u.w;
  }
  float h2 = gelu_exact(acc2);
  float p = h2 * W2[h];
  #pragma unroll
  for (int o=32;o;o>>=1) p += __shfl_down(p, o);
  if (h==0){
    float s = p + b2[0];
    weight[inst] = 1.f/(1.f+expf(-s));
  }
}

// ---------------------------------------------------------------------------
// Split fp32 -> (hi, lo) bf16 pair.
// ---------------------------------------------------------------------------
__global__ __launch_bounds__(256) void split_kernel(
    const float* __restrict__ w, unsigned short* __restrict__ hi,
    unsigned short* __restrict__ lo, int n) {
  int i = blockIdx.x*256 + threadIdx.x;
  if (i < n){
    float v = w[i];
    unsigned short h = f2bf(v);
    hi[i] = h;
    lo[i] = f2bf(v - bfval(h));
  }
}

// ---------------------------------------------------------------------------
// Compaction: per batch, ascending list of valid seq positions (slot0 = cls).
// ---------------------------------------------------------------------------
__global__ __launch_bounds__(256) void compact_kernel(
    const float* __restrict__ weight, int branch,
    int* __restrict__ idx, int* __restrict__ cnt) {
  int b = blockIdx.x;
  int t = threadIdx.x;
  int lane = t & 63, wv = t >> 6;
  __shared__ int wsum[4];
  __shared__ int base_s;
  if (t==0){ idx[b*S_TOT] = 0; base_s = 1; }
  __syncthreads();
  for (int c0=0; c0<N_INST; c0+=256){
    int n = c0 + t;
    float w = weight[b*N_INST + n];
    bool neg = (w < 0.5f);
    bool val = (branch==0) ? neg : !neg;
    unsigned long long m = __ballot(val);
    int prefix = __popcll(m & ((1ull<<lane)-1ull));
    if (lane==0) wsum[wv] = __popcll(m);
    __syncthreads();
    int wbase = 0;
    #pragma unroll
    for (int i=0;i<4;i++) if (i<wv) wbase += wsum[i];
    int total = wsum[0]+wsum[1]+wsum[2]+wsum[3];
    int mybase = base_s;
    if (val) idx[b*S_TOT + mybase + wbase + prefix] = n + 1;
    __syncthreads();
    if (t==0) base_s += total;
    __syncthreads();
  }
  if (t==0) cnt[b] = base_s;
}

// ---------------------------------------------------------------------------
// Build compacted z = LN(scale*seq[idx]) -> hi/lo bf16 pair.
// ---------------------------------------------------------------------------
__global__ __launch_bounds__(256) void build_z_kernel(
    const float* __restrict__ x, const float* __restrict__ weight,
    const float* __restrict__ cls, const float* __restrict__ g, const float* __restrict__ be,
    int branch, const int* __restrict__ idx, const int* __restrict__ cnt,
    unsigned short* __restrict__ Zh, unsigned short* __restrict__ Zl) {
  int row = blockIdx.x;
  int b = row / S_TOT, slot = row % S_TOT;
  if (slot >= cnt[b]) return;
  int t = threadIdx.x;
  __shared__ float v[512];
  __shared__ float red[16];
  int pos = idx[b*S_TOT + slot];
  float scale = 1.f;
  const float* src = cls;
  if (pos != 0){
    float w = weight[b*N_INST + (pos-1)];
    scale = (branch==0) ? powf(w, 1.5f) : powf(w, 2.0f/3.0f);
    src = x + ((size_t)b*N_INST + (pos-1))*D_MODEL;
  }
  float s1=0.f, s2=0.f;
  for (int i=t;i<512;i+=256){
    float val = src[i];
    if (pos != 0) val *= scale;
    v[i]=val; s1+=val; s2+=val*val;
  }
  __syncthreads();
  #pragma unroll
  for (int o=32;o;o>>=1){ s1+=__shfl_down(s1,o); s2+=__shfl_down(s2,o); }
  if ((t&63)==0){ red[t>>6]=s1; red[8+(t>>6)]=s2; }
  __syncthreads();
  s1 = red[0]+red[1]+red[2]+red[3];
  s2 = red[8]+red[9]+red[10]+red[11];
  float mean = s1 * (1.f/512.f);
  float var  = s2 * (1.f/512.f) - mean*mean;
  float rn = rsqrtf(var + 1e-5f);
  size_t ro = (size_t)row*512;
  for (int i=t;i<512;i+=256){
    float o = (v[i]-mean)*rn*g[i] + be[i];
    unsigned short hbits = f2bf(o);
    Zh[ro+i] = hbits;
    Zl[ro+i] = f2bf(o - bfval(hbits));
  }
}

// out = LN((Zh+Zl) + T2) rowwise -> hi/lo bf16 pair (the a1 operand)
__global__ __launch_bounds__(256) void add_ln_kernel(
    const unsigned short* __restrict__ Zh, const unsigned short* __restrict__ Zl,
    const float* __restrict__ T2,
    const float* __restrict__ g, const float* __restrict__ be,
    const int* __restrict__ cnt,
    unsigned short* __restrict__ Ah, unsigned short* __restrict__ Al) {
  int row = blockIdx.x;
  if ((row % S_TOT) >= cnt[row / S_TOT]) return;
  int t = threadIdx.x;
  __shared__ float v[512];
  __shared__ float red[16];
  size_t ro = (size_t)row*512;
  float s1=0.f, s2=0.f;
  for (int i=t;i<512;i+=256){
    float val = bfval(Zh[ro+i]) + bfval(Zl[ro+i]) + T2[ro+i];
    v[i]=val; s1+=val; s2+=val*val;
  }
  __syncthreads();
  #pragma unroll
  for (int o=32;o;o>>=1){ s1+=__shfl_down(s1,o); s2+=__shfl_down(s2,o); }
  if ((t&63)==0){ red[t>>6]=s1; red[8+(t>>6)]=s2; }
  __syncthreads();
  s1 = red[0]+red[1]+red[2]+red[3];
  s2 = red[8]+red[9]+red[10]+red[11];
  float mean = s1 * (1.f/512.f);
  float var  = s2 * (1.f/512.f) - mean*mean;
  float rn = rsqrtf(var + 1e-5f);
  for (int i=t;i<512;i+=256){
    float o = (v[i]-mean)*rn*g[i] + be[i];
    unsigned short hbits = f2bf(o);
    Ah[ro+i] = hbits;
    Al[ro+i] = f2bf(o - bfval(hbits));
  }
}

// ---------------------------------------------------------------------------
// MFMA GEMM (bf16 hi/lo 3-pass): C[M,N] = (Ah+Al)[M,512] @ (Wh+Wl)[N,512]^T + bias.
// 64x64 tile, BK=64, 4 waves; wave w stages one operand, owns n-strip w*16.
// ---------------------------------------------------------------------------
__global__ __launch_bounds__(256) void mfma_gemm_kernel(
    const unsigned short* __restrict__ Ahg, const unsigned short* __restrict__ Alg,
    const unsigned short* __restrict__ Whg, const unsigned short* __restrict__ Wlg,
    const float* __restrict__ bias, float* __restrict__ C,
    int M, int N, const int* __restrict__ cnt) {
  int t = threadIdx.x;
  int bm = blockIdx.y*64, bn = blockIdx.x*64;
  {
    int r = bm + (t>>2);
    bool ok = (r < M) && ((r % S_TOT) < cnt[r / S_TOT]);
    if (__syncthreads_or(ok ? 1 : 0) == 0) return;
  }
  __shared__ unsigned short Ahs[64*64], Als[64*64], Whs[64*64], Wls[64*64];
  int lane = t & 63, w = t >> 6;
  int l15 = lane & 15, l4 = lane >> 4;

  const unsigned short* src;
  unsigned short* dst;
  if      (w == 0){ src = Ahg; dst = Ahs; }
  else if (w == 1){ src = Alg; dst = Als; }
  else if (w == 2){ src = Whg; dst = Whs; }
  else            { src = Wlg; dst = Wls; }
  int tb  = (w < 2) ? bm : bn;
  int lim = (w < 2) ? M  : N;
  int lrow = lane >> 3;
  int lg   = lane & 7;
  const unsigned short* gp[8];
  #pragma unroll
  for (int i=0;i<8;i++){
    int row_l = i*8 + lrow;
    int rg = tb + row_l; if (rg >= lim) rg = lim-1;
    gp[i] = src + (size_t)rg*512 + (size_t)((lg ^ (row_l&7))*8);
  }

  f32x4 acc[4];
  #pragma unroll
  for (int mt=0;mt<4;mt++) acc[mt] = (f32x4){0.f,0.f,0.f,0.f};

  for (int ch=0; ch<8; ch++){
    __syncthreads();
    #pragma unroll
    for (int i=0;i<8;i++)
      GLOAD16(gp[i] + ch*64, dst + i*512);
    __syncthreads();
    #pragma unroll
    for (int ks=0; ks<2; ks++){
      int wrow = w*16 + l15;
      int wgs = (ks*4 + l4) ^ (wrow & 7);
      bf16x8 wh = *(const bf16x8*)&Whs[wrow*64 + wgs*8];
      bf16x8 wl = *(const bf16x8*)&Wls[wrow*64 + wgs*8];
      #pragma unroll
      for (int mt=0;mt<4;mt++){
        int arow = mt*16 + l15;
        int ags = (ks*4 + l4) ^ (arow & 7);
        bf16x8 ah = *(const bf16x8*)&Ahs[arow*64 + ags*8];
        bf16x8 al = *(const bf16x8*)&Als[arow*64 + ags*8];
        acc[mt] = __builtin_amdgcn_mfma_f32_16x16x32_bf16(ah, wh, acc[mt], 0,0,0);
        acc[mt] = __builtin_amdgcn_mfma_f32_16x16x32_bf16(ah, wl, acc[mt], 0,0,0);
        acc[mt] = __builtin_amdgcn_mfma_f32_16x16x32_bf16(al, wh, acc[mt], 0,0,0);
      }
    }
  }
  int ncol = bn + w*16 + l15;
  float bv = bias[ncol];
  #pragma unroll
  for (int mt=0;mt<4;mt++){
    #pragma unroll
    for (int r=0;r<4;r++){
      int mrow = bm + mt*16 + l4*4 + r;
      bool ok = (mrow < M) && ((mrow % S_TOT) < cnt[mrow / S_TOT]);
      if (ok) C[(size_t)mrow*N + ncol] = acc[mt][r] + bv;
    }
  }
}

// ---------------------------------------------------------------------------
// MFMA flash attention (layer 0), compacted keys; epilogue emits hi/lo bf16.
// ---------------------------------------------------------------------------
__global__ __launch_bounds__(256) void flash_attn_kernel(
    const float* __restrict__ qkv, const int* __restrict__ cnt,
    unsigned short* __restrict__ Oh, unsigned short* __restrict__ Ol) {
  int b = blockIdx.z, h = blockIdx.y;
  int cb = cnt[b];
  int S0 = blockIdx.x * 64;
  if (S0 >= cb) return;
  int t = threadIdx.x;
  int lane = t & 63, w = t >> 6;
  int l15 = lane & 15, l4 = lane >> 4;

  __shared__ unsigned short Kbf[64*64];
  __shared__ unsigned short Vt[64*64];
  __shared__ unsigned short Pbuf[4][16*64];

  const float* basep = qkv + (size_t)(b*S_TOT)*1536;

  int qg = S0 + w*16 + l15;
  int qr = (qg < cb) ? qg : 0;
  const float* qp = basep + (size_t)qr*1536 + h*64;
  bf16x8 Qf[2];
  #pragma unroll
  for (int c=0;c<2;c++){
    int d0 = c*32 + l4*8;
    float4 a = *(const float4*)(qp + d0);
    float4 bq = *(const float4*)(qp + d0 + 4);
    bf16x8 q8;
    q8[0]=(short)f2bf(a.x*0.125f);  q8[1]=(short)f2bf(a.y*0.125f);
    q8[2]=(short)f2bf(a.z*0.125f);  q8[3]=(short)f2bf(a.w*0.125f);
    q8[4]=(short)f2bf(bq.x*0.125f); q8[5]=(short)f2bf(bq.y*0.125f);
    q8[6]=(short)f2bf(bq.z*0.125f); q8[7]=(short)f2bf(bq.w*0.125f);
    Qf[c]=q8;
  }

  float m_run = -1e30f, l_run = 0.f;
  f32x4 accO[4];
  #pragma unroll
  for (int mt=0;mt<4;mt++) accO[mt] = (f32x4){0.f,0.f,0.f,0.f};

  unsigned int* Ku = (unsigned int*)Kbf;
  unsigned int* Vu = (unsigned int*)Vt;
  const int nt = (cb + 63)/64;
  for (int kt=0; kt<nt; kt++){
    int K0 = kt*64;
    __syncthreads();
    {
      int key = t>>2;
      int keyr = (K0+key < cb) ? (K0+key) : 0;
      const float* kp = basep + (size_t)keyr*1536 + 512 + h*64 + (t&3)*16;
      float4 x0 = *(const float4*)(kp);
      float4 x1 = *(const float4*)(kp+4);
      float4 x2 = *(const float4*)(kp+8);
      float4 x3 = *(const float4*)(kp+12);
      int g0 = (t&3)*2;
      int gs0 = g0 ^ (key&7), gs1 = (g0+1) ^ (key&7);
      uint4 pa, pb;
      pa.x = pk2(f2bf(x0.x), f2bf(x0.y)); pa.y = pk2(f2bf(x0.z), f2bf(x0.w));
      pa.z = pk2(f2bf(x1.x), f2bf(x1.y)); pa.w = pk2(f2bf(x1.z), f2bf(x1.w));
      pb.x = pk2(f2bf(x2.x), f2bf(x2.y)); pb.y = pk2(f2bf(x2.z), f2bf(x2.w));
      pb.z = pk2(f2bf(x3.x), f2bf(x3.y)); pb.w = pk2(f2bf(x3.z), f2bf(x3.w));
      *(uint4*)(Ku + key*32 + gs0*4) = pa;
      *(uint4*)(Ku + key*32 + gs1*4) = pb;
    }
    {
      int kp2 = t & 31;
      int d8 = t >> 5;
      int k0g = K0 + 2*kp2;
      int kr0 = (k0g   < cb) ? k0g   : 0;
      int kr1 = (k0g+1 < cb) ? k0g+1 : 0;
      const float* vp0 = basep + (size_t)kr0*1536 + 1024 + h*64 + d8*8;
      const float* vp1 = basep + (size_t)kr1*1536 + 1024 + h*64 + d8*8;
      float4 a0 = *(const float4*)(vp0);
      float4 a1 = *(const float4*)(vp0+4);
      float4 b0 = *(const float4*)(vp1);
      float4 b1 = *(const float4*)(vp1+4);
      float r0[8] = {a0.x,a0.y,a0.z,a0.w,a1.x,a1.y,a1.z,a1.w};
      float r1[8] = {b0.x,b0.y,b0.z,b0.w,b1.x,b1.y,b1.z,b1.w};
      int k8 = kp2 >> 2;
      #pragma unroll
      for (int dd=0; dd<8; dd++){
        int d = d8*8 + dd;
        Vu[d*32 + (k8 ^ (d&7))*4 + (kp2&3)] = pk2(f2bf(r0[dd]), f2bf(r1[dd]));
      }
    }
    __syncthreads();

    f32x4 acc[4];
    #pragma unroll
    for (int mt=0;mt<4;mt++) acc[mt] = (f32x4){0.f,0.f,0.f,0.f};
    #pragma unroll
    for (int mt=0;mt<4;mt++){
      int row = mt*16 + l15;
      #pragma unroll
      for (int c=0;c<2;c++){
        int gs = (c*4 + l4) ^ (row & 7);
        bf16x8 kf = *(const bf16x8*)&Kbf[row*64 + gs*8];
        acc[mt] = __builtin_amdgcn_mfma_f32_16x16x32_bf16(kf, Qf[c], acc[mt], 0,0,0);
      }
    }
    float p[4][4];
    float tmax = -1e30f;
    #pragma unroll
    for (int mt=0;mt<4;mt++)
      #pragma unroll
      for (int r=0;r<4;r++){
        int key = K0 + mt*16 + l4*4 + r;
        float s = (key < cb) ? acc[mt][r] : -1e30f;
        p[mt][r] = s;
        tmax = fmaxf(tmax, s);
      }
    tmax = fmaxf(tmax, __shfl_xor(tmax, 16));
    tmax = fmaxf(tmax, __shfl_xor(tmax, 32));
    float m_new = fmaxf(m_run, tmax);
    float alpha = __expf(m_run - m_new);
    float psum = 0.f;
    #pragma unroll
    for (int mt=0;mt<4;mt++)
      #pragma unroll
      for (int r=0;r<4;r++){
        float pv = __expf(p[mt][r] - m_new);
        p[mt][r] = pv; psum += pv;
      }
    psum += __shfl_xor(psum, 16);
    psum += __shfl_xor(psum, 32);
    l_run = l_run*alpha + psum;
    m_run = m_new;

    #pragma unroll
    for (int mt=0;mt<4;mt++){
      int keyl = mt*16 + l4*4;
      int gs = (keyl >> 3) ^ (l15 & 7);
      uint2 w2;
      w2.x = pk2(f2bf(p[mt][0]), f2bf(p[mt][1]));
      w2.y = pk2(f2bf(p[mt][2]), f2bf(p[mt][3]));
      *(uint2*)&Pbuf[w][ l15*64 + gs*8 + (keyl & 7) ] = w2;
    }
    #pragma unroll
    for (int mt=0;mt<4;mt++){
      accO[mt][0]*=alpha; accO[mt][1]*=alpha; accO[mt][2]*=alpha; accO[mt][3]*=alpha;
    }
    #pragma unroll
    for (int c2=0;c2<2;c2++){
      int gpv = (c2*4 + l4) ^ (l15 & 7);
      bf16x8 pf = *(const bf16x8*)&Pbuf[w][ l15*64 + gpv*8 ];
      #pragma unroll
      for (int mt=0;mt<4;mt++){
        int d = mt*16 + l15;
        int gv = (c2*4 + l4) ^ (d & 7);
        bf16x8 vf = *(const bf16x8*)&Vt[ d*64 + gv*8 ];
        accO[mt] = __builtin_amdgcn_mfma_f32_16x16x32_bf16(vf, pf, accO[mt], 0,0,0);
      }
    }
  }
  if (qg < cb){
    float inv = 1.f/l_run;
    size_t ro = ((size_t)(b*S_TOT) + qg)*512 + h*64;
    #pragma unroll
    for (int mt=0;mt<4;mt++){
      float v0 = accO[mt][0]*inv, v1 = accO[mt][1]*inv;
      float v2 = accO[mt][2]*inv, v3 = accO[mt][3]*inv;
      unsigned short h0=f2bf(v0), h1=f2bf(v1), h2=f2bf(v2), h3=f2bf(v3);
      uint2 hw; hw.x = pk2(h0,h1); hw.y = pk2(h2,h3);
      uint2 lw;
      lw.x = pk2(f2bf(v0-bfval(h0)), f2bf(v1-bfval(h1)));
      lw.y = pk2(f2bf(v2-bfval(h2)), f2bf(v3-bfval(h3)));
      *(uint2*)&Oh[ro + mt*16 + l4*4] = hw;
      *(uint2*)&Ol[ro + mt*16 + l4*4] = lw;
    }
  }
}

// ---------------------------------------------------------------------------
// q0[b][n] = bq[n] + dot(Wq_row_n, a1[b,row0]); wave-per-neuron, fp32 exact.
// a1 row0 reconstructed from hi/lo bf16 (lossless to fp32 sum).
// ---------------------------------------------------------------------------
__global__ __launch_bounds__(256) void row0_q_kernel(
    const unsigned short* __restrict__ Ah, const unsigned short* __restrict__ Al,
    const float* __restrict__ Wq, const float* __restrict__ bq,
    float* __restrict__ q0) {
  int b = blockIdx.y;
  int n = blockIdx.x*4 + (threadIdx.x >> 6);
  int lane = threadIdx.x & 63;
  __shared__ float xs[512];
  size_t ro = (size_t)(b*S_TOT)*512;
  for (int i=threadIdx.x; i<512; i+=256)
    xs[i] = bfval(Ah[ro+i]) + bfval(Al[ro+i]);
  __syncthreads();
  const float* wr = Wq + (size_t)n*512;
  float acc = 0.f;
  #pragma unroll
  for (int k=lane*4; k<512; k+=256){
    float4 u = *(const float4*)(wr + k);
    acc += xs[k]*u.x + xs[k+1]*u.y + xs[k+2]*u.z + xs[k+3]*u.w;
  }
  #pragma unroll
  for (int o=32;o;o>>=1) acc += __shfl_down(acc, o);
  if (lane==0) q0[b*512 + n] = acc + bq[n];
}

// ---------------------------------------------------------------------------
// Layer-1 attention, query 0 only, over compacted keys in KV buffer
// (row stride 1024: K at [0,512), V at [512,1024)). 2-way ILP on key loops.
// ---------------------------------------------------------------------------
__global__ __launch_bounds__(256) void attn_row0_kernel(
    const float* __restrict__ kv, const float* __restrict__ q0,
    const int* __restrict__ cnt, float* __restrict__ out0) {
  int h = blockIdx.x, b = blockIdx.y;
  int cb = cnt[b];
  int t = threadIdx.x;
  __shared__ float qs[64];
  __shared__ float sc[S_TOT];
  __shared__ float red[8];
  __shared__ float redO[4][64];
  const float* base = kv + (size_t)b*S_TOT*1024;
  if (t < 64) qs[t] = q0[b*512 + h*64 + t]*0.125f;
  __syncthreads();
  float lmax = -1e30f;
  for (int j=t; j<cb; j+=512){
    int j2 = j + 256;
    bool v2 = j2 < cb;
    const float* kp0 = base + (size_t)j*1024 + h*64;
    const float* kp1 = base + (size_t)(v2 ? j2 : j)*1024 + h*64;
    float s0 = 0.f, s1 = 0.f;
    #pragma unroll
    for (int d4=0; d4<16; d4++){
      float4 a = *(const float4*)(kp0 + d4*4);
      float4 c = *(const float4*)(kp1 + d4*4);
      s0 += qs[d4*4+0]*a.x + qs[d4*4+1]*a.y + qs[d4*4+2]*a.z + qs[d4*4+3]*a.w;
      s1 += qs[d4*4+0]*c.x + qs[d4*4+1]*c.y + qs[d4*4+2]*c.z + qs[d4*4+3]*c.w;
    }
    sc[j] = s0; lmax = fmaxf(lmax, s0);
    if (v2){ sc[j2] = s1; lmax = fmaxf(lmax, s1); }
  }
  #pragma unroll
  for (int o=32;o;o>>=1) lmax = fmaxf(lmax, __shfl_down(lmax, o));
  if ((t&63)==0) red[t>>6]=lmax;
  __syncthreads();
  float m = fmaxf(fmaxf(red[0],red[1]),fmaxf(red[2],red[3]));
  float lsum = 0.f;
  for (int j=t;j<cb;j+=256){
    float p = expf(sc[j]-m);
    sc[j]=p; lsum+=p;
  }
  #pragma unroll
  for (int o=32;o;o>>=1) lsum += __shfl_down(lsum,o);
  __syncthreads();
  if ((t&63)==0) red[t>>6]=lsum;
  __syncthreads();
  float l = red[0]+red[1]+red[2]+red[3];
  int d = t & 63, rr = t >> 6;
  float acc = 0.f;
  for (int j=rr; j<cb; j+=8){
    int j2 = j + 4;
    bool v2 = j2 < cb;
    float p0 = sc[j];
    float p1 = v2 ? sc[j2] : 0.f;
    float va = base[(size_t)j*1024 + 512 + h*64 + d];
    float vb = base[(size_t)(v2 ? j2 : j)*1024 + 512 + h*64 + d];
    acc += p0*va + p1*vb;
  }
  redO[rr][d]=acc;
  __syncthreads();
  if (t < 64){
    float o = (redO[0][t]+redO[1][t]+redO[2][t]+redO[3][t])/l;
    out0[b*512 + h*64 + t] = o;
  }
}

// layer-1 out-proj for row 0 + residual(z row0) + LN -> cls embedding slot
__global__ __launch_bounds__(256) void row0_proj_ln_kernel(
    const float* __restrict__ attn0, const float* __restrict__ Wo, const float* __restrict__ bo,
    const unsigned short* __restrict__ Zh, const unsigned short* __restrict__ Zl,
    const float* __restrict__ g, const float* __restrict__ be,
    float* __restrict__ clsbuf, int branch) {
  int b = blockIdx.x, t = threadIdx.x;
  __shared__ float xin[512];
  __shared__ float y[512];
  __shared__ float red[16];
  for (int i=t;i<512;i+=256) xin[i] = attn0[b*512+i];
  __syncthreads();
  size_t z0 = (size_t)b*S_TOT*512;
  for (int n=t;n<512;n+=256){
    const float4* wr = (const float4*)(Wo + (size_t)n*512);
    float acc = bo[n];
    for (int k4=0;k4<128;k4++){
      float4 u = wr[k4]; int k=k4*4;
      acc += xin[k+0]*u.x + xin[k+1]*u.y + xin[k+2]*u.z + xin[k+3]*u.w;
    }
    y[n] = acc + bfval(Zh[z0+n]) + bfval(Zl[z0+n]);
  }
  __syncthreads();
  float s1=0.f, s2=0.f;
  for (int i=t;i<512;i+=256){ float a=y[i]; s1+=a; s2+=a*a; }
  #pragma unroll
  for (int o=32;o;o>>=1){ s1+=__shfl_down(s1,o); s2+=__shfl_down(s2,o); }
  if ((t&63)==0){ red[t>>6]=s1; red[8+(t>>6)]=s2; }
  __syncthreads();
  s1 = red[0]+red[1]+red[2]+red[3];
  s2 = red[8]+red[9]+red[10]+red[11];
  float mean = s1*(1.f/512.f);
  float var  = s2*(1.f/512.f) - mean*mean;
  float rn = rsqrtf(var + 1e-5f);
  for (int i=t;i<512;i+=256)
    clsbuf[b*1024 + branch*512 + i] = (y[i]-mean)*rn*g[i] + be[i];
}

// ---------------------------------------------------------------------------
// Final MLP layer (wave-per-neuron GEMV): out[b][n] = act(bias[n] + W[n]·in[b]).
// grid (N/4, B), block 256 = 4 waves = 4 neurons.
// ---------------------------------------------------------------------------
__global__ __launch_bounds__(256) void fm_layer_kernel(
    const float* __restrict__ in, const float* __restrict__ W,
    const float* __restrict__ bias, float* __restrict__ out,
    int K, int N, int act) {
  int b = blockIdx.y;
  int n = blockIdx.x*4 + (threadIdx.x >> 6);
  int lane = threadIdx.x & 63;
  __shared__ float xs[1024];
  for (int i=threadIdx.x; i<K; i+=256) xs[i] = in[(size_t)b*K + i];
  __syncthreads();
  const float* wr = W + (size_t)n*K;
  float acc = 0.f;
  #pragma unroll 4
  for (int k=lane*4; k<K; k+=256){
    float4 u = *(const float4*)(wr + k);
    acc += xs[k]*u.x + xs[k+1]*u.y + xs[k+2]*u.z + xs[k+3]*u.w;
  }
  #pragma unroll
  for (int o=32;o;o>>=1) acc += __shfl_down(acc, o);
  if (lane==0){
    float v = acc + bias[n];
    if (act) v = gelu_exact(v);
    out[(size_t)b*N + n] = v;
  }
}

// ---------------------------------------------------------------------------
extern "C" void kernel_launch(void* const* d_in, const int* in_sizes, int n_in,
                              void* d_out, int out_size, void* d_ws, size_t ws_size,
                              hipStream_t stream) {
  const float* x      = (const float*)d_in[0];
  const float* cls_tk = (const float*)d_in[1];
  const float* ln_g   = (const float*)d_in[2];
  const float* ln_b   = (const float*)d_in[3];
  const float* aw_W0  = (const float*)d_in[4];  const float* aw_b0 = (const float*)d_in[5];
  const float* aw_W1  = (const float*)d_in[6];  const float* aw_b1 = (const float*)d_in[7];
  const float* aw_W2  = (const float*)d_in[8];  const float* aw_b2 = (const float*)d_in[9];
  const float* pr_W0  = (const float*)d_in[10]; const float* pr_b0 = (const float*)d_in[11];
  const float* pr_W1  = (const float*)d_in[12]; const float* pr_b1 = (const float*)d_in[13];
  const float* pr_W2  = (const float*)d_in[14]; const float* pr_b2 = (const float*)d_in[15];
  const float* mWqkv[2] = {(const float*)d_in[16], (const float*)d_in[20]};
  const float* mbqkv[2] = {(const float*)d_in[17], (const float*)d_in[21]};
  const float* mWo[2]   = {(const float*)d_in[18], (const float*)d_in[22]};
  const float* mbo[2]   = {(const float*)d_in[19], (const float*)d_in[23]};

  float* ws = (float*)d_ws;
  size_t off = 0;
  float* weight = ws + off; off += 8192;                      // [B,N]
  int*   idx    = (int*)(ws + off); off += 8448;              // [B,S]
  int*   cnt    = (int*)(ws + off); off += 16;                // [B]
  float* W0T    = ws + off; off += 32768;                     // [512][64]
  const size_t HBUF = (size_t)ROWS*512/2;                     // bf16 array in float units
  unsigned short* Zh = (unsigned short*)(ws + off); off += HBUF;
  unsigned short* Zl = (unsigned short*)(ws + off); off += HBUF;
  float* QKV    = ws + off; off += (size_t)ROWS*1536;
  float* T2     = QKV;                                        // alias: dead QKV space
  float* KV     = QKV;                                        // alias: layer-1 KV (stride 1024)
  unsigned short* Oh = (unsigned short*)(ws + off); off += HBUF;  // also a1 hi
  unsigned short* Ol = (unsigned short*)(ws + off); off += HBUF;  // also a1 lo
  unsigned short* Wq0h = (unsigned short*)(ws + off); off += 393216;
  unsigned short* Wq0l = (unsigned short*)(ws + off); off += 393216;
  unsigned short* Wq1h = (unsigned short*)(ws + off); off += 393216;
  unsigned short* Wq1l = (unsigned short*)(ws + off); off += 393216;
  unsigned short* Wo0h = (unsigned short*)(ws + off); off += 131072;
  unsigned short* Wo0l = (unsigned short*)(ws + off); off += 131072;
  float* attn0  = ws + off; off += 2048;                      // [B,D]
  float* q0buf  = ws + off; off += 2048;                      // [B,D]
  float* clsb   = ws + off; off += 4096;                      // [B,2D]
  float* h1buf  = ws + off; off += 2048;                      // [B,D]
  float* h2buf  = ws + off; off += 2048;                      // [B,D]
  (void)ws_size; (void)in_sizes; (void)n_in; (void)out_size;

  transpose_w0_kernel<<<(32768+255)/256, 256, 0, stream>>>(aw_W0, W0T);
  aw_weight_kernel<<<B_SZ*N_INST, 64, 0, stream>>>(
      x, W0T, aw_b0, aw_W1, aw_b1, aw_W2, aw_b2, weight);

  split_kernel<<<(786432+255)/256, 256, 0, stream>>>(mWqkv[0], Wq0h, Wq0l, 786432);
  split_kernel<<<(786432+255)/256, 256, 0, stream>>>(mWqkv[1], Wq1h, Wq1l, 786432);
  split_kernel<<<(262144+255)/256, 256, 0, stream>>>(mWo[0],  Wo0h, Wo0l, 262144);

  for (int br=0; br<2; br++){
    compact_kernel<<<B_SZ, 256, 0, stream>>>(weight, br, idx, cnt);
    build_z_kernel<<<ROWS, 256, 0, stream>>>(x, weight, cls_tk, ln_g, ln_b, br, idx, cnt, Zh, Zl);
    // layer 0
    mfma_gemm_kernel<<<dim3(1536/64, (ROWS+63)/64), 256, 0, stream>>>(
        Zh, Zl, Wq0h, Wq0l, mbqkv[0], QKV, ROWS, 1536, cnt);
    flash_attn_kernel<<<dim3((S_TOT+63)/64, NH, B_SZ), 256, 0, stream>>>(QKV, cnt, Oh, Ol);
    mfma_gemm_kernel<<<dim3(512/64, (ROWS+63)/64), 256, 0, stream>>>(
        Oh, Ol, Wo0h, Wo0l, mbo[0], T2, ROWS, 512, cnt);
    add_ln_kernel<<<ROWS, 256, 0, stream>>>(Zh, Zl, T2, ln_g, ln_b, cnt, Oh, Ol); // a1 -> Oh/Ol
    // layer 1: only row0's Q is consumed — compute KV for all rows (N=1024)
    // plus a tiny fp32 GEMV for q0.
    row0_q_kernel<<<dim3(128, B_SZ), 256, 0, stream>>>(Oh, Ol, mWqkv[1], mbqkv[1], q0buf);
    mfma_gemm_kernel<<<dim3(1024/64, (ROWS+63)/64), 256, 0, stream>>>(
        Oh, Ol, Wq1h + (size_t)512*512, Wq1l + (size_t)512*512,
        mbqkv[1] + 512, KV, ROWS, 1024, cnt);
    attn_row0_kernel<<<dim3(NH, B_SZ), 256, 0, stream>>>(KV, q0buf, cnt, attn0);
    row0_proj_ln_kernel<<<B_SZ, 256, 0, stream>>>(
        attn0, mWo[1], mbo[1], Zh, Zl, ln_g, ln_b, clsb, br);
  }
  // final MLP: 3 wave-per-neuron GEMV layers (512 blocks each)
  fm_layer_kernel<<<dim3(128, B_SZ), 256, 0, stream>>>(clsb,  pr_W0, pr_b0, h1buf, 1024, 512, 1);
  fm_layer_kernel<<<dim3(128, B_SZ), 256, 0, stream>>>(h1buf, pr_W1, pr_b1, h2buf,  512, 512, 1);
  fm_layer_kernel<<<dim3(128, B_SZ), 256, 0, stream>>>(h2buf, pr_W2, pr_b2, (float*)d_out, 512, 512, 0);
}

// Round 9
// 698.731 us; speedup vs baseline: 5.6841x; 1.0697x over previous
//
#include <hip/hip_runtime.h>
#include <hip/hip_bf16.h>

#define B_SZ 4
#define N_INST 2048
#define D_MODEL 512
#define S_TOT 2049          // N+1 (cls prepended)
#define NH 8
#define HD 64
#define ROWS (B_SZ*S_TOT)   // 8196

typedef __attribute__((ext_vector_type(4))) float f32x4;
typedef __attribute__((ext_vector_type(8))) short bf16x8;

__device__ __forceinline__ float gelu_exact(float x){ return 0.5f*x*(1.f+erff(x*0.70710678118654752f)); }
__device__ __forceinline__ unsigned short f2bf(float x){
  unsigned int u = __float_as_uint(x);
  u += 0x7fffu + ((u>>16)&1u);
  return (unsigned short)(u>>16);
}
__device__ __forceinline__ float bfval(unsigned short u){ return __uint_as_float(((unsigned int)u)<<16); }
__device__ __forceinline__ unsigned int pk2(unsigned short lo, unsigned short hi){
  return (unsigned int)lo | ((unsigned int)hi << 16);
}
__device__ __forceinline__ unsigned short ext16(unsigned int u, int hi){
  return (unsigned short)(hi ? (u>>16) : (u & 0xffffu));
}

#define GLOAD16(gp, lp) __builtin_amdgcn_global_load_lds( \
    (const __attribute__((address_space(1))) void*)(gp), \
    (__attribute__((address_space(3))) void*)(lp), 16, 0, 0)

// ---------------------------------------------------------------------------
// One-time transpose: W0T[k][h] = W0[h][k]   (64x512 -> 512x64, fp32)
// ---------------------------------------------------------------------------
__global__ __launch_bounds__(256) void transpose_w0_kernel(
    const float* __restrict__ W0, float* __restrict__ W0T) {
  int i = blockIdx.x*256 + threadIdx.x;
  if (i < 64*512){
    int h = i >> 9, k = i & 511;
    W0T[k*64 + h] = W0[i];
  }
}

// ---------------------------------------------------------------------------
// Gating MLP: weight[b,n] = sigmoid(MLP(x[b,n,:])). fp32 throughout — the
// w<0.5 mask is a threshold; bf16 logits risk borderline branch flips.
// ---------------------------------------------------------------------------
__global__ __launch_bounds__(64) void aw_weight_kernel(
    const float* __restrict__ x,
    const float* __restrict__ W0T, const float* __restrict__ b0,
    const float* __restrict__ W1, const float* __restrict__ b1,
    const float* __restrict__ W2, const float* __restrict__ b2,
    float* __restrict__ weight) {
  int inst = blockIdx.x;
  int h = threadIdx.x;
  __shared__ float xs[512];
  __shared__ float hs[64];
  const float* xp = x + (size_t)inst*D_MODEL;
  for (int i=h;i<512;i+=64) xs[i] = xp[i];
  __syncthreads();
  float acc = b0[h];
  const float* w0c = W0T + h;
  #pragma unroll 16
  for (int k=0;k<512;k++)
    acc = fmaf(xs[k], w0c[k*64], acc);
  hs[h] = gelu_exact(acc);
  __syncthreads();
  const float4* w1 = (const float4*)(W1 + (size_t)h*64);
  float acc2 = b1[h];
  #pragma unroll
  for (int k4=0;k4<16;k4++){
    float4 u = w1[k4]; int k = k4*4;
    acc2 += hs[k+0]*u.x + hs[k+1]*u.y + hs[k+2]*u.z + hs[k+3]*u.w;
  }
  float h2 = gelu_exact(acc2);
  float p = h2 * W2[h];
  #pragma unroll
  for (int o=32;o;o>>=1) p += __shfl_down(p, o);
  if (h==0){
    float s = p + b2[0];
    weight[inst] = 1.f/(1.f+expf(-s));
  }
}

// ---------------------------------------------------------------------------
// Split fp32 -> (hi, lo) bf16 pair.
// ---------------------------------------------------------------------------
__global__ __launch_bounds__(256) void split_kernel(
    const float* __restrict__ w, unsigned short* __restrict__ hi,
    unsigned short* __restrict__ lo, int n) {
  int i = blockIdx.x*256 + threadIdx.x;
  if (i < n){
    float v = w[i];
    unsigned short h = f2bf(v);
    hi[i] = h;
    lo[i] = f2bf(v - bfval(h));
  }
}

// ---------------------------------------------------------------------------
// Compaction: per batch, ascending list of valid seq positions (slot0 = cls).
// ---------------------------------------------------------------------------
__global__ __launch_bounds__(256) void compact_kernel(
    const float* __restrict__ weight, int branch,
    int* __restrict__ idx, int* __restrict__ cnt) {
  int b = blockIdx.x;
  int t = threadIdx.x;
  int lane = t & 63, wv = t >> 6;
  __shared__ int wsum[4];
  __shared__ int base_s;
  if (t==0){ idx[b*S_TOT] = 0; base_s = 1; }
  __syncthreads();
  for (int c0=0; c0<N_INST; c0+=256){
    int n = c0 + t;
    float w = weight[b*N_INST + n];
    bool neg = (w < 0.5f);
    bool val = (branch==0) ? neg : !neg;
    unsigned long long m = __ballot(val);
    int prefix = __popcll(m & ((1ull<<lane)-1ull));
    if (lane==0) wsum[wv] = __popcll(m);
    __syncthreads();
    int wbase = 0;
    #pragma unroll
    for (int i=0;i<4;i++) if (i<wv) wbase += wsum[i];
    int total = wsum[0]+wsum[1]+wsum[2]+wsum[3];
    int mybase = base_s;
    if (val) idx[b*S_TOT + mybase + wbase + prefix] = n + 1;
    __syncthreads();
    if (t==0) base_s += total;
    __syncthreads();
  }
  if (t==0) cnt[b] = base_s;
}

// ---------------------------------------------------------------------------
// Build compacted z = LN(scale*seq[idx]) -> hi/lo bf16 pair.
// ---------------------------------------------------------------------------
__global__ __launch_bounds__(256) void build_z_kernel(
    const float* __restrict__ x, const float* __restrict__ weight,
    const float* __restrict__ cls, const float* __restrict__ g, const float* __restrict__ be,
    int branch, const int* __restrict__ idx, const int* __restrict__ cnt,
    unsigned short* __restrict__ Zh, unsigned short* __restrict__ Zl) {
  int row = blockIdx.x;
  int b = row / S_TOT, slot = row % S_TOT;
  if (slot >= cnt[b]) return;
  int t = threadIdx.x;
  __shared__ float v[512];
  __shared__ float red[16];
  int pos = idx[b*S_TOT + slot];
  float scale = 1.f;
  const float* src = cls;
  if (pos != 0){
    float w = weight[b*N_INST + (pos-1)];
    scale = (branch==0) ? powf(w, 1.5f) : powf(w, 2.0f/3.0f);
    src = x + ((size_t)b*N_INST + (pos-1))*D_MODEL;
  }
  float s1=0.f, s2=0.f;
  for (int i=t;i<512;i+=256){
    float val = src[i];
    if (pos != 0) val *= scale;
    v[i]=val; s1+=val; s2+=val*val;
  }
  __syncthreads();
  #pragma unroll
  for (int o=32;o;o>>=1){ s1+=__shfl_down(s1,o); s2+=__shfl_down(s2,o); }
  if ((t&63)==0){ red[t>>6]=s1; red[8+(t>>6)]=s2; }
  __syncthreads();
  s1 = red[0]+red[1]+red[2]+red[3];
  s2 = red[8]+red[9]+red[10]+red[11];
  float mean = s1 * (1.f/512.f);
  float var  = s2 * (1.f/512.f) - mean*mean;
  float rn = rsqrtf(var + 1e-5f);
  size_t ro = (size_t)row*512;
  for (int i=t;i<512;i+=256){
    float o = (v[i]-mean)*rn*g[i] + be[i];
    unsigned short hbits = f2bf(o);
    Zh[ro+i] = hbits;
    Zl[ro+i] = f2bf(o - bfval(hbits));
  }
}

// out = LN((Zh+Zl) + T2) rowwise -> hi/lo bf16 pair (the a1 operand)
__global__ __launch_bounds__(256) void add_ln_kernel(
    const unsigned short* __restrict__ Zh, const unsigned short* __restrict__ Zl,
    const float* __restrict__ T2,
    const float* __restrict__ g, const float* __restrict__ be,
    const int* __restrict__ cnt,
    unsigned short* __restrict__ Ah, unsigned short* __restrict__ Al) {
  int row = blockIdx.x;
  if ((row % S_TOT) >= cnt[row / S_TOT]) return;
  int t = threadIdx.x;
  __shared__ float v[512];
  __shared__ float red[16];
  size_t ro = (size_t)row*512;
  float s1=0.f, s2=0.f;
  for (int i=t;i<512;i+=256){
    float val = bfval(Zh[ro+i]) + bfval(Zl[ro+i]) + T2[ro+i];
    v[i]=val; s1+=val; s2+=val*val;
  }
  __syncthreads();
  #pragma unroll
  for (int o=32;o;o>>=1){ s1+=__shfl_down(s1,o); s2+=__shfl_down(s2,o); }
  if ((t&63)==0){ red[t>>6]=s1; red[8+(t>>6)]=s2; }
  __syncthreads();
  s1 = red[0]+red[1]+red[2]+red[3];
  s2 = red[8]+red[9]+red[10]+red[11];
  float mean = s1 * (1.f/512.f);
  float var  = s2 * (1.f/512.f) - mean*mean;
  float rn = rsqrtf(var + 1e-5f);
  for (int i=t;i<512;i+=256){
    float o = (v[i]-mean)*rn*g[i] + be[i];
    unsigned short hbits = f2bf(o);
    Ah[ro+i] = hbits;
    Al[ro+i] = f2bf(o - bfval(hbits));
  }
}

// ---------------------------------------------------------------------------
// MFMA GEMM (bf16 hi/lo 3-pass): C[M,N] = (Ah+Al)[M,512] @ (Wh+Wl)[N,512]^T + bias.
// obf16=1 -> write bf16 (ushort, stride N); else fp32.
// ---------------------------------------------------------------------------
__global__ __launch_bounds__(256) void mfma_gemm_kernel(
    const unsigned short* __restrict__ Ahg, const unsigned short* __restrict__ Alg,
    const unsigned short* __restrict__ Whg, const unsigned short* __restrict__ Wlg,
    const float* __restrict__ bias, void* __restrict__ Cout,
    int M, int N, const int* __restrict__ cnt, int obf16) {
  int t = threadIdx.x;
  int bm = blockIdx.y*64, bn = blockIdx.x*64;
  {
    int r = bm + (t>>2);
    bool ok = (r < M) && ((r % S_TOT) < cnt[r / S_TOT]);
    if (__syncthreads_or(ok ? 1 : 0) == 0) return;
  }
  __shared__ unsigned short Ahs[64*64], Als[64*64], Whs[64*64], Wls[64*64];
  int lane = t & 63, w = t >> 6;
  int l15 = lane & 15, l4 = lane >> 4;

  const unsigned short* src;
  unsigned short* dst;
  if      (w == 0){ src = Ahg; dst = Ahs; }
  else if (w == 1){ src = Alg; dst = Als; }
  else if (w == 2){ src = Whg; dst = Whs; }
  else            { src = Wlg; dst = Wls; }
  int tb  = (w < 2) ? bm : bn;
  int lim = (w < 2) ? M  : N;
  int lrow = lane >> 3;
  int lg   = lane & 7;
  const unsigned short* gp[8];
  #pragma unroll
  for (int i=0;i<8;i++){
    int row_l = i*8 + lrow;
    int rg = tb + row_l; if (rg >= lim) rg = lim-1;
    gp[i] = src + (size_t)rg*512 + (size_t)((lg ^ (row_l&7))*8);
  }

  f32x4 acc[4];
  #pragma unroll
  for (int mt=0;mt<4;mt++) acc[mt] = (f32x4){0.f,0.f,0.f,0.f};

  for (int ch=0; ch<8; ch++){
    __syncthreads();
    #pragma unroll
    for (int i=0;i<8;i++)
      GLOAD16(gp[i] + ch*64, dst + i*512);
    __syncthreads();
    #pragma unroll
    for (int ks=0; ks<2; ks++){
      int wrow = w*16 + l15;
      int wgs = (ks*4 + l4) ^ (wrow & 7);
      bf16x8 wh = *(const bf16x8*)&Whs[wrow*64 + wgs*8];
      bf16x8 wl = *(const bf16x8*)&Wls[wrow*64 + wgs*8];
      #pragma unroll
      for (int mt=0;mt<4;mt++){
        int arow = mt*16 + l15;
        int ags = (ks*4 + l4) ^ (arow & 7);
        bf16x8 ah = *(const bf16x8*)&Ahs[arow*64 + ags*8];
        bf16x8 al = *(const bf16x8*)&Als[arow*64 + ags*8];
        acc[mt] = __builtin_amdgcn_mfma_f32_16x16x32_bf16(ah, wh, acc[mt], 0,0,0);
        acc[mt] = __builtin_amdgcn_mfma_f32_16x16x32_bf16(ah, wl, acc[mt], 0,0,0);
        acc[mt] = __builtin_amdgcn_mfma_f32_16x16x32_bf16(al, wh, acc[mt], 0,0,0);
      }
    }
  }
  int ncol = bn + w*16 + l15;
  float bv = bias[ncol];
  #pragma unroll
  for (int mt=0;mt<4;mt++){
    #pragma unroll
    for (int r=0;r<4;r++){
      int mrow = bm + mt*16 + l4*4 + r;
      bool ok = (mrow < M) && ((mrow % S_TOT) < cnt[mrow / S_TOT]);
      if (ok){
        float v = acc[mt][r] + bv;
        if (obf16) ((unsigned short*)Cout)[(size_t)mrow*N + ncol] = f2bf(v);
        else       ((float*)Cout)[(size_t)mrow*N + ncol] = v;
      }
    }
  }
}

// ---------------------------------------------------------------------------
// MFMA flash attention (layer 0), bf16 QKV input (stride 1536), compacted keys.
// Scale 1/8 applied to scores post-MFMA (exact pow2). Epilogue emits hi/lo bf16.
// ---------------------------------------------------------------------------
__global__ __launch_bounds__(256) void flash_attn_kernel(
    const unsigned short* __restrict__ qkv, const int* __restrict__ cnt,
    unsigned short* __restrict__ Oh, unsigned short* __restrict__ Ol) {
  int b = blockIdx.z, h = blockIdx.y;
  int cb = cnt[b];
  int S0 = blockIdx.x * 64;
  if (S0 >= cb) return;
  int t = threadIdx.x;
  int lane = t & 63, w = t >> 6;
  int l15 = lane & 15, l4 = lane >> 4;

  __shared__ unsigned short Kbf[64*64];
  __shared__ unsigned short Vt[64*64];
  __shared__ unsigned short Pbuf[4][16*64];

  const unsigned short* basep = qkv + (size_t)(b*S_TOT)*1536;

  int qg = S0 + w*16 + l15;
  int qr = (qg < cb) ? qg : 0;
  const unsigned short* qp = basep + (size_t)qr*1536 + h*64;
  bf16x8 Qf[2];
  Qf[0] = *(const bf16x8*)(qp + l4*8);
  Qf[1] = *(const bf16x8*)(qp + 32 + l4*8);

  float m_run = -1e30f, l_run = 0.f;
  f32x4 accO[4];
  #pragma unroll
  for (int mt=0;mt<4;mt++) accO[mt] = (f32x4){0.f,0.f,0.f,0.f};

  unsigned int* Ku = (unsigned int*)Kbf;
  unsigned int* Vu = (unsigned int*)Vt;
  const int nt = (cb + 63)/64;
  for (int kt=0; kt<nt; kt++){
    int K0 = kt*64;
    __syncthreads();
    {   // stage K rows -> Kbf[key][d] (thread: key=t>>2, 16 dims at (t&3)*16)
      int key = t>>2;
      int keyr = (K0+key < cb) ? (K0+key) : 0;
      const unsigned short* kp = basep + (size_t)keyr*1536 + 512 + h*64 + (t&3)*16;
      uint4 a  = *(const uint4*)(kp);
      uint4 b2 = *(const uint4*)(kp+8);
      int g0 = (t&3)*2;
      int gs0 = g0 ^ (key&7), gs1 = (g0+1) ^ (key&7);
      *(uint4*)(Ku + key*32 + gs0*4) = a;
      *(uint4*)(Ku + key*32 + gs1*4) = b2;
    }
    {   // stage V transposed -> Vt[d][key] (thread: keys 2kp2,2kp2+1; dims d8*8..+7)
      int kp2 = t & 31;
      int d8 = t >> 5;
      int k0g = K0 + 2*kp2;
      int kr0 = (k0g   < cb) ? k0g   : 0;
      int kr1 = (k0g+1 < cb) ? k0g+1 : 0;
      const unsigned short* vp0 = basep + (size_t)kr0*1536 + 1024 + h*64 + d8*8;
      const unsigned short* vp1 = basep + (size_t)kr1*1536 + 1024 + h*64 + d8*8;
      uint4 a = *(const uint4*)(vp0);
      uint4 c = *(const uint4*)(vp1);
      unsigned int au[4] = {a.x,a.y,a.z,a.w};
      unsigned int cu[4] = {c.x,c.y,c.z,c.w};
      int k8 = kp2 >> 2;
      #pragma unroll
      for (int dd=0; dd<8; dd++){
        int d = d8*8 + dd;
        Vu[d*32 + (k8 ^ (d&7))*4 + (kp2&3)] =
            pk2(ext16(au[dd>>1], dd&1), ext16(cu[dd>>1], dd&1));
      }
    }
    __syncthreads();

    f32x4 acc[4];
    #pragma unroll
    for (int mt=0;mt<4;mt++) acc[mt] = (f32x4){0.f,0.f,0.f,0.f};
    #pragma unroll
    for (int mt=0;mt<4;mt++){
      int row = mt*16 + l15;
      #pragma unroll
      for (int c=0;c<2;c++){
        int gs = (c*4 + l4) ^ (row & 7);
        bf16x8 kf = *(const bf16x8*)&Kbf[row*64 + gs*8];
        acc[mt] = __builtin_amdgcn_mfma_f32_16x16x32_bf16(kf, Qf[c], acc[mt], 0,0,0);
      }
    }
    float p[4][4];
    float tmax = -1e30f;
    #pragma unroll
    for (int mt=0;mt<4;mt++)
      #pragma unroll
      for (int r=0;r<4;r++){
        int key = K0 + mt*16 + l4*4 + r;
        float s = (key < cb) ? acc[mt][r]*0.125f : -1e30f;
        p[mt][r] = s;
        tmax = fmaxf(tmax, s);
      }
    tmax = fmaxf(tmax, __shfl_xor(tmax, 16));
    tmax = fmaxf(tmax, __shfl_xor(tmax, 32));
    float m_new = fmaxf(m_run, tmax);
    float alpha = __expf(m_run - m_new);
    float psum = 0.f;
    #pragma unroll
    for (int mt=0;mt<4;mt++)
      #pragma unroll
      for (int r=0;r<4;r++){
        float pv = __expf(p[mt][r] - m_new);
        p[mt][r] = pv; psum += pv;
      }
    psum += __shfl_xor(psum, 16);
    psum += __shfl_xor(psum, 32);
    l_run = l_run*alpha + psum;
    m_run = m_new;

    #pragma unroll
    for (int mt=0;mt<4;mt++){
      int keyl = mt*16 + l4*4;
      int gs = (keyl >> 3) ^ (l15 & 7);
      uint2 w2;
      w2.x = pk2(f2bf(p[mt][0]), f2bf(p[mt][1]));
      w2.y = pk2(f2bf(p[mt][2]), f2bf(p[mt][3]));
      *(uint2*)&Pbuf[w][ l15*64 + gs*8 + (keyl & 7) ] = w2;
    }
    #pragma unroll
    for (int mt=0;mt<4;mt++){
      accO[mt][0]*=alpha; accO[mt][1]*=alpha; accO[mt][2]*=alpha; accO[mt][3]*=alpha;
    }
    #pragma unroll
    for (int c2=0;c2<2;c2++){
      int gpv = (c2*4 + l4) ^ (l15 & 7);
      bf16x8 pf = *(const bf16x8*)&Pbuf[w][ l15*64 + gpv*8 ];
      #pragma unroll
      for (int mt=0;mt<4;mt++){
        int d = mt*16 + l15;
        int gv = (c2*4 + l4) ^ (d & 7);
        bf16x8 vf = *(const bf16x8*)&Vt[ d*64 + gv*8 ];
        accO[mt] = __builtin_amdgcn_mfma_f32_16x16x32_bf16(vf, pf, accO[mt], 0,0,0);
      }
    }
  }
  if (qg < cb){
    float inv = 1.f/l_run;
    size_t ro = ((size_t)(b*S_TOT) + qg)*512 + h*64;
    #pragma unroll
    for (int mt=0;mt<4;mt++){
      float v0 = accO[mt][0]*inv, v1 = accO[mt][1]*inv;
      float v2 = accO[mt][2]*inv, v3 = accO[mt][3]*inv;
      unsigned short h0=f2bf(v0), h1=f2bf(v1), h2=f2bf(v2), h3=f2bf(v3);
      uint2 hw; hw.x = pk2(h0,h1); hw.y = pk2(h2,h3);
      uint2 lw;
      lw.x = pk2(f2bf(v0-bfval(h0)), f2bf(v1-bfval(h1)));
      lw.y = pk2(f2bf(v2-bfval(h2)), f2bf(v3-bfval(h3)));
      *(uint2*)&Oh[ro + mt*16 + l4*4] = hw;
      *(uint2*)&Ol[ro + mt*16 + l4*4] = lw;
    }
  }
}

// ---------------------------------------------------------------------------
// q0[b][n] = bq[n] + dot(Wq_row_n, a1[b,row0]); wave-per-neuron, fp32 exact.
// ---------------------------------------------------------------------------
__global__ __launch_bounds__(256) void row0_q_kernel(
    const unsigned short* __restrict__ Ah, const unsigned short* __restrict__ Al,
    const float* __restrict__ Wq, const float* __restrict__ bq,
    float* __restrict__ q0) {
  int b = blockIdx.y;
  int n = blockIdx.x*4 + (threadIdx.x >> 6);
  int lane = threadIdx.x & 63;
  __shared__ float xs[512];
  size_t ro = (size_t)(b*S_TOT)*512;
  for (int i=threadIdx.x; i<512; i+=256)
    xs[i] = bfval(Ah[ro+i]) + bfval(Al[ro+i]);
  __syncthreads();
  const float* wr = Wq + (size_t)n*512;
  float acc = 0.f;
  #pragma unroll
  for (int k=lane*4; k<512; k+=256){
    float4 u = *(const float4*)(wr + k);
    acc += xs[k]*u.x + xs[k+1]*u.y + xs[k+2]*u.z + xs[k+3]*u.w;
  }
  #pragma unroll
  for (int o=32;o;o>>=1) acc += __shfl_down(acc, o);
  if (lane==0) q0[b*512 + n] = acc + bq[n];
}

// ---------------------------------------------------------------------------
// Layer-1 attention, query 0 only, bf16 KV (row stride 1024: K [0,512),
// V [512,1024)). 2-way ILP on key loops.
// ---------------------------------------------------------------------------
__global__ __launch_bounds__(256) void attn_row0_kernel(
    const unsigned short* __restrict__ kv, const float* __restrict__ q0,
    const int* __restrict__ cnt, float* __restrict__ out0) {
  int h = blockIdx.x, b = blockIdx.y;
  int cb = cnt[b];
  int t = threadIdx.x;
  __shared__ float qs[64];
  __shared__ float sc[S_TOT];
  __shared__ float red[8];
  __shared__ float redO[4][64];
  const unsigned short* base = kv + (size_t)b*S_TOT*1024;
  if (t < 64) qs[t] = q0[b*512 + h*64 + t]*0.125f;
  __syncthreads();
  float lmax = -1e30f;
  for (int j=t; j<cb; j+=512){
    int j2 = j + 256;
    bool v2 = j2 < cb;
    const unsigned short* kp0 = base + (size_t)j*1024 + h*64;
    const unsigned short* kp1 = base + (size_t)(v2 ? j2 : j)*1024 + h*64;
    float s0 = 0.f, s1 = 0.f;
    #pragma unroll
    for (int d8=0; d8<8; d8++){
      uint4 a = *(const uint4*)(kp0 + d8*8);
      uint4 c = *(const uint4*)(kp1 + d8*8);
      unsigned int au[4] = {a.x,a.y,a.z,a.w};
      unsigned int cu[4] = {c.x,c.y,c.z,c.w};
      #pragma unroll
      for (int q2=0; q2<4; q2++){
        float qa = qs[d8*8 + q2*2], qb = qs[d8*8 + q2*2 + 1];
        s0 += qa*bfval(ext16(au[q2],0)) + qb*bfval(ext16(au[q2],1));
        s1 += qa*bfval(ext16(cu[q2],0)) + qb*bfval(ext16(cu[q2],1));
      }
    }
    sc[j] = s0; lmax = fmaxf(lmax, s0);
    if (v2){ sc[j2] = s1; lmax = fmaxf(lmax, s1); }
  }
  #pragma unroll
  for (int o=32;o;o>>=1) lmax = fmaxf(lmax, __shfl_down(lmax, o));
  if ((t&63)==0) red[t>>6]=lmax;
  __syncthreads();
  float m = fmaxf(fmaxf(red[0],red[1]),fmaxf(red[2],red[3]));
  float lsum = 0.f;
  for (int j=t;j<cb;j+=256){
    float p = expf(sc[j]-m);
    sc[j]=p; lsum+=p;
  }
  #pragma unroll
  for (int o=32;o;o>>=1) lsum += __shfl_down(lsum,o);
  __syncthreads();
  if ((t&63)==0) red[t>>6]=lsum;
  __syncthreads();
  float l = red[0]+red[1]+red[2]+red[3];
  int d = t & 63, rr = t >> 6;
  float acc = 0.f;
  for (int j=rr; j<cb; j+=8){
    int j2 = j + 4;
    bool v2 = j2 < cb;
    float p0 = sc[j];
    float p1 = v2 ? sc[j2] : 0.f;
    float va = bfval(base[(size_t)j*1024 + 512 + h*64 + d]);
    float vb = bfval(base[(size_t)(v2 ? j2 : j)*1024 + 512 + h*64 + d]);
    acc += p0*va + p1*vb;
  }
  redO[rr][d]=acc;
  __syncthreads();
  if (t < 64){
    float o = (redO[0][t]+redO[1][t]+redO[2][t]+redO[3][t])/l;
    out0[b*512 + h*64 + t] = o;
  }
}

// layer-1 out-proj for row 0 + residual(z row0) + LN -> cls embedding slot
__global__ __launch_bounds__(256) void row0_proj_ln_kernel(
    const float* __restrict__ attn0, const float* __restrict__ Wo, const float* __restrict__ bo,
    const unsigned short* __restrict__ Zh, const unsigned short* __restrict__ Zl,
    const float* __restrict__ g, const float* __restrict__ be,
    float* __restrict__ clsbuf, int branch) {
  int b = blockIdx.x, t = threadIdx.x;
  __shared__ float xin[512];
  __shared__ float y[512];
  __shared__ float red[16];
  for (int i=t;i<512;i+=256) xin[i] = attn0[b*512+i];
  __syncthreads();
  size_t z0 = (size_t)b*S_TOT*512;
  for (int n=t;n<512;n+=256){
    const float4* wr = (const float4*)(Wo + (size_t)n*512);
    float acc = bo[n];
    for (int k4=0;k4<128;k4++){
      float4 u = wr[k4]; int k=k4*4;
      acc += xin[k+0]*u.x + xin[k+1]*u.y + xin[k+2]*u.z + xin[k+3]*u.w;
    }
    y[n] = acc + bfval(Zh[z0+n]) + bfval(Zl[z0+n]);
  }
  __syncthreads();
  float s1=0.f, s2=0.f;
  for (int i=t;i<512;i+=256){ float a=y[i]; s1+=a; s2+=a*a; }
  #pragma unroll
  for (int o=32;o;o>>=1){ s1+=__shfl_down(s1,o); s2+=__shfl_down(s2,o); }
  if ((t&63)==0){ red[t>>6]=s1; red[8+(t>>6)]=s2; }
  __syncthreads();
  s1 = red[0]+red[1]+red[2]+red[3];
  s2 = red[8]+red[9]+red[10]+red[11];
  float mean = s1*(1.f/512.f);
  float var  = s2*(1.f/512.f) - mean*mean;
  float rn = rsqrtf(var + 1e-5f);
  for (int i=t;i<512;i+=256)
    clsbuf[b*1024 + branch*512 + i] = (y[i]-mean)*rn*g[i] + be[i];
}

// ---------------------------------------------------------------------------
// Final MLP layer (wave-per-neuron GEMV).
// ---------------------------------------------------------------------------
__global__ __launch_bounds__(256) void fm_layer_kernel(
    const float* __restrict__ in, const float* __restrict__ W,
    const float* __restrict__ bias, float* __restrict__ out,
    int K, int N, int act) {
  int b = blockIdx.y;
  int n = blockIdx.x*4 + (threadIdx.x >> 6);
  int lane = threadIdx.x & 63;
  __shared__ float xs[1024];
  for (int i=threadIdx.x; i<K; i+=256) xs[i] = in[(size_t)b*K + i];
  __syncthreads();
  const float* wr = W + (size_t)n*K;
  float acc = 0.f;
  #pragma unroll 4
  for (int k=lane*4; k<K; k+=256){
    float4 u = *(const float4*)(wr + k);
    acc += xs[k]*u.x + xs[k+1]*u.y + xs[k+2]*u.z + xs[k+3]*u.w;
  }
  #pragma unroll
  for (int o=32;o;o>>=1) acc += __shfl_down(acc, o);
  if (lane==0){
    float v = acc + bias[n];
    if (act) v = gelu_exact(v);
    out[(size_t)b*N + n] = v;
  }
}

// ---------------------------------------------------------------------------
extern "C" void kernel_launch(void* const* d_in, const int* in_sizes, int n_in,
                              void* d_out, int out_size, void* d_ws, size_t ws_size,
                              hipStream_t stream) {
  const float* x      = (const float*)d_in[0];
  const float* cls_tk = (const float*)d_in[1];
  const float* ln_g   = (const float*)d_in[2];
  const float* ln_b   = (const float*)d_in[3];
  const float* aw_W0  = (const float*)d_in[4];  const float* aw_b0 = (const float*)d_in[5];
  const float* aw_W1  = (const float*)d_in[6];  const float* aw_b1 = (const float*)d_in[7];
  const float* aw_W2  = (const float*)d_in[8];  const float* aw_b2 = (const float*)d_in[9];
  const float* pr_W0  = (const float*)d_in[10]; const float* pr_b0 = (const float*)d_in[11];
  const float* pr_W1  = (const float*)d_in[12]; const float* pr_b1 = (const float*)d_in[13];
  const float* pr_W2  = (const float*)d_in[14]; const float* pr_b2 = (const float*)d_in[15];
  const float* mWqkv[2] = {(const float*)d_in[16], (const float*)d_in[20]};
  const float* mbqkv[2] = {(const float*)d_in[17], (const float*)d_in[21]};
  const float* mWo[2]   = {(const float*)d_in[18], (const float*)d_in[22]};
  const float* mbo[2]   = {(const float*)d_in[19], (const float*)d_in[23]};

  float* ws = (float*)d_ws;
  size_t off = 0;
  float* weight = ws + off; off += 8192;                      // [B,N]
  int*   idx    = (int*)(ws + off); off += 8448;              // [B,S]
  int*   cnt    = (int*)(ws + off); off += 16;                // [B]
  float* W0T    = ws + off; off += 32768;                     // [512][64]
  const size_t HBUF = (size_t)ROWS*512/2;                     // bf16 array in float units
  unsigned short* Zh = (unsigned short*)(ws + off); off += HBUF;
  unsigned short* Zl = (unsigned short*)(ws + off); off += HBUF;
  float* QKVr   = ws + off; off += (size_t)ROWS*1536;         // shared region:
  unsigned short* QKVb = (unsigned short*)QKVr;               //  layer-0 QKV bf16 (stride 1536)
  float* T2     = QKVr;                                       //  out-proj result fp32 (stride 512)
  unsigned short* KVb  = (unsigned short*)QKVr;               //  layer-1 KV bf16 (stride 1024)
  unsigned short* Oh = (unsigned short*)(ws + off); off += HBUF;  // also a1 hi
  unsigned short* Ol = (unsigned short*)(ws + off); off += HBUF;  // also a1 lo
  unsigned short* Wq0h = (unsigned short*)(ws + off); off += 393216;
  unsigned short* Wq0l = (unsigned short*)(ws + off); off += 393216;
  unsigned short* Wq1h = (unsigned short*)(ws + off); off += 393216;
  unsigned short* Wq1l = (unsigned short*)(ws + off); off += 393216;
  unsigned short* Wo0h = (unsigned short*)(ws + off); off += 131072;
  unsigned short* Wo0l = (unsigned short*)(ws + off); off += 131072;
  float* attn0  = ws + off; off += 2048;                      // [B,D]
  float* q0buf  = ws + off; off += 2048;                      // [B,D]
  float* clsb   = ws + off; off += 4096;                      // [B,2D]
  float* h1buf  = ws + off; off += 2048;                      // [B,D]
  float* h2buf  = ws + off; off += 2048;                      // [B,D]
  (void)ws_size; (void)in_sizes; (void)n_in; (void)out_size;

  transpose_w0_kernel<<<(32768+255)/256, 256, 0, stream>>>(aw_W0, W0T);
  aw_weight_kernel<<<B_SZ*N_INST, 64, 0, stream>>>(
      x, W0T, aw_b0, aw_W1, aw_b1, aw_W2, aw_b2, weight);

  split_kernel<<<(786432+255)/256, 256, 0, stream>>>(mWqkv[0], Wq0h, Wq0l, 786432);
  split_kernel<<<(786432+255)/256, 256, 0, stream>>>(mWqkv[1], Wq1h, Wq1l, 786432);
  split_kernel<<<(262144+255)/256, 256, 0, stream>>>(mWo[0],  Wo0h, Wo0l, 262144);

  for (int br=0; br<2; br++){
    compact_kernel<<<B_SZ, 256, 0, stream>>>(weight, br, idx, cnt);
    build_z_kernel<<<ROWS, 256, 0, stream>>>(x, weight, cls_tk, ln_g, ln_b, br, idx, cnt, Zh, Zl);
    // layer 0 (QKV written bf16 — exactly the values flash would convert anyway)
    mfma_gemm_kernel<<<dim3(1536/64, (ROWS+63)/64), 256, 0, stream>>>(
        Zh, Zl, Wq0h, Wq0l, mbqkv[0], QKVb, ROWS, 1536, cnt, 1);
    flash_attn_kernel<<<dim3((S_TOT+63)/64, NH, B_SZ), 256, 0, stream>>>(QKVb, cnt, Oh, Ol);
    mfma_gemm_kernel<<<dim3(512/64, (ROWS+63)/64), 256, 0, stream>>>(
        Oh, Ol, Wo0h, Wo0l, mbo[0], T2, ROWS, 512, cnt, 0);
    add_ln_kernel<<<ROWS, 256, 0, stream>>>(Zh, Zl, T2, ln_g, ln_b, cnt, Oh, Ol); // a1 -> Oh/Ol
    // layer 1: row0 Q via fp32 GEMV; KV for all rows, written bf16 (stride 1024)
    row0_q_kernel<<<dim3(128, B_SZ), 256, 0, stream>>>(Oh, Ol, mWqkv[1], mbqkv[1], q0buf);
    mfma_gemm_kernel<<<dim3(1024/64, (ROWS+63)/64), 256, 0, stream>>>(
        Oh, Ol, Wq1h + (size_t)512*512, Wq1l + (size_t)512*512,
        mbqkv[1] + 512, KVb, ROWS, 1024, cnt, 1);
    attn_row0_kernel<<<dim3(NH, B_SZ), 256, 0, stream>>>(KVb, q0buf, cnt, attn0);
    row0_proj_ln_kernel<<<B_SZ, 256, 0, stream>>>(
        attn0, mWo[1], mbo[1], Zh, Zl, ln_g, ln_b, clsb, br);
  }
  // final MLP: 3 wave-per-neuron GEMV layers
  fm_layer_kernel<<<dim3(128, B_SZ), 256, 0, stream>>>(clsb,  pr_W0, pr_b0, h1buf, 1024, 512, 1);
  fm_layer_kernel<<<dim3(128, B_SZ), 256, 0, stream>>>(h1buf, pr_W1, pr_b1, h2buf,  512, 512, 1);
  fm_layer_kernel<<<dim3(128, B_SZ), 256, 0, stream>>>(h2buf, pr_W2, pr_b2, (float*)d_out, 512, 512, 0);
}

// Round 10
// 613.341 us; speedup vs baseline: 6.4755x; 1.1392x over previous
//
#include <hip/hip_runtime.h>
#include <hip/hip_bf16.h>

#define B_SZ 4
#define N_INST 2048
#define D_MODEL 512
#define S_TOT 2049          // N+1 (cls prepended)
#define NH 8
#define HD 64
#define ROWS (B_SZ*S_TOT)   // 8196
#define NCHUNK 16           // split-K chunks for row-0 attention

typedef __attribute__((ext_vector_type(4))) float f32x4;
typedef __attribute__((ext_vector_type(8))) short bf16x8;

__device__ __forceinline__ float gelu_exact(float x){ return 0.5f*x*(1.f+erff(x*0.70710678118654752f)); }
__device__ __forceinline__ unsigned short f2bf(float x){
  unsigned int u = __float_as_uint(x);
  u += 0x7fffu + ((u>>16)&1u);
  return (unsigned short)(u>>16);
}
__device__ __forceinline__ float bfval(unsigned short u){ return __uint_as_float(((unsigned int)u)<<16); }
__device__ __forceinline__ unsigned int pk2(unsigned short lo, unsigned short hi){
  return (unsigned int)lo | ((unsigned int)hi << 16);
}
__device__ __forceinline__ unsigned short ext16(unsigned int u, int hi){
  return (unsigned short)(hi ? (u>>16) : (u & 0xffffu));
}

#define GLOAD16(gp, lp) __builtin_amdgcn_global_load_lds( \
    (const __attribute__((address_space(1))) void*)(gp), \
    (__attribute__((address_space(3))) void*)(lp), 16, 0, 0)

// ---------------------------------------------------------------------------
// One-time transpose: W0T[k][h] = W0[h][k]   (64x512 -> 512x64, fp32)
// ---------------------------------------------------------------------------
__global__ __launch_bounds__(256) void transpose_w0_kernel(
    const float* __restrict__ W0, float* __restrict__ W0T) {
  int i = blockIdx.x*256 + threadIdx.x;
  if (i < 64*512){
    int h = i >> 9, k = i & 511;
    W0T[k*64 + h] = W0[i];
  }
}

// ---------------------------------------------------------------------------
// Gating MLP: weight[b,n] = sigmoid(MLP(x[b,n,:])). fp32 throughout — the
// w<0.5 mask is a threshold; bf16 logits risk borderline branch flips.
// ---------------------------------------------------------------------------
__global__ __launch_bounds__(64) void aw_weight_kernel(
    const float* __restrict__ x,
    const float* __restrict__ W0T, const float* __restrict__ b0,
    const float* __restrict__ W1, const float* __restrict__ b1,
    const float* __restrict__ W2, const float* __restrict__ b2,
    float* __restrict__ weight) {
  int inst = blockIdx.x;
  int h = threadIdx.x;
  __shared__ float xs[512];
  __shared__ float hs[64];
  const float* xp = x + (size_t)inst*D_MODEL;
  for (int i=h;i<512;i+=64) xs[i] = xp[i];
  __syncthreads();
  float acc = b0[h];
  const float* w0c = W0T + h;
  #pragma unroll 16
  for (int k=0;k<512;k++)
    acc = fmaf(xs[k], w0c[k*64], acc);
  hs[h] = gelu_exact(acc);
  __syncthreads();
  const float4* w1 = (const float4*)(W1 + (size_t)h*64);
  float acc2 = b1[h];
  #pragma unroll
  for (int k4=0;k4<16;k4++){
    float4 u = w1[k4]; int k = k4*4;
    acc2 += hs[k+0]*u.x + hs[k+1]*u.y + hs[k+2]*u.z + hs[k+3]*u.w;
  }
  float h2 = gelu_exact(acc2);
  float p = h2 * W2[h];
  #pragma unroll
  for (int o=32;o;o>>=1) p += __shfl_down(p, o);
  if (h==0){
    float s = p + b2[0];
    weight[inst] = 1.f/(1.f+expf(-s));
  }
}

// ---------------------------------------------------------------------------
// Split fp32 -> (hi, lo) bf16 pair.
// ---------------------------------------------------------------------------
__global__ __launch_bounds__(256) void split_kernel(
    const float* __restrict__ w, unsigned short* __restrict__ hi,
    unsigned short* __restrict__ lo, int n) {
  int i = blockIdx.x*256 + threadIdx.x;
  if (i < n){
    float v = w[i];
    unsigned short h = f2bf(v);
    hi[i] = h;
    lo[i] = f2bf(v - bfval(h));
  }
}

// ---------------------------------------------------------------------------
// Compaction: per batch, ascending list of valid seq positions (slot0 = cls).
// ---------------------------------------------------------------------------
__global__ __launch_bounds__(256) void compact_kernel(
    const float* __restrict__ weight, int branch,
    int* __restrict__ idx, int* __restrict__ cnt) {
  int b = blockIdx.x;
  int t = threadIdx.x;
  int lane = t & 63, wv = t >> 6;
  __shared__ int wsum[4];
  __shared__ int base_s;
  if (t==0){ idx[b*S_TOT] = 0; base_s = 1; }
  __syncthreads();
  for (int c0=0; c0<N_INST; c0+=256){
    int n = c0 + t;
    float w = weight[b*N_INST + n];
    bool neg = (w < 0.5f);
    bool val = (branch==0) ? neg : !neg;
    unsigned long long m = __ballot(val);
    int prefix = __popcll(m & ((1ull<<lane)-1ull));
    if (lane==0) wsum[wv] = __popcll(m);
    __syncthreads();
    int wbase = 0;
    #pragma unroll
    for (int i=0;i<4;i++) if (i<wv) wbase += wsum[i];
    int total = wsum[0]+wsum[1]+wsum[2]+wsum[3];
    int mybase = base_s;
    if (val) idx[b*S_TOT + mybase + wbase + prefix] = n + 1;
    __syncthreads();
    if (t==0) base_s += total;
    __syncthreads();
  }
  if (t==0) cnt[b] = base_s;
}

// ---------------------------------------------------------------------------
// Build compacted z = LN(scale*seq[idx]) -> hi/lo bf16 pair.
// ---------------------------------------------------------------------------
__global__ __launch_bounds__(256) void build_z_kernel(
    const float* __restrict__ x, const float* __restrict__ weight,
    const float* __restrict__ cls, const float* __restrict__ g, const float* __restrict__ be,
    int branch, const int* __restrict__ idx, const int* __restrict__ cnt,
    unsigned short* __restrict__ Zh, unsigned short* __restrict__ Zl) {
  int row = blockIdx.x;
  int b = row / S_TOT, slot = row % S_TOT;
  if (slot >= cnt[b]) return;
  int t = threadIdx.x;
  __shared__ float v[512];
  __shared__ float red[16];
  int pos = idx[b*S_TOT + slot];
  float scale = 1.f;
  const float* src = cls;
  if (pos != 0){
    float w = weight[b*N_INST + (pos-1)];
    scale = (branch==0) ? powf(w, 1.5f) : powf(w, 2.0f/3.0f);
    src = x + ((size_t)b*N_INST + (pos-1))*D_MODEL;
  }
  float s1=0.f, s2=0.f;
  for (int i=t;i<512;i+=256){
    float val = src[i];
    if (pos != 0) val *= scale;
    v[i]=val; s1+=val; s2+=val*val;
  }
  __syncthreads();
  #pragma unroll
  for (int o=32;o;o>>=1){ s1+=__shfl_down(s1,o); s2+=__shfl_down(s2,o); }
  if ((t&63)==0){ red[t>>6]=s1; red[8+(t>>6)]=s2; }
  __syncthreads();
  s1 = red[0]+red[1]+red[2]+red[3];
  s2 = red[8]+red[9]+red[10]+red[11];
  float mean = s1 * (1.f/512.f);
  float var  = s2 * (1.f/512.f) - mean*mean;
  float rn = rsqrtf(var + 1e-5f);
  size_t ro = (size_t)row*512;
  for (int i=t;i<512;i+=256){
    float o = (v[i]-mean)*rn*g[i] + be[i];
    unsigned short hbits = f2bf(o);
    Zh[ro+i] = hbits;
    Zl[ro+i] = f2bf(o - bfval(hbits));
  }
}

// out = LN((Zh+Zl) + T2) rowwise -> hi/lo bf16 pair (the a1 operand)
__global__ __launch_bounds__(256) void add_ln_kernel(
    const unsigned short* __restrict__ Zh, const unsigned short* __restrict__ Zl,
    const float* __restrict__ T2,
    const float* __restrict__ g, const float* __restrict__ be,
    const int* __restrict__ cnt,
    unsigned short* __restrict__ Ah, unsigned short* __restrict__ Al) {
  int row = blockIdx.x;
  if ((row % S_TOT) >= cnt[row / S_TOT]) return;
  int t = threadIdx.x;
  __shared__ float v[512];
  __shared__ float red[16];
  size_t ro = (size_t)row*512;
  float s1=0.f, s2=0.f;
  for (int i=t;i<512;i+=256){
    float val = bfval(Zh[ro+i]) + bfval(Zl[ro+i]) + T2[ro+i];
    v[i]=val; s1+=val; s2+=val*val;
  }
  __syncthreads();
  #pragma unroll
  for (int o=32;o;o>>=1){ s1+=__shfl_down(s1,o); s2+=__shfl_down(s2,o); }
  if ((t&63)==0){ red[t>>6]=s1; red[8+(t>>6)]=s2; }
  __syncthreads();
  s1 = red[0]+red[1]+red[2]+red[3];
  s2 = red[8]+red[9]+red[10]+red[11];
  float mean = s1 * (1.f/512.f);
  float var  = s2 * (1.f/512.f) - mean*mean;
  float rn = rsqrtf(var + 1e-5f);
  for (int i=t;i<512;i+=256){
    float o = (v[i]-mean)*rn*g[i] + be[i];
    unsigned short hbits = f2bf(o);
    Ah[ro+i] = hbits;
    Al[ro+i] = f2bf(o - bfval(hbits));
  }
}

// ---------------------------------------------------------------------------
// MFMA GEMM (bf16 hi/lo 3-pass): C[M,N] = (Ah+Al)[M,512] @ (Wh+Wl)[N,512]^T + bias.
// obf16=1 -> write bf16 (ushort, stride N); else fp32.
// ---------------------------------------------------------------------------
__global__ __launch_bounds__(256) void mfma_gemm_kernel(
    const unsigned short* __restrict__ Ahg, const unsigned short* __restrict__ Alg,
    const unsigned short* __restrict__ Whg, const unsigned short* __restrict__ Wlg,
    const float* __restrict__ bias, void* __restrict__ Cout,
    int M, int N, const int* __restrict__ cnt, int obf16) {
  int t = threadIdx.x;
  int bm = blockIdx.y*64, bn = blockIdx.x*64;
  {
    int r = bm + (t>>2);
    bool ok = (r < M) && ((r % S_TOT) < cnt[r / S_TOT]);
    if (__syncthreads_or(ok ? 1 : 0) == 0) return;
  }
  __shared__ unsigned short Ahs[64*64], Als[64*64], Whs[64*64], Wls[64*64];
  int lane = t & 63, w = t >> 6;
  int l15 = lane & 15, l4 = lane >> 4;

  const unsigned short* src;
  unsigned short* dst;
  if      (w == 0){ src = Ahg; dst = Ahs; }
  else if (w == 1){ src = Alg; dst = Als; }
  else if (w == 2){ src = Whg; dst = Whs; }
  else            { src = Wlg; dst = Wls; }
  int tb  = (w < 2) ? bm : bn;
  int lim = (w < 2) ? M  : N;
  int lrow = lane >> 3;
  int lg   = lane & 7;
  const unsigned short* gp[8];
  #pragma unroll
  for (int i=0;i<8;i++){
    int row_l = i*8 + lrow;
    int rg = tb + row_l; if (rg >= lim) rg = lim-1;
    gp[i] = src + (size_t)rg*512 + (size_t)((lg ^ (row_l&7))*8);
  }

  f32x4 acc[4];
  #pragma unroll
  for (int mt=0;mt<4;mt++) acc[mt] = (f32x4){0.f,0.f,0.f,0.f};

  for (int ch=0; ch<8; ch++){
    __syncthreads();
    #pragma unroll
    for (int i=0;i<8;i++)
      GLOAD16(gp[i] + ch*64, dst + i*512);
    __syncthreads();
    #pragma unroll
    for (int ks=0; ks<2; ks++){
      int wrow = w*16 + l15;
      int wgs = (ks*4 + l4) ^ (wrow & 7);
      bf16x8 wh = *(const bf16x8*)&Whs[wrow*64 + wgs*8];
      bf16x8 wl = *(const bf16x8*)&Wls[wrow*64 + wgs*8];
      #pragma unroll
      for (int mt=0;mt<4;mt++){
        int arow = mt*16 + l15;
        int ags = (ks*4 + l4) ^ (arow & 7);
        bf16x8 ah = *(const bf16x8*)&Ahs[arow*64 + ags*8];
        bf16x8 al = *(const bf16x8*)&Als[arow*64 + ags*8];
        acc[mt] = __builtin_amdgcn_mfma_f32_16x16x32_bf16(ah, wh, acc[mt], 0,0,0);
        acc[mt] = __builtin_amdgcn_mfma_f32_16x16x32_bf16(ah, wl, acc[mt], 0,0,0);
        acc[mt] = __builtin_amdgcn_mfma_f32_16x16x32_bf16(al, wh, acc[mt], 0,0,0);
      }
    }
  }
  int ncol = bn + w*16 + l15;
  float bv = bias[ncol];
  #pragma unroll
  for (int mt=0;mt<4;mt++){
    #pragma unroll
    for (int r=0;r<4;r++){
      int mrow = bm + mt*16 + l4*4 + r;
      bool ok = (mrow < M) && ((mrow % S_TOT) < cnt[mrow / S_TOT]);
      if (ok){
        float v = acc[mt][r] + bv;
        if (obf16) ((unsigned short*)Cout)[(size_t)mrow*N + ncol] = f2bf(v);
        else       ((float*)Cout)[(size_t)mrow*N + ncol] = v;
      }
    }
  }
}

// ---------------------------------------------------------------------------
// MFMA flash attention (layer 0), bf16 QKV input (stride 1536), compacted keys.
// ---------------------------------------------------------------------------
__global__ __launch_bounds__(256) void flash_attn_kernel(
    const unsigned short* __restrict__ qkv, const int* __restrict__ cnt,
    unsigned short* __restrict__ Oh, unsigned short* __restrict__ Ol) {
  int b = blockIdx.z, h = blockIdx.y;
  int cb = cnt[b];
  int S0 = blockIdx.x * 64;
  if (S0 >= cb) return;
  int t = threadIdx.x;
  int lane = t & 63, w = t >> 6;
  int l15 = lane & 15, l4 = lane >> 4;

  __shared__ unsigned short Kbf[64*64];
  __shared__ unsigned short Vt[64*64];
  __shared__ unsigned short Pbuf[4][16*64];

  const unsigned short* basep = qkv + (size_t)(b*S_TOT)*1536;

  int qg = S0 + w*16 + l15;
  int qr = (qg < cb) ? qg : 0;
  const unsigned short* qp = basep + (size_t)qr*1536 + h*64;
  bf16x8 Qf[2];
  Qf[0] = *(const bf16x8*)(qp + l4*8);
  Qf[1] = *(const bf16x8*)(qp + 32 + l4*8);

  float m_run = -1e30f, l_run = 0.f;
  f32x4 accO[4];
  #pragma unroll
  for (int mt=0;mt<4;mt++) accO[mt] = (f32x4){0.f,0.f,0.f,0.f};

  unsigned int* Ku = (unsigned int*)Kbf;
  unsigned int* Vu = (unsigned int*)Vt;
  const int nt = (cb + 63)/64;
  for (int kt=0; kt<nt; kt++){
    int K0 = kt*64;
    __syncthreads();
    {
      int key = t>>2;
      int keyr = (K0+key < cb) ? (K0+key) : 0;
      const unsigned short* kp = basep + (size_t)keyr*1536 + 512 + h*64 + (t&3)*16;
      uint4 a  = *(const uint4*)(kp);
      uint4 b2 = *(const uint4*)(kp+8);
      int g0 = (t&3)*2;
      int gs0 = g0 ^ (key&7), gs1 = (g0+1) ^ (key&7);
      *(uint4*)(Ku + key*32 + gs0*4) = a;
      *(uint4*)(Ku + key*32 + gs1*4) = b2;
    }
    {
      int kp2 = t & 31;
      int d8 = t >> 5;
      int k0g = K0 + 2*kp2;
      int kr0 = (k0g   < cb) ? k0g   : 0;
      int kr1 = (k0g+1 < cb) ? k0g+1 : 0;
      const unsigned short* vp0 = basep + (size_t)kr0*1536 + 1024 + h*64 + d8*8;
      const unsigned short* vp1 = basep + (size_t)kr1*1536 + 1024 + h*64 + d8*8;
      uint4 a = *(const uint4*)(vp0);
      uint4 c = *(const uint4*)(vp1);
      unsigned int au[4] = {a.x,a.y,a.z,a.w};
      unsigned int cu[4] = {c.x,c.y,c.z,c.w};
      int k8 = kp2 >> 2;
      #pragma unroll
      for (int dd=0; dd<8; dd++){
        int d = d8*8 + dd;
        Vu[d*32 + (k8 ^ (d&7))*4 + (kp2&3)] =
            pk2(ext16(au[dd>>1], dd&1), ext16(cu[dd>>1], dd&1));
      }
    }
    __syncthreads();

    f32x4 acc[4];
    #pragma unroll
    for (int mt=0;mt<4;mt++) acc[mt] = (f32x4){0.f,0.f,0.f,0.f};
    #pragma unroll
    for (int mt=0;mt<4;mt++){
      int row = mt*16 + l15;
      #pragma unroll
      for (int c=0;c<2;c++){
        int gs = (c*4 + l4) ^ (row & 7);
        bf16x8 kf = *(const bf16x8*)&Kbf[row*64 + gs*8];
        acc[mt] = __builtin_amdgcn_mfma_f32_16x16x32_bf16(kf, Qf[c], acc[mt], 0,0,0);
      }
    }
    float p[4][4];
    float tmax = -1e30f;
    #pragma unroll
    for (int mt=0;mt<4;mt++)
      #pragma unroll
      for (int r=0;r<4;r++){
        int key = K0 + mt*16 + l4*4 + r;
        float s = (key < cb) ? acc[mt][r]*0.125f : -1e30f;
        p[mt][r] = s;
        tmax = fmaxf(tmax, s);
      }
    tmax = fmaxf(tmax, __shfl_xor(tmax, 16));
    tmax = fmaxf(tmax, __shfl_xor(tmax, 32));
    float m_new = fmaxf(m_run, tmax);
    float alpha = __expf(m_run - m_new);
    float psum = 0.f;
    #pragma unroll
    for (int mt=0;mt<4;mt++)
      #pragma unroll
      for (int r=0;r<4;r++){
        float pv = __expf(p[mt][r] - m_new);
        p[mt][r] = pv; psum += pv;
      }
    psum += __shfl_xor(psum, 16);
    psum += __shfl_xor(psum, 32);
    l_run = l_run*alpha + psum;
    m_run = m_new;

    #pragma unroll
    for (int mt=0;mt<4;mt++){
      int keyl = mt*16 + l4*4;
      int gs = (keyl >> 3) ^ (l15 & 7);
      uint2 w2;
      w2.x = pk2(f2bf(p[mt][0]), f2bf(p[mt][1]));
      w2.y = pk2(f2bf(p[mt][2]), f2bf(p[mt][3]));
      *(uint2*)&Pbuf[w][ l15*64 + gs*8 + (keyl & 7) ] = w2;
    }
    #pragma unroll
    for (int mt=0;mt<4;mt++){
      accO[mt][0]*=alpha; accO[mt][1]*=alpha; accO[mt][2]*=alpha; accO[mt][3]*=alpha;
    }
    #pragma unroll
    for (int c2=0;c2<2;c2++){
      int gpv = (c2*4 + l4) ^ (l15 & 7);
      bf16x8 pf = *(const bf16x8*)&Pbuf[w][ l15*64 + gpv*8 ];
      #pragma unroll
      for (int mt=0;mt<4;mt++){
        int d = mt*16 + l15;
        int gv = (c2*4 + l4) ^ (d & 7);
        bf16x8 vf = *(const bf16x8*)&Vt[ d*64 + gv*8 ];
        accO[mt] = __builtin_amdgcn_mfma_f32_16x16x32_bf16(vf, pf, accO[mt], 0,0,0);
      }
    }
  }
  if (qg < cb){
    float inv = 1.f/l_run;
    size_t ro = ((size_t)(b*S_TOT) + qg)*512 + h*64;
    #pragma unroll
    for (int mt=0;mt<4;mt++){
      float v0 = accO[mt][0]*inv, v1 = accO[mt][1]*inv;
      float v2 = accO[mt][2]*inv, v3 = accO[mt][3]*inv;
      unsigned short h0=f2bf(v0), h1=f2bf(v1), h2=f2bf(v2), h3=f2bf(v3);
      uint2 hw; hw.x = pk2(h0,h1); hw.y = pk2(h2,h3);
      uint2 lw;
      lw.x = pk2(f2bf(v0-bfval(h0)), f2bf(v1-bfval(h1)));
      lw.y = pk2(f2bf(v2-bfval(h2)), f2bf(v3-bfval(h3)));
      *(uint2*)&Oh[ro + mt*16 + l4*4] = hw;
      *(uint2*)&Ol[ro + mt*16 + l4*4] = lw;
    }
  }
}

// ---------------------------------------------------------------------------
// q0[b][n] = bq[n] + dot(Wq_row_n, a1[b,row0]); wave-per-neuron, fp32 exact.
// ---------------------------------------------------------------------------
__global__ __launch_bounds__(256) void row0_q_kernel(
    const unsigned short* __restrict__ Ah, const unsigned short* __restrict__ Al,
    const float* __restrict__ Wq, const float* __restrict__ bq,
    float* __restrict__ q0) {
  int b = blockIdx.y;
  int n = blockIdx.x*4 + (threadIdx.x >> 6);
  int lane = threadIdx.x & 63;
  __shared__ float xs[512];
  size_t ro = (size_t)(b*S_TOT)*512;
  for (int i=threadIdx.x; i<512; i+=256)
    xs[i] = bfval(Ah[ro+i]) + bfval(Al[ro+i]);
  __syncthreads();
  const float* wr = Wq + (size_t)n*512;
  float acc = 0.f;
  #pragma unroll
  for (int k=lane*4; k<512; k+=256){
    float4 u = *(const float4*)(wr + k);
    acc += xs[k]*u.x + xs[k+1]*u.y + xs[k+2]*u.z + xs[k+3]*u.w;
  }
  #pragma unroll
  for (int o=32;o;o>>=1) acc += __shfl_down(acc, o);
  if (lane==0) q0[b*512 + n] = acc + bq[n];
}

// ---------------------------------------------------------------------------
// Split-K row-0 attention, phase 1: block (h, b, chunk) computes partial
// softmax over its key range: m_c, l_c, N_c[d] = sum exp(s-m_c)*v[d].
// ---------------------------------------------------------------------------
__global__ __launch_bounds__(256) void attn_row0_part_kernel(
    const unsigned short* __restrict__ kv, const float* __restrict__ q0,
    const int* __restrict__ cnt,
    float* __restrict__ partM, float* __restrict__ partL,
    float* __restrict__ partN) {
  int h = blockIdx.x, b = blockIdx.y, c = blockIdx.z;
  int cb = cnt[b];
  int chunk = (cb + NCHUNK-1)/NCHUNK;
  int j0 = c*chunk;
  int j1 = j0+chunk; if (j1 > cb) j1 = cb;
  int t = threadIdx.x;
  int pidx = (b*NH + h)*NCHUNK + c;
  __shared__ float qs[64];
  __shared__ float sc[144];     // chunk <= ceil(2049/16) = 129
  __shared__ float red[8];
  __shared__ float redO[4][64];
  if (t < 64) qs[t] = q0[b*512 + h*64 + t]*0.125f;
  __syncthreads();
  if (j0 >= cb){
    if (t == 0){ partM[pidx] = -1e30f; partL[pidx] = 0.f; }
    if (t < 64) partN[(size_t)pidx*64 + t] = 0.f;
    return;
  }
  const unsigned short* base = kv + (size_t)b*S_TOT*1024;
  int len = j1 - j0;
  float lmax = -1e30f;
  for (int jj=t; jj<len; jj+=256){
    const unsigned short* kp = base + (size_t)(j0+jj)*1024 + h*64;
    float s = 0.f;
    #pragma unroll
    for (int d8=0; d8<8; d8++){
      uint4 a = *(const uint4*)(kp + d8*8);
      unsigned int au[4] = {a.x,a.y,a.z,a.w};
      #pragma unroll
      for (int q2=0; q2<4; q2++){
        s += qs[d8*8+q2*2]*bfval(ext16(au[q2],0))
           + qs[d8*8+q2*2+1]*bfval(ext16(au[q2],1));
      }
    }
    sc[jj] = s;
    lmax = fmaxf(lmax, s);
  }
  #pragma unroll
  for (int o=32;o;o>>=1) lmax = fmaxf(lmax, __shfl_down(lmax,o));
  if ((t&63)==0) red[t>>6] = lmax;
  __syncthreads();
  float m = fmaxf(fmaxf(red[0],red[1]),fmaxf(red[2],red[3]));
  float lsum = 0.f;
  for (int jj=t; jj<len; jj+=256){
    float p = __expf(sc[jj]-m);
    sc[jj] = p; lsum += p;
  }
  #pragma unroll
  for (int o=32;o;o>>=1) lsum += __shfl_down(lsum,o);
  __syncthreads();
  if ((t&63)==0) red[t>>6] = lsum;
  __syncthreads();
  float l = red[0]+red[1]+red[2]+red[3];
  int d = t & 63, rr = t >> 6;
  float acc = 0.f;
  for (int jj=rr; jj<len; jj+=4)
    acc += sc[jj]*bfval(base[(size_t)(j0+jj)*1024 + 512 + h*64 + d]);
  redO[rr][d] = acc;
  __syncthreads();
  if (t < 64){
    partN[(size_t)pidx*64 + t] = redO[0][t]+redO[1][t]+redO[2][t]+redO[3][t];
    if (t==0){ partM[pidx] = m; partL[pidx] = l; }
  }
}

// phase 2: combine partials. block (h, b), 64 threads (d).
__global__ __launch_bounds__(64) void attn_row0_combine_kernel(
    const float* __restrict__ partM, const float* __restrict__ partL,
    const float* __restrict__ partN, float* __restrict__ out0) {
  int h = blockIdx.x, b = blockIdx.y;
  int t = threadIdx.x;
  int pb = (b*NH + h)*NCHUNK;
  float m = -1e30f;
  #pragma unroll
  for (int c=0;c<NCHUNK;c++) m = fmaxf(m, partM[pb+c]);
  float lsum = 0.f, nsum = 0.f;
  #pragma unroll
  for (int c=0;c<NCHUNK;c++){
    float w = __expf(partM[pb+c]-m);
    lsum += w*partL[pb+c];
    nsum += w*partN[(size_t)(pb+c)*64 + t];
  }
  out0[b*512 + h*64 + t] = nsum/lsum;
}

// layer-1 out-proj for row 0 + residual(z row0) + LN -> cls embedding slot
__global__ __launch_bounds__(256) void row0_proj_ln_kernel(
    const float* __restrict__ attn0, const float* __restrict__ Wo, const float* __restrict__ bo,
    const unsigned short* __restrict__ Zh, const unsigned short* __restrict__ Zl,
    const float* __restrict__ g, const float* __restrict__ be,
    float* __restrict__ clsbuf, int branch) {
  int b = blockIdx.x, t = threadIdx.x;
  __shared__ float xin[512];
  __shared__ float y[512];
  __shared__ float red[16];
  for (int i=t;i<512;i+=256) xin[i] = attn0[b*512+i];
  __syncthreads();
  size_t z0 = (size_t)b*S_TOT*512;
  for (int n=t;n<512;n+=256){
    const float4* wr = (const float4*)(Wo + (size_t)n*512);
    float acc = bo[n];
    for (int k4=0;k4<128;k4++){
      float4 u = wr[k4]; int k=k4*4;
      acc += xin[k+0]*u.x + xin[k+1]*u.y + xin[k+2]*u.z + xin[k+3]*u.w;
    }
    y[n] = acc + bfval(Zh[z0+n]) + bfval(Zl[z0+n]);
  }
  __syncthreads();
  float s1=0.f, s2=0.f;
  for (int i=t;i<512;i+=256){ float a=y[i]; s1+=a; s2+=a*a; }
  #pragma unroll
  for (int o=32;o;o>>=1){ s1+=__shfl_down(s1,o); s2+=__shfl_down(s2,o); }
  if ((t&63)==0){ red[t>>6]=s1; red[8+(t>>6)]=s2; }
  __syncthreads();
  s1 = red[0]+red[1]+red[2]+red[3];
  s2 = red[8]+red[9]+red[10]+red[11];
  float mean = s1*(1.f/512.f);
  float var  = s2*(1.f/512.f) - mean*mean;
  float rn = rsqrtf(var + 1e-5f);
  for (int i=t;i<512;i+=256)
    clsbuf[b*1024 + branch*512 + i] = (y[i]-mean)*rn*g[i] + be[i];
}

// ---------------------------------------------------------------------------
// Final MLP layer (wave-per-neuron GEMV).
// ---------------------------------------------------------------------------
__global__ __launch_bounds__(256) void fm_layer_kernel(
    const float* __restrict__ in, const float* __restrict__ W,
    const float* __restrict__ bias, float* __restrict__ out,
    int K, int N, int act) {
  int b = blockIdx.y;
  int n = blockIdx.x*4 + (threadIdx.x >> 6);
  int lane = threadIdx.x & 63;
  __shared__ float xs[1024];
  for (int i=threadIdx.x; i<K; i+=256) xs[i] = in[(size_t)b*K + i];
  __syncthreads();
  const float* wr = W + (size_t)n*K;
  float acc = 0.f;
  #pragma unroll 4
  for (int k=lane*4; k<K; k+=256){
    float4 u = *(const float4*)(wr + k);
    acc += xs[k]*u.x + xs[k+1]*u.y + xs[k+2]*u.z + xs[k+3]*u.w;
  }
  #pragma unroll
  for (int o=32;o;o>>=1) acc += __shfl_down(acc, o);
  if (lane==0){
    float v = acc + bias[n];
    if (act) v = gelu_exact(v);
    out[(size_t)b*N + n] = v;
  }
}

// ---------------------------------------------------------------------------
extern "C" void kernel_launch(void* const* d_in, const int* in_sizes, int n_in,
                              void* d_out, int out_size, void* d_ws, size_t ws_size,
                              hipStream_t stream) {
  const float* x      = (const float*)d_in[0];
  const float* cls_tk = (const float*)d_in[1];
  const float* ln_g   = (const float*)d_in[2];
  const float* ln_b   = (const float*)d_in[3];
  const float* aw_W0  = (const float*)d_in[4];  const float* aw_b0 = (const float*)d_in[5];
  const float* aw_W1  = (const float*)d_in[6];  const float* aw_b1 = (const float*)d_in[7];
  const float* aw_W2  = (const float*)d_in[8];  const float* aw_b2 = (const float*)d_in[9];
  const float* pr_W0  = (const float*)d_in[10]; const float* pr_b0 = (const float*)d_in[11];
  const float* pr_W1  = (const float*)d_in[12]; const float* pr_b1 = (const float*)d_in[13];
  const float* pr_W2  = (const float*)d_in[14]; const float* pr_b2 = (const float*)d_in[15];
  const float* mWqkv[2] = {(const float*)d_in[16], (const float*)d_in[20]};
  const float* mbqkv[2] = {(const float*)d_in[17], (const float*)d_in[21]};
  const float* mWo[2]   = {(const float*)d_in[18], (const float*)d_in[22]};
  const float* mbo[2]   = {(const float*)d_in[19], (const float*)d_in[23]};

  float* ws = (float*)d_ws;
  size_t off = 0;
  float* weight = ws + off; off += 8192;                      // [B,N]
  int*   idx    = (int*)(ws + off); off += 8448;              // [B,S]
  int*   cnt    = (int*)(ws + off); off += 16;                // [B]
  float* W0T    = ws + off; off += 32768;                     // [512][64]
  const size_t HBUF = (size_t)ROWS*512/2;                     // bf16 array in float units
  unsigned short* Zh = (unsigned short*)(ws + off); off += HBUF;
  unsigned short* Zl = (unsigned short*)(ws + off); off += HBUF;
  float* QKVr   = ws + off; off += (size_t)ROWS*1536;         // shared region:
  unsigned short* QKVb = (unsigned short*)QKVr;               //  layer-0 QKV bf16 (stride 1536)
  float* T2     = QKVr;                                       //  out-proj result fp32 (stride 512)
  unsigned short* KVb  = (unsigned short*)QKVr;               //  layer-1 KV bf16 (stride 1024)
  unsigned short* Oh = (unsigned short*)(ws + off); off += HBUF;  // also a1 hi
  unsigned short* Ol = (unsigned short*)(ws + off); off += HBUF;  // also a1 lo
  unsigned short* Wq0h = (unsigned short*)(ws + off); off += 393216;
  unsigned short* Wq0l = (unsigned short*)(ws + off); off += 393216;
  unsigned short* Wq1h = (unsigned short*)(ws + off); off += 393216;
  unsigned short* Wq1l = (unsigned short*)(ws + off); off += 393216;
  unsigned short* Wo0h = (unsigned short*)(ws + off); off += 131072;
  unsigned short* Wo0l = (unsigned short*)(ws + off); off += 131072;
  float* attn0  = ws + off; off += 2048;                      // [B,D]
  float* q0buf  = ws + off; off += 2048;                      // [B,D]
  float* clsb   = ws + off; off += 4096;                      // [B,2D]
  float* h1buf  = ws + off; off += 2048;                      // [B,D]
  float* h2buf  = ws + off; off += 2048;                      // [B,D]
  float* partM  = ws + off; off += B_SZ*NH*NCHUNK;            // 512
  float* partL  = ws + off; off += B_SZ*NH*NCHUNK;            // 512
  float* partN  = ws + off; off += (size_t)B_SZ*NH*NCHUNK*64; // 32768
  (void)ws_size; (void)in_sizes; (void)n_in; (void)out_size;

  transpose_w0_kernel<<<(32768+255)/256, 256, 0, stream>>>(aw_W0, W0T);
  aw_weight_kernel<<<B_SZ*N_INST, 64, 0, stream>>>(
      x, W0T, aw_b0, aw_W1, aw_b1, aw_W2, aw_b2, weight);

  split_kernel<<<(786432+255)/256, 256, 0, stream>>>(mWqkv[0], Wq0h, Wq0l, 786432);
  split_kernel<<<(786432+255)/256, 256, 0, stream>>>(mWqkv[1], Wq1h, Wq1l, 786432);
  split_kernel<<<(262144+255)/256, 256, 0, stream>>>(mWo[0],  Wo0h, Wo0l, 262144);

  for (int br=0; br<2; br++){
    compact_kernel<<<B_SZ, 256, 0, stream>>>(weight, br, idx, cnt);
    build_z_kernel<<<ROWS, 256, 0, stream>>>(x, weight, cls_tk, ln_g, ln_b, br, idx, cnt, Zh, Zl);
    // layer 0 (QKV written bf16)
    mfma_gemm_kernel<<<dim3(1536/64, (ROWS+63)/64), 256, 0, stream>>>(
        Zh, Zl, Wq0h, Wq0l, mbqkv[0], QKVb, ROWS, 1536, cnt, 1);
    flash_attn_kernel<<<dim3((S_TOT+63)/64, NH, B_SZ), 256, 0, stream>>>(QKVb, cnt, Oh, Ol);
    mfma_gemm_kernel<<<dim3(512/64, (ROWS+63)/64), 256, 0, stream>>>(
        Oh, Ol, Wo0h, Wo0l, mbo[0], T2, ROWS, 512, cnt, 0);
    add_ln_kernel<<<ROWS, 256, 0, stream>>>(Zh, Zl, T2, ln_g, ln_b, cnt, Oh, Ol); // a1 -> Oh/Ol
    // layer 1: row0 Q via fp32 GEMV; KV for all rows, bf16 (stride 1024)
    row0_q_kernel<<<dim3(128, B_SZ), 256, 0, stream>>>(Oh, Ol, mWqkv[1], mbqkv[1], q0buf);
    mfma_gemm_kernel<<<dim3(1024/64, (ROWS+63)/64), 256, 0, stream>>>(
        Oh, Ol, Wq1h + (size_t)512*512, Wq1l + (size_t)512*512,
        mbqkv[1] + 512, KVb, ROWS, 1024, cnt, 1);
    // split-K row-0 attention: 512-block partial phase + tiny combine
    attn_row0_part_kernel<<<dim3(NH, B_SZ, NCHUNK), 256, 0, stream>>>(
        KVb, q0buf, cnt, partM, partL, partN);
    attn_row0_combine_kernel<<<dim3(NH, B_SZ), 64, 0, stream>>>(
        partM, partL, partN, attn0);
    row0_proj_ln_kernel<<<B_SZ, 256, 0, stream>>>(
        attn0, mWo[1], mbo[1], Zh, Zl, ln_g, ln_b, clsb, br);
  }
  // final MLP: 3 wave-per-neuron GEMV layers
  fm_layer_kernel<<<dim3(128, B_SZ), 256, 0, stream>>>(clsb,  pr_W0, pr_b0, h1buf, 1024, 512, 1);
  fm_layer_kernel<<<dim3(128, B_SZ), 256, 0, stream>>>(h1buf, pr_W1, pr_b1, h2buf,  512, 512, 1);
  fm_layer_kernel<<<dim3(128, B_SZ), 256, 0, stream>>>(h2buf, pr_W2, pr_b2, (float*)d_out, 512, 512, 0);
}

// Round 11
// 486.406 us; speedup vs baseline: 8.1653x; 1.2610x over previous
//
#include <hip/hip_runtime.h>
#include <hip/hip_bf16.h>

#define B_SZ 4
#define N_INST 2048
#define D_MODEL 512
#define S_TOT 2049          // N+1 (cls prepended)
#define NH 8
#define HD 64
#define VB 8                // virtual batches = 2 branches x 4 batch
#define VROWS (VB*S_TOT)    // 16392
#define NCHUNK 16           // split-K chunks for row-0 attention

typedef __attribute__((ext_vector_type(4))) float f32x4;
typedef __attribute__((ext_vector_type(8))) short bf16x8;

__device__ __forceinline__ float gelu_exact(float x){ return 0.5f*x*(1.f+erff(x*0.70710678118654752f)); }
__device__ __forceinline__ unsigned short f2bf(float x){
  unsigned int u = __float_as_uint(x);
  u += 0x7fffu + ((u>>16)&1u);
  return (unsigned short)(u>>16);
}
__device__ __forceinline__ float bfval(unsigned short u){ return __uint_as_float(((unsigned int)u)<<16); }
__device__ __forceinline__ unsigned int pk2(unsigned short lo, unsigned short hi){
  return (unsigned int)lo | ((unsigned int)hi << 16);
}
__device__ __forceinline__ unsigned short ext16(unsigned int u, int hi){
  return (unsigned short)(hi ? (u>>16) : (u & 0xffffu));
}

#define GLOAD16(gp, lp) __builtin_amdgcn_global_load_lds( \
    (const __attribute__((address_space(1))) void*)(gp), \
    (__attribute__((address_space(3))) void*)(lp), 16, 0, 0)

// ---------------------------------------------------------------------------
// One-time transpose: W0T[k][h] = W0[h][k]   (64x512 -> 512x64, fp32)
// ---------------------------------------------------------------------------
__global__ __launch_bounds__(256) void transpose_w0_kernel(
    const float* __restrict__ W0, float* __restrict__ W0T) {
  int i = blockIdx.x*256 + threadIdx.x;
  if (i < 64*512){
    int h = i >> 9, k = i & 511;
    W0T[k*64 + h] = W0[i];
  }
}

// ---------------------------------------------------------------------------
// Gating MLP (fp32: the w<0.5 mask is a threshold — bf16 risks branch flips).
// ---------------------------------------------------------------------------
__global__ __launch_bounds__(64) void aw_weight_kernel(
    const float* __restrict__ x,
    const float* __restrict__ W0T, const float* __restrict__ b0,
    const float* __restrict__ W1, const float* __restrict__ b1,
    const float* __restrict__ W2, const float* __restrict__ b2,
    float* __restrict__ weight) {
  int inst = blockIdx.x;
  int h = threadIdx.x;
  __shared__ float xs[512];
  __shared__ float hs[64];
  const float* xp = x + (size_t)inst*D_MODEL;
  for (int i=h;i<512;i+=64) xs[i] = xp[i];
  __syncthreads();
  float acc = b0[h];
  const float* w0c = W0T + h;
  #pragma unroll 16
  for (int k=0;k<512;k++)
    acc = fmaf(xs[k], w0c[k*64], acc);
  hs[h] = gelu_exact(acc);
  __syncthreads();
  const float4* w1 = (const float4*)(W1 + (size_t)h*64);
  float acc2 = b1[h];
  #pragma unroll
  for (int k4=0;k4<16;k4++){
    float4 u = w1[k4]; int k = k4*4;
    acc2 += hs[k+0]*u.x + hs[k+1]*u.y + hs[k+2]*u.z + hs[k+3]*u.w;
  }
  float h2 = gelu_exact(acc2);
  float p = h2 * W2[h];
  #pragma unroll
  for (int o=32;o;o>>=1) p += __shfl_down(p, o);
  if (h==0){
    float s = p + b2[0];
    weight[inst] = 1.f/(1.f+expf(-s));
  }
}

// ---------------------------------------------------------------------------
// Split fp32 -> (hi, lo) bf16 pair.
// ---------------------------------------------------------------------------
__global__ __launch_bounds__(256) void split_kernel(
    const float* __restrict__ w, unsigned short* __restrict__ hi,
    unsigned short* __restrict__ lo, int n) {
  int i = blockIdx.x*256 + threadIdx.x;
  if (i < n){
    float v = w[i];
    unsigned short h = f2bf(v);
    hi[i] = h;
    lo[i] = f2bf(v - bfval(h));
  }
}

// ---------------------------------------------------------------------------
// Compaction per virtual batch vb = branch*4 + b (slot0 = cls).
// ---------------------------------------------------------------------------
__global__ __launch_bounds__(256) void compact_kernel(
    const float* __restrict__ weight,
    int* __restrict__ idx, int* __restrict__ cnt) {
  int vb = blockIdx.x;
  int b = vb & 3, branch = vb >> 2;
  int t = threadIdx.x;
  int lane = t & 63, wv = t >> 6;
  __shared__ int wsum[4];
  __shared__ int base_s;
  if (t==0){ idx[vb*S_TOT] = 0; base_s = 1; }
  __syncthreads();
  for (int c0=0; c0<N_INST; c0+=256){
    int n = c0 + t;
    float w = weight[b*N_INST + n];
    bool neg = (w < 0.5f);
    bool val = (branch==0) ? neg : !neg;
    unsigned long long m = __ballot(val);
    int prefix = __popcll(m & ((1ull<<lane)-1ull));
    if (lane==0) wsum[wv] = __popcll(m);
    __syncthreads();
    int wbase = 0;
    #pragma unroll
    for (int i=0;i<4;i++) if (i<wv) wbase += wsum[i];
    int total = wsum[0]+wsum[1]+wsum[2]+wsum[3];
    int mybase = base_s;
    if (val) idx[vb*S_TOT + mybase + wbase + prefix] = n + 1;
    __syncthreads();
    if (t==0) base_s += total;
    __syncthreads();
  }
  if (t==0) cnt[vb] = base_s;
}

// ---------------------------------------------------------------------------
// Build compacted z = LN(scale*seq[idx]) -> hi/lo bf16 pair. grid = VROWS.
// ---------------------------------------------------------------------------
__global__ __launch_bounds__(256) void build_z_kernel(
    const float* __restrict__ x, const float* __restrict__ weight,
    const float* __restrict__ cls, const float* __restrict__ g, const float* __restrict__ be,
    const int* __restrict__ idx, const int* __restrict__ cnt,
    unsigned short* __restrict__ Zh, unsigned short* __restrict__ Zl) {
  int row = blockIdx.x;
  int vb = row / S_TOT, slot = row % S_TOT;
  if (slot >= cnt[vb]) return;
  int b = vb & 3, branch = vb >> 2;
  int t = threadIdx.x;
  __shared__ float v[512];
  __shared__ float red[16];
  int pos = idx[vb*S_TOT + slot];
  float scale = 1.f;
  const float* src = cls;
  if (pos != 0){
    float w = weight[b*N_INST + (pos-1)];
    scale = (branch==0) ? powf(w, 1.5f) : powf(w, 2.0f/3.0f);
    src = x + ((size_t)b*N_INST + (pos-1))*D_MODEL;
  }
  float s1=0.f, s2=0.f;
  for (int i=t;i<512;i+=256){
    float val = src[i];
    if (pos != 0) val *= scale;
    v[i]=val; s1+=val; s2+=val*val;
  }
  __syncthreads();
  #pragma unroll
  for (int o=32;o;o>>=1){ s1+=__shfl_down(s1,o); s2+=__shfl_down(s2,o); }
  if ((t&63)==0){ red[t>>6]=s1; red[8+(t>>6)]=s2; }
  __syncthreads();
  s1 = red[0]+red[1]+red[2]+red[3];
  s2 = red[8]+red[9]+red[10]+red[11];
  float mean = s1 * (1.f/512.f);
  float var  = s2 * (1.f/512.f) - mean*mean;
  float rn = rsqrtf(var + 1e-5f);
  size_t ro = (size_t)row*512;
  for (int i=t;i<512;i+=256){
    float o = (v[i]-mean)*rn*g[i] + be[i];
    unsigned short hbits = f2bf(o);
    Zh[ro+i] = hbits;
    Zl[ro+i] = f2bf(o - bfval(hbits));
  }
}

// out = LN((Zh+Zl) + T2) rowwise -> hi/lo bf16 pair (the a1 operand)
__global__ __launch_bounds__(256) void add_ln_kernel(
    const unsigned short* __restrict__ Zh, const unsigned short* __restrict__ Zl,
    const float* __restrict__ T2,
    const float* __restrict__ g, const float* __restrict__ be,
    const int* __restrict__ cnt,
    unsigned short* __restrict__ Ah, unsigned short* __restrict__ Al) {
  int row = blockIdx.x;
  if ((row % S_TOT) >= cnt[row / S_TOT]) return;
  int t = threadIdx.x;
  __shared__ float v[512];
  __shared__ float red[16];
  size_t ro = (size_t)row*512;
  float s1=0.f, s2=0.f;
  for (int i=t;i<512;i+=256){
    float val = bfval(Zh[ro+i]) + bfval(Zl[ro+i]) + T2[ro+i];
    v[i]=val; s1+=val; s2+=val*val;
  }
  __syncthreads();
  #pragma unroll
  for (int o=32;o;o>>=1){ s1+=__shfl_down(s1,o); s2+=__shfl_down(s2,o); }
  if ((t&63)==0){ red[t>>6]=s1; red[8+(t>>6)]=s2; }
  __syncthreads();
  s1 = red[0]+red[1]+red[2]+red[3];
  s2 = red[8]+red[9]+red[10]+red[11];
  float mean = s1 * (1.f/512.f);
  float var  = s2 * (1.f/512.f) - mean*mean;
  float rn = rsqrtf(var + 1e-5f);
  for (int i=t;i<512;i+=256){
    float o = (v[i]-mean)*rn*g[i] + be[i];
    unsigned short hbits = f2bf(o);
    Ah[ro+i] = hbits;
    Al[ro+i] = f2bf(o - bfval(hbits));
  }
}

// ---------------------------------------------------------------------------
// MFMA GEMM (bf16 hi/lo 3-pass): C[M,N] = (Ah+Al)[M,512] @ (Wh+Wl)[N,512]^T + bias.
// obf16=1 -> write bf16 (ushort, stride N); else fp32.
// ---------------------------------------------------------------------------
__global__ __launch_bounds__(256) void mfma_gemm_kernel(
    const unsigned short* __restrict__ Ahg, const unsigned short* __restrict__ Alg,
    const unsigned short* __restrict__ Whg, const unsigned short* __restrict__ Wlg,
    const float* __restrict__ bias, void* __restrict__ Cout,
    int M, int N, const int* __restrict__ cnt, int obf16) {
  int t = threadIdx.x;
  int bm = blockIdx.y*64, bn = blockIdx.x*64;
  {
    int r = bm + (t>>2);
    bool ok = (r < M) && ((r % S_TOT) < cnt[r / S_TOT]);
    if (__syncthreads_or(ok ? 1 : 0) == 0) return;
  }
  __shared__ unsigned short Ahs[64*64], Als[64*64], Whs[64*64], Wls[64*64];
  int lane = t & 63, w = t >> 6;
  int l15 = lane & 15, l4 = lane >> 4;

  const unsigned short* src;
  unsigned short* dst;
  if      (w == 0){ src = Ahg; dst = Ahs; }
  else if (w == 1){ src = Alg; dst = Als; }
  else if (w == 2){ src = Whg; dst = Whs; }
  else            { src = Wlg; dst = Wls; }
  int tb  = (w < 2) ? bm : bn;
  int lim = (w < 2) ? M  : N;
  int lrow = lane >> 3;
  int lg   = lane & 7;
  const unsigned short* gp[8];
  #pragma unroll
  for (int i=0;i<8;i++){
    int row_l = i*8 + lrow;
    int rg = tb + row_l; if (rg >= lim) rg = lim-1;
    gp[i] = src + (size_t)rg*512 + (size_t)((lg ^ (row_l&7))*8);
  }

  f32x4 acc[4];
  #pragma unroll
  for (int mt=0;mt<4;mt++) acc[mt] = (f32x4){0.f,0.f,0.f,0.f};

  for (int ch=0; ch<8; ch++){
    __syncthreads();
    #pragma unroll
    for (int i=0;i<8;i++)
      GLOAD16(gp[i] + ch*64, dst + i*512);
    __syncthreads();
    #pragma unroll
    for (int ks=0; ks<2; ks++){
      int wrow = w*16 + l15;
      int wgs = (ks*4 + l4) ^ (wrow & 7);
      bf16x8 wh = *(const bf16x8*)&Whs[wrow*64 + wgs*8];
      bf16x8 wl = *(const bf16x8*)&Wls[wrow*64 + wgs*8];
      #pragma unroll
      for (int mt=0;mt<4;mt++){
        int arow = mt*16 + l15;
        int ags = (ks*4 + l4) ^ (arow & 7);
        bf16x8 ah = *(const bf16x8*)&Ahs[arow*64 + ags*8];
        bf16x8 al = *(const bf16x8*)&Als[arow*64 + ags*8];
        acc[mt] = __builtin_amdgcn_mfma_f32_16x16x32_bf16(ah, wh, acc[mt], 0,0,0);
        acc[mt] = __builtin_amdgcn_mfma_f32_16x16x32_bf16(ah, wl, acc[mt], 0,0,0);
        acc[mt] = __builtin_amdgcn_mfma_f32_16x16x32_bf16(al, wh, acc[mt], 0,0,0);
      }
    }
  }
  int ncol = bn + w*16 + l15;
  float bv = bias[ncol];
  #pragma unroll
  for (int mt=0;mt<4;mt++){
    #pragma unroll
    for (int r=0;r<4;r++){
      int mrow = bm + mt*16 + l4*4 + r;
      bool ok = (mrow < M) && ((mrow % S_TOT) < cnt[mrow / S_TOT]);
      if (ok){
        float v = acc[mt][r] + bv;
        if (obf16) ((unsigned short*)Cout)[(size_t)mrow*N + ncol] = f2bf(v);
        else       ((float*)Cout)[(size_t)mrow*N + ncol] = v;
      }
    }
  }
}

// ---------------------------------------------------------------------------
// MFMA flash attention (layer 0), bf16 QKV (stride 1536), vb = blockIdx.z.
// ---------------------------------------------------------------------------
__global__ __launch_bounds__(256) void flash_attn_kernel(
    const unsigned short* __restrict__ qkv, const int* __restrict__ cnt,
    unsigned short* __restrict__ Oh, unsigned short* __restrict__ Ol) {
  int vb = blockIdx.z, h = blockIdx.y;
  int cb = cnt[vb];
  int S0 = blockIdx.x * 64;
  if (S0 >= cb) return;
  int t = threadIdx.x;
  int lane = t & 63, w = t >> 6;
  int l15 = lane & 15, l4 = lane >> 4;

  __shared__ unsigned short Kbf[64*64];
  __shared__ unsigned short Vt[64*64];
  __shared__ unsigned short Pbuf[4][16*64];

  const unsigned short* basep = qkv + (size_t)(vb*S_TOT)*1536;

  int qg = S0 + w*16 + l15;
  int qr = (qg < cb) ? qg : 0;
  const unsigned short* qp = basep + (size_t)qr*1536 + h*64;
  bf16x8 Qf[2];
  Qf[0] = *(const bf16x8*)(qp + l4*8);
  Qf[1] = *(const bf16x8*)(qp + 32 + l4*8);

  float m_run = -1e30f, l_run = 0.f;
  f32x4 accO[4];
  #pragma unroll
  for (int mt=0;mt<4;mt++) accO[mt] = (f32x4){0.f,0.f,0.f,0.f};

  unsigned int* Ku = (unsigned int*)Kbf;
  unsigned int* Vu = (unsigned int*)Vt;
  const int nt = (cb + 63)/64;
  for (int kt=0; kt<nt; kt++){
    int K0 = kt*64;
    __syncthreads();
    {
      int key = t>>2;
      int keyr = (K0+key < cb) ? (K0+key) : 0;
      const unsigned short* kp = basep + (size_t)keyr*1536 + 512 + h*64 + (t&3)*16;
      uint4 a  = *(const uint4*)(kp);
      uint4 b2 = *(const uint4*)(kp+8);
      int g0 = (t&3)*2;
      int gs0 = g0 ^ (key&7), gs1 = (g0+1) ^ (key&7);
      *(uint4*)(Ku + key*32 + gs0*4) = a;
      *(uint4*)(Ku + key*32 + gs1*4) = b2;
    }
    {
      int kp2 = t & 31;
      int d8 = t >> 5;
      int k0g = K0 + 2*kp2;
      int kr0 = (k0g   < cb) ? k0g   : 0;
      int kr1 = (k0g+1 < cb) ? k0g+1 : 0;
      const unsigned short* vp0 = basep + (size_t)kr0*1536 + 1024 + h*64 + d8*8;
      const unsigned short* vp1 = basep + (size_t)kr1*1536 + 1024 + h*64 + d8*8;
      uint4 a = *(const uint4*)(vp0);
      uint4 c = *(const uint4*)(vp1);
      unsigned int au[4] = {a.x,a.y,a.z,a.w};
      unsigned int cu[4] = {c.x,c.y,c.z,c.w};
      int k8 = kp2 >> 2;
      #pragma unroll
      for (int dd=0; dd<8; dd++){
        int d = d8*8 + dd;
        Vu[d*32 + (k8 ^ (d&7))*4 + (kp2&3)] =
            pk2(ext16(au[dd>>1], dd&1), ext16(cu[dd>>1], dd&1));
      }
    }
    __syncthreads();

    f32x4 acc[4];
    #pragma unroll
    for (int mt=0;mt<4;mt++) acc[mt] = (f32x4){0.f,0.f,0.f,0.f};
    #pragma unroll
    for (int mt=0;mt<4;mt++){
      int row = mt*16 + l15;
      #pragma unroll
      for (int c=0;c<2;c++){
        int gs = (c*4 + l4) ^ (row & 7);
        bf16x8 kf = *(const bf16x8*)&Kbf[row*64 + gs*8];
        acc[mt] = __builtin_amdgcn_mfma_f32_16x16x32_bf16(kf, Qf[c], acc[mt], 0,0,0);
      }
    }
    float p[4][4];
    float tmax = -1e30f;
    #pragma unroll
    for (int mt=0;mt<4;mt++)
      #pragma unroll
      for (int r=0;r<4;r++){
        int key = K0 + mt*16 + l4*4 + r;
        float s = (key < cb) ? acc[mt][r]*0.125f : -1e30f;
        p[mt][r] = s;
        tmax = fmaxf(tmax, s);
      }
    tmax = fmaxf(tmax, __shfl_xor(tmax, 16));
    tmax = fmaxf(tmax, __shfl_xor(tmax, 32));
    float m_new = fmaxf(m_run, tmax);
    float alpha = __expf(m_run - m_new);
    float psum = 0.f;
    #pragma unroll
    for (int mt=0;mt<4;mt++)
      #pragma unroll
      for (int r=0;r<4;r++){
        float pv = __expf(p[mt][r] - m_new);
        p[mt][r] = pv; psum += pv;
      }
    psum += __shfl_xor(psum, 16);
    psum += __shfl_xor(psum, 32);
    l_run = l_run*alpha + psum;
    m_run = m_new;

    #pragma unroll
    for (int mt=0;mt<4;mt++){
      int keyl = mt*16 + l4*4;
      int gs = (keyl >> 3) ^ (l15 & 7);
      uint2 w2;
      w2.x = pk2(f2bf(p[mt][0]), f2bf(p[mt][1]));
      w2.y = pk2(f2bf(p[mt][2]), f2bf(p[mt][3]));
      *(uint2*)&Pbuf[w][ l15*64 + gs*8 + (keyl & 7) ] = w2;
    }
    #pragma unroll
    for (int mt=0;mt<4;mt++){
      accO[mt][0]*=alpha; accO[mt][1]*=alpha; accO[mt][2]*=alpha; accO[mt][3]*=alpha;
    }
    #pragma unroll
    for (int c2=0;c2<2;c2++){
      int gpv = (c2*4 + l4) ^ (l15 & 7);
      bf16x8 pf = *(const bf16x8*)&Pbuf[w][ l15*64 + gpv*8 ];
      #pragma unroll
      for (int mt=0;mt<4;mt++){
        int d = mt*16 + l15;
        int gv = (c2*4 + l4) ^ (d & 7);
        bf16x8 vf = *(const bf16x8*)&Vt[ d*64 + gv*8 ];
        accO[mt] = __builtin_amdgcn_mfma_f32_16x16x32_bf16(vf, pf, accO[mt], 0,0,0);
      }
    }
  }
  if (qg < cb){
    float inv = 1.f/l_run;
    size_t ro = ((size_t)(vb*S_TOT) + qg)*512 + h*64;
    #pragma unroll
    for (int mt=0;mt<4;mt++){
      float v0 = accO[mt][0]*inv, v1 = accO[mt][1]*inv;
      float v2 = accO[mt][2]*inv, v3 = accO[mt][3]*inv;
      unsigned short h0=f2bf(v0), h1=f2bf(v1), h2=f2bf(v2), h3=f2bf(v3);
      uint2 hw; hw.x = pk2(h0,h1); hw.y = pk2(h2,h3);
      uint2 lw;
      lw.x = pk2(f2bf(v0-bfval(h0)), f2bf(v1-bfval(h1)));
      lw.y = pk2(f2bf(v2-bfval(h2)), f2bf(v3-bfval(h3)));
      *(uint2*)&Oh[ro + mt*16 + l4*4] = hw;
      *(uint2*)&Ol[ro + mt*16 + l4*4] = lw;
    }
  }
}

// ---------------------------------------------------------------------------
// q0[vb][n] = bq[n] + dot(Wq_row_n, a1[vb,row0]); wave-per-neuron, fp32 exact.
// ---------------------------------------------------------------------------
__global__ __launch_bounds__(256) void row0_q_kernel(
    const unsigned short* __restrict__ Ah, const unsigned short* __restrict__ Al,
    const float* __restrict__ Wq, const float* __restrict__ bq,
    float* __restrict__ q0) {
  int vb = blockIdx.y;
  int n = blockIdx.x*4 + (threadIdx.x >> 6);
  int lane = threadIdx.x & 63;
  __shared__ float xs[512];
  size_t ro = (size_t)(vb*S_TOT)*512;
  for (int i=threadIdx.x; i<512; i+=256)
    xs[i] = bfval(Ah[ro+i]) + bfval(Al[ro+i]);
  __syncthreads();
  const float* wr = Wq + (size_t)n*512;
  float acc = 0.f;
  #pragma unroll
  for (int k=lane*4; k<512; k+=256){
    float4 u = *(const float4*)(wr + k);
    acc += xs[k]*u.x + xs[k+1]*u.y + xs[k+2]*u.z + xs[k+3]*u.w;
  }
  #pragma unroll
  for (int o=32;o;o>>=1) acc += __shfl_down(acc, o);
  if (lane==0) q0[vb*512 + n] = acc + bq[n];
}

// ---------------------------------------------------------------------------
// Split-K row-0 attention, phase 1: block (h, vb, chunk).
// ---------------------------------------------------------------------------
__global__ __launch_bounds__(256) void attn_row0_part_kernel(
    const unsigned short* __restrict__ kv, const float* __restrict__ q0,
    const int* __restrict__ cnt,
    float* __restrict__ partM, float* __restrict__ partL,
    float* __restrict__ partN) {
  int h = blockIdx.x, vb = blockIdx.y, c = blockIdx.z;
  int cb = cnt[vb];
  int chunk = (cb + NCHUNK-1)/NCHUNK;
  int j0 = c*chunk;
  int j1 = j0+chunk; if (j1 > cb) j1 = cb;
  int t = threadIdx.x;
  int pidx = (vb*NH + h)*NCHUNK + c;
  __shared__ float qs[64];
  __shared__ float sc[144];     // chunk <= ceil(2049/16) = 129
  __shared__ float red[8];
  __shared__ float redO[4][64];
  if (t < 64) qs[t] = q0[vb*512 + h*64 + t]*0.125f;
  __syncthreads();
  if (j0 >= cb){
    if (t == 0){ partM[pidx] = -1e30f; partL[pidx] = 0.f; }
    if (t < 64) partN[(size_t)pidx*64 + t] = 0.f;
    return;
  }
  const unsigned short* base = kv + (size_t)vb*S_TOT*1024;
  int len = j1 - j0;
  float lmax = -1e30f;
  for (int jj=t; jj<len; jj+=256){
    const unsigned short* kp = base + (size_t)(j0+jj)*1024 + h*64;
    float s = 0.f;
    #pragma unroll
    for (int d8=0; d8<8; d8++){
      uint4 a = *(const uint4*)(kp + d8*8);
      unsigned int au[4] = {a.x,a.y,a.z,a.w};
      #pragma unroll
      for (int q2=0; q2<4; q2++){
        s += qs[d8*8+q2*2]*bfval(ext16(au[q2],0))
           + qs[d8*8+q2*2+1]*bfval(ext16(au[q2],1));
      }
    }
    sc[jj] = s;
    lmax = fmaxf(lmax, s);
  }
  #pragma unroll
  for (int o=32;o;o>>=1) lmax = fmaxf(lmax, __shfl_down(lmax,o));
  if ((t&63)==0) red[t>>6] = lmax;
  __syncthreads();
  float m = fmaxf(fmaxf(red[0],red[1]),fmaxf(red[2],red[3]));
  float lsum = 0.f;
  for (int jj=t; jj<len; jj+=256){
    float p = __expf(sc[jj]-m);
    sc[jj] = p; lsum += p;
  }
  #pragma unroll
  for (int o=32;o;o>>=1) lsum += __shfl_down(lsum,o);
  __syncthreads();
  if ((t&63)==0) red[t>>6] = lsum;
  __syncthreads();
  float l = red[0]+red[1]+red[2]+red[3];
  int d = t & 63, rr = t >> 6;
  float acc = 0.f;
  for (int jj=rr; jj<len; jj+=4)
    acc += sc[jj]*bfval(base[(size_t)(j0+jj)*1024 + 512 + h*64 + d]);
  redO[rr][d] = acc;
  __syncthreads();
  if (t < 64){
    partN[(size_t)pidx*64 + t] = redO[0][t]+redO[1][t]+redO[2][t]+redO[3][t];
    if (t==0){ partM[pidx] = m; partL[pidx] = l; }
  }
}

// phase 2: combine partials. block (h, vb), 64 threads (d).
__global__ __launch_bounds__(64) void attn_row0_combine_kernel(
    const float* __restrict__ partM, const float* __restrict__ partL,
    const float* __restrict__ partN, float* __restrict__ out0) {
  int h = blockIdx.x, vb = blockIdx.y;
  int t = threadIdx.x;
  int pb = (vb*NH + h)*NCHUNK;
  float m = -1e30f;
  #pragma unroll
  for (int c=0;c<NCHUNK;c++) m = fmaxf(m, partM[pb+c]);
  float lsum = 0.f, nsum = 0.f;
  #pragma unroll
  for (int c=0;c<NCHUNK;c++){
    float w = __expf(partM[pb+c]-m);
    lsum += w*partL[pb+c];
    nsum += w*partN[(size_t)(pb+c)*64 + t];
  }
  out0[vb*512 + h*64 + t] = nsum/lsum;
}

// layer-1 out-proj for row 0 + residual(z row0) + LN -> cls embedding slot.
// grid = VB; vb -> clsb[b][branch].
__global__ __launch_bounds__(256) void row0_proj_ln_kernel(
    const float* __restrict__ attn0, const float* __restrict__ Wo, const float* __restrict__ bo,
    const unsigned short* __restrict__ Zh, const unsigned short* __restrict__ Zl,
    const float* __restrict__ g, const float* __restrict__ be,
    float* __restrict__ clsbuf) {
  int vb = blockIdx.x, t = threadIdx.x;
  int b = vb & 3, branch = vb >> 2;
  __shared__ float xin[512];
  __shared__ float y[512];
  __shared__ float red[16];
  for (int i=t;i<512;i+=256) xin[i] = attn0[vb*512+i];
  __syncthreads();
  size_t z0 = (size_t)vb*S_TOT*512;
  for (int n=t;n<512;n+=256){
    const float4* wr = (const float4*)(Wo + (size_t)n*512);
    float acc = bo[n];
    for (int k4=0;k4<128;k4++){
      float4 u = wr[k4]; int k=k4*4;
      acc += xin[k+0]*u.x + xin[k+1]*u.y + xin[k+2]*u.z + xin[k+3]*u.w;
    }
    y[n] = acc + bfval(Zh[z0+n]) + bfval(Zl[z0+n]);
  }
  __syncthreads();
  float s1=0.f, s2=0.f;
  for (int i=t;i<512;i+=256){ float a=y[i]; s1+=a; s2+=a*a; }
  #pragma unroll
  for (int o=32;o;o>>=1){ s1+=__shfl_down(s1,o); s2+=__shfl_down(s2,o); }
  if ((t&63)==0){ red[t>>6]=s1; red[8+(t>>6)]=s2; }
  __syncthreads();
  s1 = red[0]+red[1]+red[2]+red[3];
  s2 = red[8]+red[9]+red[10]+red[11];
  float mean = s1*(1.f/512.f);
  float var  = s2*(1.f/512.f) - mean*mean;
  float rn = rsqrtf(var + 1e-5f);
  for (int i=t;i<512;i+=256)
    clsbuf[b*1024 + branch*512 + i] = (y[i]-mean)*rn*g[i] + be[i];
}

// ---------------------------------------------------------------------------
// Final MLP layer (wave-per-neuron GEMV).
// ---------------------------------------------------------------------------
__global__ __launch_bounds__(256) void fm_layer_kernel(
    const float* __restrict__ in, const float* __restrict__ W,
    const float* __restrict__ bias, float* __restrict__ out,
    int K, int N, int act) {
  int b = blockIdx.y;
  int n = blockIdx.x*4 + (threadIdx.x >> 6);
  int lane = threadIdx.x & 63;
  __shared__ float xs[1024];
  for (int i=threadIdx.x; i<K; i+=256) xs[i] = in[(size_t)b*K + i];
  __syncthreads();
  const float* wr = W + (size_t)n*K;
  float acc = 0.f;
  #pragma unroll 4
  for (int k=lane*4; k<K; k+=256){
    float4 u = *(const float4*)(wr + k);
    acc += xs[k]*u.x + xs[k+1]*u.y + xs[k+2]*u.z + xs[k+3]*u.w;
  }
  #pragma unroll
  for (int o=32;o;o>>=1) acc += __shfl_down(acc, o);
  if (lane==0){
    float v = acc + bias[n];
    if (act) v = gelu_exact(v);
    out[(size_t)b*N + n] = v;
  }
}

// ---------------------------------------------------------------------------
extern "C" void kernel_launch(void* const* d_in, const int* in_sizes, int n_in,
                              void* d_out, int out_size, void* d_ws, size_t ws_size,
                              hipStream_t stream) {
  const float* x      = (const float*)d_in[0];
  const float* cls_tk = (const float*)d_in[1];
  const float* ln_g   = (const float*)d_in[2];
  const float* ln_b   = (const float*)d_in[3];
  const float* aw_W0  = (const float*)d_in[4];  const float* aw_b0 = (const float*)d_in[5];
  const float* aw_W1  = (const float*)d_in[6];  const float* aw_b1 = (const float*)d_in[7];
  const float* aw_W2  = (const float*)d_in[8];  const float* aw_b2 = (const float*)d_in[9];
  const float* pr_W0  = (const float*)d_in[10]; const float* pr_b0 = (const float*)d_in[11];
  const float* pr_W1  = (const float*)d_in[12]; const float* pr_b1 = (const float*)d_in[13];
  const float* pr_W2  = (const float*)d_in[14]; const float* pr_b2 = (const float*)d_in[15];
  const float* mWqkv[2] = {(const float*)d_in[16], (const float*)d_in[20]};
  const float* mbqkv[2] = {(const float*)d_in[17], (const float*)d_in[21]};
  const float* mWo[2]   = {(const float*)d_in[18], (const float*)d_in[22]};
  const float* mbo[2]   = {(const float*)d_in[19], (const float*)d_in[23]};

  float* ws = (float*)d_ws;
  size_t off = 0;
  float* weight = ws + off; off += 8192;                      // [B,N]
  int*   idx    = (int*)(ws + off); off += VROWS + 8;         // [VB,S]
  int*   cnt    = (int*)(ws + off); off += 16;                // [VB]
  float* W0T    = ws + off; off += 32768;                     // [512][64]
  const size_t HBUF = (size_t)VROWS*512/2;                    // bf16 array in float units
  unsigned short* Zh = (unsigned short*)(ws + off); off += HBUF;
  unsigned short* Zl = (unsigned short*)(ws + off); off += HBUF;
  float* QKVr   = ws + off; off += (size_t)VROWS*1536/2;      // shared region (bf16-sized):
  unsigned short* QKVb = (unsigned short*)QKVr;               //  layer-0 QKV bf16 (stride 1536)
  float* T2     = QKVr;                                       //  out-proj fp32 (stride 512, 2/3 of region)
  unsigned short* KVb  = (unsigned short*)QKVr;               //  layer-1 KV bf16 (stride 1024, 2/3)
  unsigned short* Oh = (unsigned short*)(ws + off); off += HBUF;  // also a1 hi
  unsigned short* Ol = (unsigned short*)(ws + off); off += HBUF;  // also a1 lo
  unsigned short* Wq0h = (unsigned short*)(ws + off); off += 393216;
  unsigned short* Wq0l = (unsigned short*)(ws + off); off += 393216;
  unsigned short* Wq1h = (unsigned short*)(ws + off); off += 393216;
  unsigned short* Wq1l = (unsigned short*)(ws + off); off += 393216;
  unsigned short* Wo0h = (unsigned short*)(ws + off); off += 131072;
  unsigned short* Wo0l = (unsigned short*)(ws + off); off += 131072;
  float* attn0  = ws + off; off += VB*512;                    // [VB,D]
  float* q0buf  = ws + off; off += VB*512;                    // [VB,D]
  float* clsb   = ws + off; off += 4096;                      // [B,2D]
  float* h1buf  = ws + off; off += 2048;                      // [B,D]
  float* h2buf  = ws + off; off += 2048;                      // [B,D]
  float* partM  = ws + off; off += VB*NH*NCHUNK;              // 1024
  float* partL  = ws + off; off += VB*NH*NCHUNK;              // 1024
  float* partN  = ws + off; off += (size_t)VB*NH*NCHUNK*64;   // 65536
  (void)ws_size; (void)in_sizes; (void)n_in; (void)out_size;

  transpose_w0_kernel<<<(32768+255)/256, 256, 0, stream>>>(aw_W0, W0T);
  aw_weight_kernel<<<B_SZ*N_INST, 64, 0, stream>>>(
      x, W0T, aw_b0, aw_W1, aw_b1, aw_W2, aw_b2, weight);

  split_kernel<<<(786432+255)/256, 256, 0, stream>>>(mWqkv[0], Wq0h, Wq0l, 786432);
  split_kernel<<<(786432+255)/256, 256, 0, stream>>>(mWqkv[1], Wq1h, Wq1l, 786432);
  split_kernel<<<(262144+255)/256, 256, 0, stream>>>(mWo[0],  Wo0h, Wo0l, 262144);

  const int MT = (VROWS + 63)/64;   // 257 row tiles
  // both branches batched as vb = branch*4 + b
  compact_kernel<<<VB, 256, 0, stream>>>(weight, idx, cnt);
  build_z_kernel<<<VROWS, 256, 0, stream>>>(x, weight, cls_tk, ln_g, ln_b, idx, cnt, Zh, Zl);
  // layer 0
  mfma_gemm_kernel<<<dim3(1536/64, MT), 256, 0, stream>>>(
      Zh, Zl, Wq0h, Wq0l, mbqkv[0], QKVb, VROWS, 1536, cnt, 1);
  flash_attn_kernel<<<dim3((S_TOT+63)/64, NH, VB), 256, 0, stream>>>(QKVb, cnt, Oh, Ol);
  mfma_gemm_kernel<<<dim3(512/64, MT), 256, 0, stream>>>(
      Oh, Ol, Wo0h, Wo0l, mbo[0], T2, VROWS, 512, cnt, 0);
  add_ln_kernel<<<VROWS, 256, 0, stream>>>(Zh, Zl, T2, ln_g, ln_b, cnt, Oh, Ol); // a1 -> Oh/Ol
  // layer 1: row0 Q via fp32 GEMV; KV for all rows, bf16 (stride 1024)
  row0_q_kernel<<<dim3(128, VB), 256, 0, stream>>>(Oh, Ol, mWqkv[1], mbqkv[1], q0buf);
  mfma_gemm_kernel<<<dim3(1024/64, MT), 256, 0, stream>>>(
      Oh, Ol, Wq1h + (size_t)512*512, Wq1l + (size_t)512*512,
      mbqkv[1] + 512, KVb, VROWS, 1024, cnt, 1);
  attn_row0_part_kernel<<<dim3(NH, VB, NCHUNK), 256, 0, stream>>>(
      KVb, q0buf, cnt, partM, partL, partN);
  attn_row0_combine_kernel<<<dim3(NH, VB), 64, 0, stream>>>(
      partM, partL, partN, attn0);
  row0_proj_ln_kernel<<<VB, 256, 0, stream>>>(
      attn0, mWo[1], mbo[1], Zh, Zl, ln_g, ln_b, clsb);
  // final MLP: 3 wave-per-neuron GEMV layers
  fm_layer_kernel<<<dim3(128, B_SZ), 256, 0, stream>>>(clsb,  pr_W0, pr_b0, h1buf, 1024, 512, 1);
  fm_layer_kernel<<<dim3(128, B_SZ), 256, 0, stream>>>(h1buf, pr_W1, pr_b1, h2buf,  512, 512, 1);
  fm_layer_kernel<<<dim3(128, B_SZ), 256, 0, stream>>>(h2buf, pr_W2, pr_b2, (float*)d_out, 512, 512, 0);
}

// Round 12
// 467.052 us; speedup vs baseline: 8.5037x; 1.0414x over previous
//
#include <hip/hip_runtime.h>
#include <hip/hip_bf16.h>

#define B_SZ 4
#define N_INST 2048
#define D_MODEL 512
#define S_TOT 2049          // N+1 (cls prepended)
#define NH 8
#define HD 64
#define VB 8                // virtual batches = 2 branches x 4 batch
#define VROWS (VB*S_TOT)    // 16392
#define NCHUNK 16           // split-K chunks for row-0 attention

typedef __attribute__((ext_vector_type(4))) float f32x4;
typedef __attribute__((ext_vector_type(8))) short bf16x8;

__device__ __forceinline__ float gelu_exact(float x){ return 0.5f*x*(1.f+erff(x*0.70710678118654752f)); }
__device__ __forceinline__ unsigned short f2bf(float x){
  unsigned int u = __float_as_uint(x);
  u += 0x7fffu + ((u>>16)&1u);
  return (unsigned short)(u>>16);
}
__device__ __forceinline__ float bfval(unsigned short u){ return __uint_as_float(((unsigned int)u)<<16); }
__device__ __forceinline__ unsigned int pk2(unsigned short lo, unsigned short hi){
  return (unsigned int)lo | ((unsigned int)hi << 16);
}
__device__ __forceinline__ unsigned short ext16(unsigned int u, int hi){
  return (unsigned short)(hi ? (u>>16) : (u & 0xffffu));
}

#define GLOAD16(gp, lp) __builtin_amdgcn_global_load_lds( \
    (const __attribute__((address_space(1))) void*)(gp), \
    (__attribute__((address_space(3))) void*)(lp), 16, 0, 0)

// ---------------------------------------------------------------------------
// One-time transpose: W0T[k][h] = W0[h][k]   (64x512 -> 512x64, fp32)
// ---------------------------------------------------------------------------
__global__ __launch_bounds__(256) void transpose_w0_kernel(
    const float* __restrict__ W0, float* __restrict__ W0T) {
  int i = blockIdx.x*256 + threadIdx.x;
  if (i < 64*512){
    int h = i >> 9, k = i & 511;
    W0T[k*64 + h] = W0[i];
  }
}

// ---------------------------------------------------------------------------
// Gating MLP (fp32: the w<0.5 mask is a threshold — bf16 risks branch flips).
// ---------------------------------------------------------------------------
__global__ __launch_bounds__(64) void aw_weight_kernel(
    const float* __restrict__ x,
    const float* __restrict__ W0T, const float* __restrict__ b0,
    const float* __restrict__ W1, const float* __restrict__ b1,
    const float* __restrict__ W2, const float* __restrict__ b2,
    float* __restrict__ weight) {
  int inst = blockIdx.x;
  int h = threadIdx.x;
  __shared__ float xs[512];
  __shared__ float hs[64];
  const float* xp = x + (size_t)inst*D_MODEL;
  for (int i=h;i<512;i+=64) xs[i] = xp[i];
  __syncthreads();
  float acc = b0[h];
  const float* w0c = W0T + h;
  #pragma unroll 16
  for (int k=0;k<512;k++)
    acc = fmaf(xs[k], w0c[k*64], acc);
  hs[h] = gelu_exact(acc);
  __syncthreads();
  const float4* w1 = (const float4*)(W1 + (size_t)h*64);
  float acc2 = b1[h];
  #pragma unroll
  for (int k4=0;k4<16;k4++){
    float4 u = w1[k4]; int k = k4*4;
    acc2 += hs[k+0]*u.x + hs[k+1]*u.y + hs[k+2]*u.z + hs[k+3]*u.w;
  }
  float h2 = gelu_exact(acc2);
  float p = h2 * W2[h];
  #pragma unroll
  for (int o=32;o;o>>=1) p += __shfl_down(p, o);
  if (h==0){
    float s = p + b2[0];
    weight[inst] = 1.f/(1.f+expf(-s));
  }
}

// ---------------------------------------------------------------------------
// Split fp32 -> (hi, lo) bf16 pair.
// ---------------------------------------------------------------------------
__global__ __launch_bounds__(256) void split_kernel(
    const float* __restrict__ w, unsigned short* __restrict__ hi,
    unsigned short* __restrict__ lo, int n) {
  int i = blockIdx.x*256 + threadIdx.x;
  if (i < n){
    float v = w[i];
    unsigned short h = f2bf(v);
    hi[i] = h;
    lo[i] = f2bf(v - bfval(h));
  }
}

// ---------------------------------------------------------------------------
// Compaction per virtual batch vb = branch*4 + b (slot0 = cls).
// ---------------------------------------------------------------------------
__global__ __launch_bounds__(256) void compact_kernel(
    const float* __restrict__ weight,
    int* __restrict__ idx, int* __restrict__ cnt) {
  int vb = blockIdx.x;
  int b = vb & 3, branch = vb >> 2;
  int t = threadIdx.x;
  int lane = t & 63, wv = t >> 6;
  __shared__ int wsum[4];
  __shared__ int base_s;
  if (t==0){ idx[vb*S_TOT] = 0; base_s = 1; }
  __syncthreads();
  for (int c0=0; c0<N_INST; c0+=256){
    int n = c0 + t;
    float w = weight[b*N_INST + n];
    bool neg = (w < 0.5f);
    bool val = (branch==0) ? neg : !neg;
    unsigned long long m = __ballot(val);
    int prefix = __popcll(m & ((1ull<<lane)-1ull));
    if (lane==0) wsum[wv] = __popcll(m);
    __syncthreads();
    int wbase = 0;
    #pragma unroll
    for (int i=0;i<4;i++) if (i<wv) wbase += wsum[i];
    int total = wsum[0]+wsum[1]+wsum[2]+wsum[3];
    int mybase = base_s;
    if (val) idx[vb*S_TOT + mybase + wbase + prefix] = n + 1;
    __syncthreads();
    if (t==0) base_s += total;
    __syncthreads();
  }
  if (t==0) cnt[vb] = base_s;
}

// ---------------------------------------------------------------------------
// Build compacted z = LN(scale*seq[idx]) -> hi/lo bf16 pair. grid = VROWS.
// ---------------------------------------------------------------------------
__global__ __launch_bounds__(256) void build_z_kernel(
    const float* __restrict__ x, const float* __restrict__ weight,
    const float* __restrict__ cls, const float* __restrict__ g, const float* __restrict__ be,
    const int* __restrict__ idx, const int* __restrict__ cnt,
    unsigned short* __restrict__ Zh, unsigned short* __restrict__ Zl) {
  int row = blockIdx.x;
  int vb = row / S_TOT, slot = row % S_TOT;
  if (slot >= cnt[vb]) return;
  int b = vb & 3, branch = vb >> 2;
  int t = threadIdx.x;
  __shared__ float v[512];
  __shared__ float red[16];
  int pos = idx[vb*S_TOT + slot];
  float scale = 1.f;
  const float* src = cls;
  if (pos != 0){
    float w = weight[b*N_INST + (pos-1)];
    scale = (branch==0) ? powf(w, 1.5f) : powf(w, 2.0f/3.0f);
    src = x + ((size_t)b*N_INST + (pos-1))*D_MODEL;
  }
  float s1=0.f, s2=0.f;
  for (int i=t;i<512;i+=256){
    float val = src[i];
    if (pos != 0) val *= scale;
    v[i]=val; s1+=val; s2+=val*val;
  }
  __syncthreads();
  #pragma unroll
  for (int o=32;o;o>>=1){ s1+=__shfl_down(s1,o); s2+=__shfl_down(s2,o); }
  if ((t&63)==0){ red[t>>6]=s1; red[8+(t>>6)]=s2; }
  __syncthreads();
  s1 = red[0]+red[1]+red[2]+red[3];
  s2 = red[8]+red[9]+red[10]+red[11];
  float mean = s1 * (1.f/512.f);
  float var  = s2 * (1.f/512.f) - mean*mean;
  float rn = rsqrtf(var + 1e-5f);
  size_t ro = (size_t)row*512;
  for (int i=t;i<512;i+=256){
    float o = (v[i]-mean)*rn*g[i] + be[i];
    unsigned short hbits = f2bf(o);
    Zh[ro+i] = hbits;
    Zl[ro+i] = f2bf(o - bfval(hbits));
  }
}

// out = LN((Zh+Zl) + T2) rowwise -> hi/lo bf16 pair (the a1 operand)
__global__ __launch_bounds__(256) void add_ln_kernel(
    const unsigned short* __restrict__ Zh, const unsigned short* __restrict__ Zl,
    const float* __restrict__ T2,
    const float* __restrict__ g, const float* __restrict__ be,
    const int* __restrict__ cnt,
    unsigned short* __restrict__ Ah, unsigned short* __restrict__ Al) {
  int row = blockIdx.x;
  if ((row % S_TOT) >= cnt[row / S_TOT]) return;
  int t = threadIdx.x;
  __shared__ float v[512];
  __shared__ float red[16];
  size_t ro = (size_t)row*512;
  float s1=0.f, s2=0.f;
  for (int i=t;i<512;i+=256){
    float val = bfval(Zh[ro+i]) + bfval(Zl[ro+i]) + T2[ro+i];
    v[i]=val; s1+=val; s2+=val*val;
  }
  __syncthreads();
  #pragma unroll
  for (int o=32;o;o>>=1){ s1+=__shfl_down(s1,o); s2+=__shfl_down(s2,o); }
  if ((t&63)==0){ red[t>>6]=s1; red[8+(t>>6)]=s2; }
  __syncthreads();
  s1 = red[0]+red[1]+red[2]+red[3];
  s2 = red[8]+red[9]+red[10]+red[11];
  float mean = s1 * (1.f/512.f);
  float var  = s2 * (1.f/512.f) - mean*mean;
  float rn = rsqrtf(var + 1e-5f);
  for (int i=t;i<512;i+=256){
    float o = (v[i]-mean)*rn*g[i] + be[i];
    unsigned short hbits = f2bf(o);
    Ah[ro+i] = hbits;
    Al[ro+i] = f2bf(o - bfval(hbits));
  }
}

// ---------------------------------------------------------------------------
// MFMA GEMM (bf16 hi/lo 3-pass): C[M,N] = (Ah+Al)[M,512] @ (Wh+Wl)[N,512]^T + bias.
// obf16=1 -> write bf16 (ushort, stride N); else fp32.
// ---------------------------------------------------------------------------
__global__ __launch_bounds__(256) void mfma_gemm_kernel(
    const unsigned short* __restrict__ Ahg, const unsigned short* __restrict__ Alg,
    const unsigned short* __restrict__ Whg, const unsigned short* __restrict__ Wlg,
    const float* __restrict__ bias, void* __restrict__ Cout,
    int M, int N, const int* __restrict__ cnt, int obf16) {
  int t = threadIdx.x;
  int bm = blockIdx.y*64, bn = blockIdx.x*64;
  {
    int r = bm + (t>>2);
    bool ok = (r < M) && ((r % S_TOT) < cnt[r / S_TOT]);
    if (__syncthreads_or(ok ? 1 : 0) == 0) return;
  }
  __shared__ unsigned short Ahs[64*64], Als[64*64], Whs[64*64], Wls[64*64];
  int lane = t & 63, w = t >> 6;
  int l15 = lane & 15, l4 = lane >> 4;

  const unsigned short* src;
  unsigned short* dst;
  if      (w == 0){ src = Ahg; dst = Ahs; }
  else if (w == 1){ src = Alg; dst = Als; }
  else if (w == 2){ src = Whg; dst = Whs; }
  else            { src = Wlg; dst = Wls; }
  int tb  = (w < 2) ? bm : bn;
  int lim = (w < 2) ? M  : N;
  int lrow = lane >> 3;
  int lg   = lane & 7;
  const unsigned short* gp[8];
  #pragma unroll
  for (int i=0;i<8;i++){
    int row_l = i*8 + lrow;
    int rg = tb + row_l; if (rg >= lim) rg = lim-1;
    gp[i] = src + (size_t)rg*512 + (size_t)((lg ^ (row_l&7))*8);
  }

  f32x4 acc[4];
  #pragma unroll
  for (int mt=0;mt<4;mt++) acc[mt] = (f32x4){0.f,0.f,0.f,0.f};

  for (int ch=0; ch<8; ch++){
    __syncthreads();
    #pragma unroll
    for (int i=0;i<8;i++)
      GLOAD16(gp[i] + ch*64, dst + i*512);
    __syncthreads();
    #pragma unroll
    for (int ks=0; ks<2; ks++){
      int wrow = w*16 + l15;
      int wgs = (ks*4 + l4) ^ (wrow & 7);
      bf16x8 wh = *(const bf16x8*)&Whs[wrow*64 + wgs*8];
      bf16x8 wl = *(const bf16x8*)&Wls[wrow*64 + wgs*8];
      #pragma unroll
      for (int mt=0;mt<4;mt++){
        int arow = mt*16 + l15;
        int ags = (ks*4 + l4) ^ (arow & 7);
        bf16x8 ah = *(const bf16x8*)&Ahs[arow*64 + ags*8];
        bf16x8 al = *(const bf16x8*)&Als[arow*64 + ags*8];
        acc[mt] = __builtin_amdgcn_mfma_f32_16x16x32_bf16(ah, wh, acc[mt], 0,0,0);
        acc[mt] = __builtin_amdgcn_mfma_f32_16x16x32_bf16(ah, wl, acc[mt], 0,0,0);
        acc[mt] = __builtin_amdgcn_mfma_f32_16x16x32_bf16(al, wh, acc[mt], 0,0,0);
      }
    }
  }
  int ncol = bn + w*16 + l15;
  float bv = bias[ncol];
  #pragma unroll
  for (int mt=0;mt<4;mt++){
    #pragma unroll
    for (int r=0;r<4;r++){
      int mrow = bm + mt*16 + l4*4 + r;
      bool ok = (mrow < M) && ((mrow % S_TOT) < cnt[mrow / S_TOT]);
      if (ok){
        float v = acc[mt][r] + bv;
        if (obf16) ((unsigned short*)Cout)[(size_t)mrow*N + ncol] = f2bf(v);
        else       ((float*)Cout)[(size_t)mrow*N + ncol] = v;
      }
    }
  }
}

// ---------------------------------------------------------------------------
// MFMA flash attention (layer 0), bf16 QKV (stride 1536), vb = blockIdx.z.
// 128 queries/block: each wave owns 32 queries as two 16-query fragments
// processed sequentially against the staged K/V tile (halves K/V traffic
// vs the 64-query tile; per-query math identical).
// ---------------------------------------------------------------------------
__global__ __launch_bounds__(256) void flash_attn_kernel(
    const unsigned short* __restrict__ qkv, const int* __restrict__ cnt,
    unsigned short* __restrict__ Oh, unsigned short* __restrict__ Ol) {
  int vb = blockIdx.z, h = blockIdx.y;
  int cb = cnt[vb];
  int S0 = blockIdx.x * 128;
  if (S0 >= cb) return;
  int t = threadIdx.x;
  int lane = t & 63, w = t >> 6;
  int l15 = lane & 15, l4 = lane >> 4;

  __shared__ unsigned short Kbf[64*64];
  __shared__ unsigned short Vt[64*64];
  __shared__ unsigned short Pbuf[4][16*64];

  const unsigned short* basep = qkv + (size_t)(vb*S_TOT)*1536;

  int qg[2];
  bf16x8 Qf[2][2];
  #pragma unroll
  for (int qf=0; qf<2; qf++){
    qg[qf] = S0 + w*32 + qf*16 + l15;
    int qr = (qg[qf] < cb) ? qg[qf] : 0;
    const unsigned short* qp = basep + (size_t)qr*1536 + h*64;
    Qf[qf][0] = *(const bf16x8*)(qp + l4*8);
    Qf[qf][1] = *(const bf16x8*)(qp + 32 + l4*8);
  }

  float m_run[2] = {-1e30f, -1e30f}, l_run[2] = {0.f, 0.f};
  f32x4 accO[2][4];
  #pragma unroll
  for (int qf=0;qf<2;qf++)
    #pragma unroll
    for (int mt=0;mt<4;mt++) accO[qf][mt] = (f32x4){0.f,0.f,0.f,0.f};

  unsigned int* Ku = (unsigned int*)Kbf;
  unsigned int* Vu = (unsigned int*)Vt;
  const int nt = (cb + 63)/64;
  for (int kt=0; kt<nt; kt++){
    int K0 = kt*64;
    __syncthreads();
    {   // stage K rows -> Kbf[key][d]
      int key = t>>2;
      int keyr = (K0+key < cb) ? (K0+key) : 0;
      const unsigned short* kp = basep + (size_t)keyr*1536 + 512 + h*64 + (t&3)*16;
      uint4 a  = *(const uint4*)(kp);
      uint4 b2 = *(const uint4*)(kp+8);
      int g0 = (t&3)*2;
      int gs0 = g0 ^ (key&7), gs1 = (g0+1) ^ (key&7);
      *(uint4*)(Ku + key*32 + gs0*4) = a;
      *(uint4*)(Ku + key*32 + gs1*4) = b2;
    }
    {   // stage V transposed -> Vt[d][key]
      int kp2 = t & 31;
      int d8 = t >> 5;
      int k0g = K0 + 2*kp2;
      int kr0 = (k0g   < cb) ? k0g   : 0;
      int kr1 = (k0g+1 < cb) ? k0g+1 : 0;
      const unsigned short* vp0 = basep + (size_t)kr0*1536 + 1024 + h*64 + d8*8;
      const unsigned short* vp1 = basep + (size_t)kr1*1536 + 1024 + h*64 + d8*8;
      uint4 a = *(const uint4*)(vp0);
      uint4 c = *(const uint4*)(vp1);
      unsigned int au[4] = {a.x,a.y,a.z,a.w};
      unsigned int cu[4] = {c.x,c.y,c.z,c.w};
      int k8 = kp2 >> 2;
      #pragma unroll
      for (int dd=0; dd<8; dd++){
        int d = d8*8 + dd;
        Vu[d*32 + (k8 ^ (d&7))*4 + (kp2&3)] =
            pk2(ext16(au[dd>>1], dd&1), ext16(cu[dd>>1], dd&1));
      }
    }
    __syncthreads();

    #pragma unroll
    for (int qf=0; qf<2; qf++){
      f32x4 acc[4];
      #pragma unroll
      for (int mt=0;mt<4;mt++) acc[mt] = (f32x4){0.f,0.f,0.f,0.f};
      #pragma unroll
      for (int mt=0;mt<4;mt++){
        int row = mt*16 + l15;
        #pragma unroll
        for (int c=0;c<2;c++){
          int gs = (c*4 + l4) ^ (row & 7);
          bf16x8 kf = *(const bf16x8*)&Kbf[row*64 + gs*8];
          acc[mt] = __builtin_amdgcn_mfma_f32_16x16x32_bf16(kf, Qf[qf][c], acc[mt], 0,0,0);
        }
      }
      float p[4][4];
      float tmax = -1e30f;
      #pragma unroll
      for (int mt=0;mt<4;mt++)
        #pragma unroll
        for (int r=0;r<4;r++){
          int key = K0 + mt*16 + l4*4 + r;
          float s = (key < cb) ? acc[mt][r]*0.125f : -1e30f;
          p[mt][r] = s;
          tmax = fmaxf(tmax, s);
        }
      tmax = fmaxf(tmax, __shfl_xor(tmax, 16));
      tmax = fmaxf(tmax, __shfl_xor(tmax, 32));
      float m_new = fmaxf(m_run[qf], tmax);
      float alpha = __expf(m_run[qf] - m_new);
      float psum = 0.f;
      #pragma unroll
      for (int mt=0;mt<4;mt++)
        #pragma unroll
        for (int r=0;r<4;r++){
          float pv = __expf(p[mt][r] - m_new);
          p[mt][r] = pv; psum += pv;
        }
      psum += __shfl_xor(psum, 16);
      psum += __shfl_xor(psum, 32);
      l_run[qf] = l_run[qf]*alpha + psum;
      m_run[qf] = m_new;

      #pragma unroll
      for (int mt=0;mt<4;mt++){
        int keyl = mt*16 + l4*4;
        int gs = (keyl >> 3) ^ (l15 & 7);
        uint2 w2;
        w2.x = pk2(f2bf(p[mt][0]), f2bf(p[mt][1]));
        w2.y = pk2(f2bf(p[mt][2]), f2bf(p[mt][3]));
        *(uint2*)&Pbuf[w][ l15*64 + gs*8 + (keyl & 7) ] = w2;
      }
      #pragma unroll
      for (int mt=0;mt<4;mt++){
        accO[qf][mt][0]*=alpha; accO[qf][mt][1]*=alpha;
        accO[qf][mt][2]*=alpha; accO[qf][mt][3]*=alpha;
      }
      #pragma unroll
      for (int c2=0;c2<2;c2++){
        int gpv = (c2*4 + l4) ^ (l15 & 7);
        bf16x8 pf = *(const bf16x8*)&Pbuf[w][ l15*64 + gpv*8 ];
        #pragma unroll
        for (int mt=0;mt<4;mt++){
          int d = mt*16 + l15;
          int gv = (c2*4 + l4) ^ (d & 7);
          bf16x8 vf = *(const bf16x8*)&Vt[ d*64 + gv*8 ];
          accO[qf][mt] = __builtin_amdgcn_mfma_f32_16x16x32_bf16(vf, pf, accO[qf][mt], 0,0,0);
        }
      }
    }
  }
  #pragma unroll
  for (int qf=0; qf<2; qf++){
    if (qg[qf] < cb){
      float inv = 1.f/l_run[qf];
      size_t ro = ((size_t)(vb*S_TOT) + qg[qf])*512 + h*64;
      #pragma unroll
      for (int mt=0;mt<4;mt++){
        float v0 = accO[qf][mt][0]*inv, v1 = accO[qf][mt][1]*inv;
        float v2 = accO[qf][mt][2]*inv, v3 = accO[qf][mt][3]*inv;
        unsigned short h0=f2bf(v0), h1=f2bf(v1), h2=f2bf(v2), h3=f2bf(v3);
        uint2 hw; hw.x = pk2(h0,h1); hw.y = pk2(h2,h3);
        uint2 lw;
        lw.x = pk2(f2bf(v0-bfval(h0)), f2bf(v1-bfval(h1)));
        lw.y = pk2(f2bf(v2-bfval(h2)), f2bf(v3-bfval(h3)));
        *(uint2*)&Oh[ro + mt*16 + l4*4] = hw;
        *(uint2*)&Ol[ro + mt*16 + l4*4] = lw;
      }
    }
  }
}

// ---------------------------------------------------------------------------
// q0[vb][n] = bq[n] + dot(Wq_row_n, a1[vb,row0]); wave-per-neuron, fp32 exact.
// ---------------------------------------------------------------------------
__global__ __launch_bounds__(256) void row0_q_kernel(
    const unsigned short* __restrict__ Ah, const unsigned short* __restrict__ Al,
    const float* __restrict__ Wq, const float* __restrict__ bq,
    float* __restrict__ q0) {
  int vb = blockIdx.y;
  int n = blockIdx.x*4 + (threadIdx.x >> 6);
  int lane = threadIdx.x & 63;
  __shared__ float xs[512];
  size_t ro = (size_t)(vb*S_TOT)*512;
  for (int i=threadIdx.x; i<512; i+=256)
    xs[i] = bfval(Ah[ro+i]) + bfval(Al[ro+i]);
  __syncthreads();
  const float* wr = Wq + (size_t)n*512;
  float acc = 0.f;
  #pragma unroll
  for (int k=lane*4; k<512; k+=256){
    float4 u = *(const float4*)(wr + k);
    acc += xs[k]*u.x + xs[k+1]*u.y + xs[k+2]*u.z + xs[k+3]*u.w;
  }
  #pragma unroll
  for (int o=32;o;o>>=1) acc += __shfl_down(acc, o);
  if (lane==0) q0[vb*512 + n] = acc + bq[n];
}

// ---------------------------------------------------------------------------
// Split-K row-0 attention, phase 1: block (h, vb, chunk).
// ---------------------------------------------------------------------------
__global__ __launch_bounds__(256) void attn_row0_part_kernel(
    const unsigned short* __restrict__ kv, const float* __restrict__ q0,
    const int* __restrict__ cnt,
    float* __restrict__ partM, float* __restrict__ partL,
    float* __restrict__ partN) {
  int h = blockIdx.x, vb = blockIdx.y, c = blockIdx.z;
  int cb = cnt[vb];
  int chunk = (cb + NCHUNK-1)/NCHUNK;
  int j0 = c*chunk;
  int j1 = j0+chunk; if (j1 > cb) j1 = cb;
  int t = threadIdx.x;
  int pidx = (vb*NH + h)*NCHUNK + c;
  __shared__ float qs[64];
  __shared__ float sc[144];     // chunk <= ceil(2049/16) = 129
  __shared__ float red[8];
  __shared__ float redO[4][64];
  if (t < 64) qs[t] = q0[vb*512 + h*64 + t]*0.125f;
  __syncthreads();
  if (j0 >= cb){
    if (t == 0){ partM[pidx] = -1e30f; partL[pidx] = 0.f; }
    if (t < 64) partN[(size_t)pidx*64 + t] = 0.f;
    return;
  }
  const unsigned short* base = kv + (size_t)vb*S_TOT*1024;
  int len = j1 - j0;
  float lmax = -1e30f;
  for (int jj=t; jj<len; jj+=256){
    const unsigned short* kp = base + (size_t)(j0+jj)*1024 + h*64;
    float s = 0.f;
    #pragma unroll
    for (int d8=0; d8<8; d8++){
      uint4 a = *(const uint4*)(kp + d8*8);
      unsigned int au[4] = {a.x,a.y,a.z,a.w};
      #pragma unroll
      for (int q2=0; q2<4; q2++){
        s += qs[d8*8+q2*2]*bfval(ext16(au[q2],0))
           + qs[d8*8+q2*2+1]*bfval(ext16(au[q2],1));
      }
    }
    sc[jj] = s;
    lmax = fmaxf(lmax, s);
  }
  #pragma unroll
  for (int o=32;o;o>>=1) lmax = fmaxf(lmax, __shfl_down(lmax,o));
  if ((t&63)==0) red[t>>6] = lmax;
  __syncthreads();
  float m = fmaxf(fmaxf(red[0],red[1]),fmaxf(red[2],red[3]));
  float lsum = 0.f;
  for (int jj=t; jj<len; jj+=256){
    float p = __expf(sc[jj]-m);
    sc[jj] = p; lsum += p;
  }
  #pragma unroll
  for (int o=32;o;o>>=1) lsum += __shfl_down(lsum,o);
  __syncthreads();
  if ((t&63)==0) red[t>>6] = lsum;
  __syncthreads();
  float l = red[0]+red[1]+red[2]+red[3];
  int d = t & 63, rr = t >> 6;
  float acc = 0.f;
  for (int jj=rr; jj<len; jj+=4)
    acc += sc[jj]*bfval(base[(size_t)(j0+jj)*1024 + 512 + h*64 + d]);
  redO[rr][d] = acc;
  __syncthreads();
  if (t < 64){
    partN[(size_t)pidx*64 + t] = redO[0][t]+redO[1][t]+redO[2][t]+redO[3][t];
    if (t==0){ partM[pidx] = m; partL[pidx] = l; }
  }
}

// phase 2: combine partials. block (h, vb), 64 threads (d).
__global__ __launch_bounds__(64) void attn_row0_combine_kernel(
    const float* __restrict__ partM, const float* __restrict__ partL,
    const float* __restrict__ partN, float* __restrict__ out0) {
  int h = blockIdx.x, vb = blockIdx.y;
  int t = threadIdx.x;
  int pb = (vb*NH + h)*NCHUNK;
  float m = -1e30f;
  #pragma unroll
  for (int c=0;c<NCHUNK;c++) m = fmaxf(m, partM[pb+c]);
  float lsum = 0.f, nsum = 0.f;
  #pragma unroll
  for (int c=0;c<NCHUNK;c++){
    float w = __expf(partM[pb+c]-m);
    lsum += w*partL[pb+c];
    nsum += w*partN[(size_t)(pb+c)*64 + t];
  }
  out0[vb*512 + h*64 + t] = nsum/lsum;
}

// layer-1 out-proj for row 0 + residual(z row0) + LN -> cls embedding slot.
// grid = VB; vb -> clsb[b][branch].
__global__ __launch_bounds__(256) void row0_proj_ln_kernel(
    const float* __restrict__ attn0, const float* __restrict__ Wo, const float* __restrict__ bo,
    const unsigned short* __restrict__ Zh, const unsigned short* __restrict__ Zl,
    const float* __restrict__ g, const float* __restrict__ be,
    float* __restrict__ clsbuf) {
  int vb = blockIdx.x, t = threadIdx.x;
  int b = vb & 3, branch = vb >> 2;
  __shared__ float xin[512];
  __shared__ float y[512];
  __shared__ float red[16];
  for (int i=t;i<512;i+=256) xin[i] = attn0[vb*512+i];
  __syncthreads();
  size_t z0 = (size_t)vb*S_TOT*512;
  for (int n=t;n<512;n+=256){
    const float4* wr = (const float4*)(Wo + (size_t)n*512);
    float acc = bo[n];
    for (int k4=0;k4<128;k4++){
      float4 u = wr[k4]; int k=k4*4;
      acc += xin[k+0]*u.x + xin[k+1]*u.y + xin[k+2]*u.z + xin[k+3]*u.w;
    }
    y[n] = acc + bfval(Zh[z0+n]) + bfval(Zl[z0+n]);
  }
  __syncthreads();
  float s1=0.f, s2=0.f;
  for (int i=t;i<512;i+=256){ float a=y[i]; s1+=a; s2+=a*a; }
  #pragma unroll
  for (int o=32;o;o>>=1){ s1+=__shfl_down(s1,o); s2+=__shfl_down(s2,o); }
  if ((t&63)==0){ red[t>>6]=s1; red[8+(t>>6)]=s2; }
  __syncthreads();
  s1 = red[0]+red[1]+red[2]+red[3];
  s2 = red[8]+red[9]+red[10]+red[11];
  float mean = s1*(1.f/512.f);
  float var  = s2*(1.f/512.f) - mean*mean;
  float rn = rsqrtf(var + 1e-5f);
  for (int i=t;i<512;i+=256)
    clsbuf[b*1024 + branch*512 + i] = (y[i]-mean)*rn*g[i] + be[i];
}

// ---------------------------------------------------------------------------
// Final MLP layer (wave-per-neuron GEMV).
// ---------------------------------------------------------------------------
__global__ __launch_bounds__(256) void fm_layer_kernel(
    const float* __restrict__ in, const float* __restrict__ W,
    const float* __restrict__ bias, float* __restrict__ out,
    int K, int N, int act) {
  int b = blockIdx.y;
  int n = blockIdx.x*4 + (threadIdx.x >> 6);
  int lane = threadIdx.x & 63;
  __shared__ float xs[1024];
  for (int i=threadIdx.x; i<K; i+=256) xs[i] = in[(size_t)b*K + i];
  __syncthreads();
  const float* wr = W + (size_t)n*K;
  float acc = 0.f;
  #pragma unroll 4
  for (int k=lane*4; k<K; k+=256){
    float4 u = *(const float4*)(wr + k);
    acc += xs[k]*u.x + xs[k+1]*u.y + xs[k+2]*u.z + xs[k+3]*u.w;
  }
  #pragma unroll
  for (int o=32;o;o>>=1) acc += __shfl_down(acc, o);
  if (lane==0){
    float v = acc + bias[n];
    if (act) v = gelu_exact(v);
    out[(size_t)b*N + n] = v;
  }
}

// ---------------------------------------------------------------------------
extern "C" void kernel_launch(void* const* d_in, const int* in_sizes, int n_in,
                              void* d_out, int out_size, void* d_ws, size_t ws_size,
                              hipStream_t stream) {
  const float* x      = (const float*)d_in[0];
  const float* cls_tk = (const float*)d_in[1];
  const float* ln_g   = (const float*)d_in[2];
  const float* ln_b   = (const float*)d_in[3];
  const float* aw_W0  = (const float*)d_in[4];  const float* aw_b0 = (const float*)d_in[5];
  const float* aw_W1  = (const float*)d_in[6];  const float* aw_b1 = (const float*)d_in[7];
  const float* aw_W2  = (const float*)d_in[8];  const float* aw_b2 = (const float*)d_in[9];
  const float* pr_W0  = (const float*)d_in[10]; const float* pr_b0 = (const float*)d_in[11];
  const float* pr_W1  = (const float*)d_in[12]; const float* pr_b1 = (const float*)d_in[13];
  const float* pr_W2  = (const float*)d_in[14]; const float* pr_b2 = (const float*)d_in[15];
  const float* mWqkv[2] = {(const float*)d_in[16], (const float*)d_in[20]};
  const float* mbqkv[2] = {(const float*)d_in[17], (const float*)d_in[21]};
  const float* mWo[2]   = {(const float*)d_in[18], (const float*)d_in[22]};
  const float* mbo[2]   = {(const float*)d_in[19], (const float*)d_in[23]};

  float* ws = (float*)d_ws;
  size_t off = 0;
  float* weight = ws + off; off += 8192;                      // [B,N]
  int*   idx    = (int*)(ws + off); off += VROWS + 8;         // [VB,S]
  int*   cnt    = (int*)(ws + off); off += 16;                // [VB]
  float* W0T    = ws + off; off += 32768;                     // [512][64]
  const size_t HBUF = (size_t)VROWS*512/2;                    // bf16 array in float units
  unsigned short* Zh = (unsigned short*)(ws + off); off += HBUF;
  unsigned short* Zl = (unsigned short*)(ws + off); off += HBUF;
  float* QKVr   = ws + off; off += (size_t)VROWS*1536/2;      // shared region (bf16-sized):
  unsigned short* QKVb = (unsigned short*)QKVr;               //  layer-0 QKV bf16 (stride 1536)
  float* T2     = QKVr;                                       //  out-proj fp32 (stride 512, 2/3 of region)
  unsigned short* KVb  = (unsigned short*)QKVr;               //  layer-1 KV bf16 (stride 1024, 2/3)
  unsigned short* Oh = (unsigned short*)(ws + off); off += HBUF;  // also a1 hi
  unsigned short* Ol = (unsigned short*)(ws + off); off += HBUF;  // also a1 lo
  unsigned short* Wq0h = (unsigned short*)(ws + off); off += 393216;
  unsigned short* Wq0l = (unsigned short*)(ws + off); off += 393216;
  unsigned short* Wq1h = (unsigned short*)(ws + off); off += 393216;
  unsigned short* Wq1l = (unsigned short*)(ws + off); off += 393216;
  unsigned short* Wo0h = (unsigned short*)(ws + off); off += 131072;
  unsigned short* Wo0l = (unsigned short*)(ws + off); off += 131072;
  float* attn0  = ws + off; off += VB*512;                    // [VB,D]
  float* q0buf  = ws + off; off += VB*512;                    // [VB,D]
  float* clsb   = ws + off; off += 4096;                      // [B,2D]
  float* h1buf  = ws + off; off += 2048;                      // [B,D]
  float* h2buf  = ws + off; off += 2048;                      // [B,D]
  float* partM  = ws + off; off += VB*NH*NCHUNK;              // 1024
  float* partL  = ws + off; off += VB*NH*NCHUNK;              // 1024
  float* partN  = ws + off; off += (size_t)VB*NH*NCHUNK*64;   // 65536
  (void)ws_size; (void)in_sizes; (void)n_in; (void)out_size;

  transpose_w0_kernel<<<(32768+255)/256, 256, 0, stream>>>(aw_W0, W0T);
  aw_weight_kernel<<<B_SZ*N_INST, 64, 0, stream>>>(
      x, W0T, aw_b0, aw_W1, aw_b1, aw_W2, aw_b2, weight);

  split_kernel<<<(786432+255)/256, 256, 0, stream>>>(mWqkv[0], Wq0h, Wq0l, 786432);
  split_kernel<<<(786432+255)/256, 256, 0, stream>>>(mWqkv[1], Wq1h, Wq1l, 786432);
  split_kernel<<<(262144+255)/256, 256, 0, stream>>>(mWo[0],  Wo0h, Wo0l, 262144);

  const int MT = (VROWS + 63)/64;   // 257 row tiles
  // both branches batched as vb = branch*4 + b
  compact_kernel<<<VB, 256, 0, stream>>>(weight, idx, cnt);
  build_z_kernel<<<VROWS, 256, 0, stream>>>(x, weight, cls_tk, ln_g, ln_b, idx, cnt, Zh, Zl);
  // layer 0
  mfma_gemm_kernel<<<dim3(1536/64, MT), 256, 0, stream>>>(
      Zh, Zl, Wq0h, Wq0l, mbqkv[0], QKVb, VROWS, 1536, cnt, 1);
  flash_attn_kernel<<<dim3((S_TOT+127)/128, NH, VB), 256, 0, stream>>>(QKVb, cnt, Oh, Ol);
  mfma_gemm_kernel<<<dim3(512/64, MT), 256, 0, stream>>>(
      Oh, Ol, Wo0h, Wo0l, mbo[0], T2, VROWS, 512, cnt, 0);
  add_ln_kernel<<<VROWS, 256, 0, stream>>>(Zh, Zl, T2, ln_g, ln_b, cnt, Oh, Ol); // a1 -> Oh/Ol
  // layer 1: row0 Q via fp32 GEMV; KV for all rows, bf16 (stride 1024)
  row0_q_kernel<<<dim3(128, VB), 256, 0, stream>>>(Oh, Ol, mWqkv[1], mbqkv[1], q0buf);
  mfma_gemm_kernel<<<dim3(1024/64, MT), 256, 0, stream>>>(
      Oh, Ol, Wq1h + (size_t)512*512, Wq1l + (size_t)512*512,
      mbqkv[1] + 512, KVb, VROWS, 1024, cnt, 1);
  attn_row0_part_kernel<<<dim3(NH, VB, NCHUNK), 256, 0, stream>>>(
      KVb, q0buf, cnt, partM, partL, partN);
  attn_row0_combine_kernel<<<dim3(NH, VB), 64, 0, stream>>>(
      partM, partL, partN, attn0);
  row0_proj_ln_kernel<<<VB, 256, 0, stream>>>(
      attn0, mWo[1], mbo[1], Zh, Zl, ln_g, ln_b, clsb);
  // final MLP: 3 wave-per-neuron GEMV layers
  fm_layer_kernel<<<dim3(128, B_SZ), 256, 0, stream>>>(clsb,  pr_W0, pr_b0, h1buf, 1024, 512, 1);
  fm_layer_kernel<<<dim3(128, B_SZ), 256, 0, stream>>>(h1buf, pr_W1, pr_b1, h2buf,  512, 512, 1);
  fm_layer_kernel<<<dim3(128, B_SZ), 256, 0, stream>>>(h2buf, pr_W2, pr_b2, (float*)d_out, 512, 512, 0);
}